// Round 11
// baseline (722.199 us; speedup 1.0000x reference)
//
#include <hip/hip_runtime.h>
#include <math.h>

typedef __attribute__((ext_vector_type(4))) float f32x4;
typedef __attribute__((ext_vector_type(8))) __bf16 bf16x8;
typedef __attribute__((ext_vector_type(4))) unsigned short us4;
typedef unsigned long long u64;

__device__ __forceinline__ unsigned short f2bf(float f) {
  unsigned int u = __float_as_uint(f);
  u += 0x7fffu + ((u >> 16) & 1u);            // RNE
  return (unsigned short)(u >> 16);
}
__device__ __forceinline__ float bf2f(unsigned short h) {
  return __uint_as_float(((unsigned int)h) << 16);
}

__device__ __forceinline__ void gload16(const void* g, void* l) {
  __builtin_amdgcn_global_load_lds(
      (__attribute__((address_space(1))) void*)g,
      (__attribute__((address_space(3))) void*)l, 16, 0, 0);
}

// ---------------- K2 fragment-major index: K element (s, kvh, d) ----------------
__device__ __forceinline__ long k2idx(int kvh, int s, int d) {
  int ct = s >> 4;
  int lane = (((d & 31) >> 3) << 4) | (s & 15);
  return ((long)(kvh * 128 + ct) * 4 + (d >> 5)) * 512 + lane * 8 + (d & 7);
}

// ---------------- fused fp32 -> bf16 conversions (all 5 inputs, one kernel) ----------------
__device__ __forceinline__ void split1(const float* __restrict__ in,
                                       unsigned short* __restrict__ hi,
                                       unsigned short* __restrict__ lo, int i) {
  float4 v = ((const float4*)in)[i];
  us4 h, l;
  float vv[4] = {v.x, v.y, v.z, v.w};
#pragma unroll
  for (int j = 0; j < 4; ++j) {
    unsigned short hh = f2bf(vv[j]);
    h[j] = hh;
    l[j] = f2bf(vv[j] - bf2f(hh));
  }
  ((us4*)hi)[i] = h;
  ((us4*)lo)[i] = l;
}
__device__ __forceinline__ void plain1(const float* __restrict__ in,
                                       unsigned short* __restrict__ out, int i) {
  float4 v = ((const float4*)in)[i];
  us4 o;
  o[0] = f2bf(v.x); o[1] = f2bf(v.y); o[2] = f2bf(v.z); o[3] = f2bf(v.w);
  ((us4*)out)[i] = o;
}

__global__ __launch_bounds__(256) void cvt_all(const float* __restrict__ hidden,
                                               const float* __restrict__ wq,
                                               const float* __restrict__ wk,
                                               const float* __restrict__ wv,
                                               const float* __restrict__ wo,
                                               unsigned short* __restrict__ hb_hi,
                                               unsigned short* __restrict__ hb_lo,
                                               unsigned short* __restrict__ wq_hi,
                                               unsigned short* __restrict__ wq_lo,
                                               unsigned short* __restrict__ wk_hi,
                                               unsigned short* __restrict__ wk_lo,
                                               unsigned short* __restrict__ wv_b,
                                               unsigned short* __restrict__ wo_b) {
  int i = blockIdx.x * 256 + threadIdx.x;
  if (i < 2097152)       split1(hidden, hb_hi, hb_lo, i);
  else if (i < 6291456)  split1(wq, wq_hi, wq_lo, i - 2097152);
  else if (i < 7340032)  split1(wk, wk_hi, wk_lo, i - 6291456);
  else if (i < 8388608)  plain1(wv, wv_b, i - 7340032);
  else if (i < 12582912) plain1(wo, wo_b, i - 8388608);
}

// ---------------- RoPE angle table (staged in d_out; overwritten by final GEMM) ----------------
__global__ __launch_bounds__(256) void rope_table(float* __restrict__ ctab,
                                                  float* __restrict__ stab) {
  int idx = blockIdx.x * 256 + threadIdx.x;   // 2048*64
  if (idx >= 2048 * 64) return;
  int s = idx >> 6, d = idx & 63;
  float inv = powf(10000.0f, -(float)d * (1.0f / 64.0f));
  float ang = (float)s * inv;
  ctab[idx] = cosf(ang);
  stab[idx] = sinf(ang);
}

// ======== fused QKV projection, 256-wide tiles, 512 threads, 1 block/CU ========
// bid [0,128): Q 256x256 3-term (m=bid&7 aligns A-panel with XCD L2)
// bid [128,192): K 256x128 3-term; bid [192,256): V 256x128 1-term
// Accumulation order per element identical to prior rounds: (kt asc; hh, lh, hl).
__global__ __launch_bounds__(512, 2) void qkv256(const unsigned short* __restrict__ Ahg,
                                                 const unsigned short* __restrict__ Alg,
                                                 const unsigned short* __restrict__ wq_hi,
                                                 const unsigned short* __restrict__ wq_lo,
                                                 const unsigned short* __restrict__ wk_hi,
                                                 const unsigned short* __restrict__ wk_lo,
                                                 const unsigned short* __restrict__ wv_b,
                                                 const float* __restrict__ ctab,
                                                 const float* __restrict__ stab,
                                                 unsigned short* __restrict__ Qh,
                                                 unsigned short* __restrict__ Ql,
                                                 unsigned short* __restrict__ K2h,
                                                 unsigned short* __restrict__ K2l,
                                                 unsigned short* __restrict__ V2) {
  __shared__ __align__(16) unsigned short shb[65536];   // 128 KB
  const int bid = blockIdx.x;
  const int tid = threadIdx.x;
  const int w = tid >> 6, l = tid & 63;
  const int lr = l & 15, lg = l >> 4;
  const int wr = w >> 2, wc = w & 3;
  const int nt = 128;

  if (bid < 128) {
    // ---------------- Q-proj: 256x256, 3-term split, rope epilogue ----------------
    const long m0 = (long)(bid & 7) * 256;
    const long n0 = (long)(bid >> 3) * 256;
    f32x4 acc[8][4] = {};
    const int ca0 = w * 128 + l, ca1 = ca0 + 64;
    const long a0 = (m0 + (ca0 >> 2)) * 4096 + (ca0 & 3) * 8;
    const long a1 = (m0 + (ca1 >> 2)) * 4096 + (ca1 & 3) * 8;
    const long b0 = (n0 + (ca0 >> 2)) * 4096 + (ca0 & 3) * 8;
    const long b1 = (n0 + (ca1 >> 2)) * 4096 + (ca1 & 3) * 8;
    const int cu0 = (w * 128) * 8, cu1 = (w * 128 + 64) * 8;

#define QSTAGE(t, b)                                                \
    { long kt = (long)(t) * 32;                                     \
      gload16(Ahg + a0 + kt, &shb[(b) * 8192 + cu0]);               \
      gload16(Ahg + a1 + kt, &shb[(b) * 8192 + cu1]);               \
      gload16(Alg + a0 + kt, &shb[16384 + (b) * 8192 + cu0]);       \
      gload16(Alg + a1 + kt, &shb[16384 + (b) * 8192 + cu1]);       \
      gload16(wq_hi + b0 + kt, &shb[32768 + (b) * 8192 + cu0]);     \
      gload16(wq_hi + b1 + kt, &shb[32768 + (b) * 8192 + cu1]);     \
      gload16(wq_lo + b0 + kt, &shb[49152 + (b) * 8192 + cu0]);     \
      gload16(wq_lo + b1 + kt, &shb[49152 + (b) * 8192 + cu1]); }

    QSTAGE(0, 0);
    QSTAGE(1, 1);
    for (int t = 0; t < nt; ++t) {
      if (t + 1 < nt) asm volatile("s_waitcnt vmcnt(8)" ::: "memory");
      else            asm volatile("s_waitcnt vmcnt(0)" ::: "memory");
      __builtin_amdgcn_s_barrier();
      __builtin_amdgcn_sched_barrier(0);
      const int b = t & 1;
      bf16x8 bfh[4], bfl[4];
#pragma unroll
      for (int ni = 0; ni < 4; ++ni) {
        const int rb = (wc * 64 + ni * 16 + lr) * 32 + lg * 8;
        bfh[ni] = *(const bf16x8*)&shb[32768 + b * 8192 + rb];
        bfl[ni] = *(const bf16x8*)&shb[49152 + b * 8192 + rb];
      }
#pragma unroll
      for (int mi = 0; mi < 8; ++mi) {
        const int ra = (wr * 128 + mi * 16 + lr) * 32 + lg * 8;
        bf16x8 afh = *(const bf16x8*)&shb[b * 8192 + ra];
        bf16x8 afl = *(const bf16x8*)&shb[16384 + b * 8192 + ra];
#pragma unroll
        for (int ni = 0; ni < 4; ++ni) {
          acc[mi][ni] = __builtin_amdgcn_mfma_f32_16x16x32_bf16(afh, bfh[ni], acc[mi][ni], 0, 0, 0);
          acc[mi][ni] = __builtin_amdgcn_mfma_f32_16x16x32_bf16(afl, bfh[ni], acc[mi][ni], 0, 0, 0);
          acc[mi][ni] = __builtin_amdgcn_mfma_f32_16x16x32_bf16(afh, bfl[ni], acc[mi][ni], 0, 0, 0);
        }
      }
      __builtin_amdgcn_sched_barrier(0);
      __builtin_amdgcn_s_barrier();
      __builtin_amdgcn_sched_barrier(0);
      if (t + 2 < nt) QSTAGE(t + 2, b);
    }
#undef QSTAGE

    // epilogue: two 256x128 col-halves through LDS, rope+split (math identical to prior rounds)
    float* Cls = (float*)shb;
    for (int ch = 0; ch < 2; ++ch) {
      __syncthreads();
      if ((wc >> 1) == ch) {
#pragma unroll
        for (int mi = 0; mi < 8; ++mi)
#pragma unroll
          for (int ni = 0; ni < 4; ++ni)
#pragma unroll
            for (int j = 0; j < 4; ++j)
              Cls[(wr * 128 + mi * 16 + lg * 4 + j) * 128 + (wc & 1) * 64 + ni * 16 + lr] = acc[mi][ni][j];
      }
      __syncthreads();
      const int head = (int)(n0 >> 7) + ch;
      const int r0l = tid >> 3;
      const int d0 = (tid & 7) * 8;
#pragma unroll
      for (int k = 0; k < 4; ++k) {
        const int r = r0l + 64 * k;
        const long s = m0 + r;
        float X1[8], X2[8], CC[8], SS[8];
        {
          f32x4 a = *(const f32x4*)&Cls[r * 128 + d0];
          f32x4 b = *(const f32x4*)&Cls[r * 128 + d0 + 4];
          f32x4 c = *(const f32x4*)&Cls[r * 128 + 64 + d0];
          f32x4 d = *(const f32x4*)&Cls[r * 128 + 64 + d0 + 4];
          f32x4 e = *(const f32x4*)&ctab[s * 64 + d0];
          f32x4 f = *(const f32x4*)&ctab[s * 64 + d0 + 4];
          f32x4 g = *(const f32x4*)&stab[s * 64 + d0];
          f32x4 h = *(const f32x4*)&stab[s * 64 + d0 + 4];
#pragma unroll
          for (int j = 0; j < 4; ++j) {
            X1[j] = a[j]; X1[j + 4] = b[j];
            X2[j] = c[j]; X2[j + 4] = d[j];
            CC[j] = e[j]; CC[j + 4] = f[j];
            SS[j] = g[j]; SS[j + 4] = h[j];
          }
        }
        us4 H1[2], L1[2], H2[2], L2[2];
#pragma unroll
        for (int j = 0; j < 8; ++j) {
          float y1 = (X1[j] * CC[j] - X2[j] * SS[j]) * 0.08838834764831845f;
          float y2 = (X2[j] * CC[j] + X1[j] * SS[j]) * 0.08838834764831845f;
          unsigned short h1 = f2bf(y1), h2 = f2bf(y2);
          H1[j >> 2][j & 3] = h1; L1[j >> 2][j & 3] = f2bf(y1 - bf2f(h1));
          H2[j >> 2][j & 3] = h2; L2[j >> 2][j & 3] = f2bf(y2 - bf2f(h2));
        }
        long row = s * 4096 + head * 128;
        *(us4*)&Qh[row + d0] = H1[0];      *(us4*)&Qh[row + d0 + 4] = H1[1];
        *(us4*)&Ql[row + d0] = L1[0];      *(us4*)&Ql[row + d0 + 4] = L1[1];
        *(us4*)&Qh[row + 64 + d0] = H2[0]; *(us4*)&Qh[row + 64 + d0 + 4] = H2[1];
        *(us4*)&Ql[row + 64 + d0] = L2[0]; *(us4*)&Ql[row + 64 + d0 + 4] = L2[1];
      }
      __syncthreads();
    }
    return;
  }

  if (bid < 192) {
    // ---------------- K-proj: 256x128, 3-term split, rope epilogue -> frag-major ----------------
    const int tK = bid - 128;
    const long m0 = (long)(tK & 7) * 256;
    const long n0 = (long)(tK >> 3) * 128;
    f32x4 acc[8][2] = {};
    const int ca0 = w * 128 + l, ca1 = ca0 + 64;
    const long a0 = (m0 + (ca0 >> 2)) * 4096 + (ca0 & 3) * 8;
    const long a1 = (m0 + (ca1 >> 2)) * 4096 + (ca1 & 3) * 8;
    const int cb = w * 64 + l;
    const long b0 = (n0 + (cb >> 2)) * 4096 + (cb & 3) * 8;
    const int cu0 = (w * 128) * 8, cu1 = (w * 128 + 64) * 8, cub = (w * 64) * 8;

#define KSTAGE(t, b)                                                \
    { long kt = (long)(t) * 32;                                     \
      gload16(Ahg + a0 + kt, &shb[(b) * 8192 + cu0]);               \
      gload16(Ahg + a1 + kt, &shb[(b) * 8192 + cu1]);               \
      gload16(Alg + a0 + kt, &shb[16384 + (b) * 8192 + cu0]);       \
      gload16(Alg + a1 + kt, &shb[16384 + (b) * 8192 + cu1]);       \
      gload16(wk_hi + b0 + kt, &shb[32768 + (b) * 4096 + cub]);     \
      gload16(wk_lo + b0 + kt, &shb[40960 + (b) * 4096 + cub]); }

    KSTAGE(0, 0);
    KSTAGE(1, 1);
    for (int t = 0; t < nt; ++t) {
      if (t + 1 < nt) asm volatile("s_waitcnt vmcnt(6)" ::: "memory");
      else            asm volatile("s_waitcnt vmcnt(0)" ::: "memory");
      __builtin_amdgcn_s_barrier();
      __builtin_amdgcn_sched_barrier(0);
      const int b = t & 1;
      bf16x8 bfh[2], bfl[2];
#pragma unroll
      for (int ni = 0; ni < 2; ++ni) {
        const int rb = (wc * 32 + ni * 16 + lr) * 32 + lg * 8;
        bfh[ni] = *(const bf16x8*)&shb[32768 + b * 4096 + rb];
        bfl[ni] = *(const bf16x8*)&shb[40960 + b * 4096 + rb];
      }
#pragma unroll
      for (int mi = 0; mi < 8; ++mi) {
        const int ra = (wr * 128 + mi * 16 + lr) * 32 + lg * 8;
        bf16x8 afh = *(const bf16x8*)&shb[b * 8192 + ra];
        bf16x8 afl = *(const bf16x8*)&shb[16384 + b * 8192 + ra];
#pragma unroll
        for (int ni = 0; ni < 2; ++ni) {
          acc[mi][ni] = __builtin_amdgcn_mfma_f32_16x16x32_bf16(afh, bfh[ni], acc[mi][ni], 0, 0, 0);
          acc[mi][ni] = __builtin_amdgcn_mfma_f32_16x16x32_bf16(afl, bfh[ni], acc[mi][ni], 0, 0, 0);
          acc[mi][ni] = __builtin_amdgcn_mfma_f32_16x16x32_bf16(afh, bfl[ni], acc[mi][ni], 0, 0, 0);
        }
      }
      __builtin_amdgcn_sched_barrier(0);
      __builtin_amdgcn_s_barrier();
      __builtin_amdgcn_sched_barrier(0);
      if (t + 2 < nt) KSTAGE(t + 2, b);
    }
#undef KSTAGE

    // epilogue: whole 256x128 tile through LDS, rope (scale 1) -> K2 frag-major
    float* Cls = (float*)shb;
    __syncthreads();
#pragma unroll
    for (int mi = 0; mi < 8; ++mi)
#pragma unroll
      for (int ni = 0; ni < 2; ++ni)
#pragma unroll
        for (int j = 0; j < 4; ++j)
          Cls[(wr * 128 + mi * 16 + lg * 4 + j) * 128 + wc * 32 + ni * 16 + lr] = acc[mi][ni][j];
    __syncthreads();
    const int kvh = (int)(n0 >> 7);
    const int r0l = tid >> 3;
    const int d0 = (tid & 7) * 8;
#pragma unroll
    for (int k = 0; k < 4; ++k) {
      const int r = r0l + 64 * k;
      const long s = m0 + r;
      float X1[8], X2[8], CC[8], SS[8];
      {
        f32x4 a = *(const f32x4*)&Cls[r * 128 + d0];
        f32x4 b = *(const f32x4*)&Cls[r * 128 + d0 + 4];
        f32x4 c = *(const f32x4*)&Cls[r * 128 + 64 + d0];
        f32x4 d = *(const f32x4*)&Cls[r * 128 + 64 + d0 + 4];
        f32x4 e = *(const f32x4*)&ctab[s * 64 + d0];
        f32x4 f = *(const f32x4*)&ctab[s * 64 + d0 + 4];
        f32x4 g = *(const f32x4*)&stab[s * 64 + d0];
        f32x4 h = *(const f32x4*)&stab[s * 64 + d0 + 4];
#pragma unroll
        for (int j = 0; j < 4; ++j) {
          X1[j] = a[j]; X1[j + 4] = b[j];
          X2[j] = c[j]; X2[j + 4] = d[j];
          CC[j] = e[j]; CC[j + 4] = f[j];
          SS[j] = g[j]; SS[j + 4] = h[j];
        }
      }
      us4 H1[2], L1[2], H2[2], L2[2];
#pragma unroll
      for (int j = 0; j < 8; ++j) {
        float y1 = X1[j] * CC[j] - X2[j] * SS[j];
        float y2 = X2[j] * CC[j] + X1[j] * SS[j];
        unsigned short h1 = f2bf(y1), h2 = f2bf(y2);
        H1[j >> 2][j & 3] = h1; L1[j >> 2][j & 3] = f2bf(y1 - bf2f(h1));
        H2[j >> 2][j & 3] = h2; L2[j >> 2][j & 3] = f2bf(y2 - bf2f(h2));
      }
      long i1 = k2idx(kvh, (int)s, d0);
      long i2 = k2idx(kvh, (int)s, d0 + 64);
      *(us4*)&K2h[i1] = H1[0]; *(us4*)&K2h[i1 + 4] = H1[1];
      *(us4*)&K2l[i1] = L1[0]; *(us4*)&K2l[i1 + 4] = L1[1];
      *(us4*)&K2h[i2] = H2[0]; *(us4*)&K2h[i2 + 4] = H2[1];
      *(us4*)&K2l[i2] = L2[0]; *(us4*)&K2l[i2 + 4] = L2[1];
    }
    return;
  }

  // ---------------- V-proj: 256x128, 1-term, V2 fragment-major ----------------
  {
    const int tV = bid - 192;
    const long m0 = (long)(tV & 7) * 256;
    const long n0 = (long)(tV >> 3) * 128;
    f32x4 acc[8][2] = {};
    const int ca0 = w * 128 + l, ca1 = ca0 + 64;
    const long a0 = (m0 + (ca0 >> 2)) * 4096 + (ca0 & 3) * 8;
    const long a1 = (m0 + (ca1 >> 2)) * 4096 + (ca1 & 3) * 8;
    const int cb = w * 64 + l;
    const long b0 = (n0 + (cb >> 2)) * 4096 + (cb & 3) * 8;
    const int cu0 = (w * 128) * 8, cu1 = (w * 128 + 64) * 8, cub = (w * 64) * 8;

#define VSTAGE(t, b)                                                \
    { long kt = (long)(t) * 32;                                     \
      gload16(Ahg + a0 + kt, &shb[(b) * 8192 + cu0]);               \
      gload16(Ahg + a1 + kt, &shb[(b) * 8192 + cu1]);               \
      gload16(wv_b + b0 + kt, &shb[32768 + (b) * 4096 + cub]); }

    VSTAGE(0, 0);
    VSTAGE(1, 1);
    for (int t = 0; t < nt; ++t) {
      if (t + 1 < nt) asm volatile("s_waitcnt vmcnt(3)" ::: "memory");
      else            asm volatile("s_waitcnt vmcnt(0)" ::: "memory");
      __builtin_amdgcn_s_barrier();
      __builtin_amdgcn_sched_barrier(0);
      const int b = t & 1;
      bf16x8 bfr[2];
#pragma unroll
      for (int ni = 0; ni < 2; ++ni) {
        const int rb = (wc * 32 + ni * 16 + lr) * 32 + lg * 8;
        bfr[ni] = *(const bf16x8*)&shb[32768 + b * 4096 + rb];
      }
#pragma unroll
      for (int mi = 0; mi < 8; ++mi) {
        const int ra = (wr * 128 + mi * 16 + lr) * 32 + lg * 8;
        bf16x8 af = *(const bf16x8*)&shb[b * 8192 + ra];
#pragma unroll
        for (int ni = 0; ni < 2; ++ni)
          acc[mi][ni] = __builtin_amdgcn_mfma_f32_16x16x32_bf16(af, bfr[ni], acc[mi][ni], 0, 0, 0);
      }
      __builtin_amdgcn_sched_barrier(0);
      __builtin_amdgcn_s_barrier();
      __builtin_amdgcn_sched_barrier(0);
      if (t + 2 < nt) VSTAGE(t + 2, b);
    }
#undef VSTAGE

#pragma unroll
    for (int mi = 0; mi < 8; ++mi)
#pragma unroll
      for (int ni = 0; ni < 2; ++ni)
#pragma unroll
        for (int j = 0; j < 4; ++j) {
          long r = m0 + wr * 128 + mi * 16 + lg * 4 + j;
          long cc = n0 + wc * 32 + ni * 16 + lr;
          int kvh = (int)(cc >> 7), d = (int)(cc & 127);
          int c = (int)(r >> 4), t2 = (int)(r & 15);
          long idx = ((long)(kvh * 128 + c) * 8 + (d >> 4)) * 256 + ((t2 >> 3) * 16 + (d & 15)) * 8 + (t2 & 7);
          V2[idx] = f2bf(acc[mi][ni][j]);
        }
  }
}

// ---------------- GEMM: C = A * B^T (O-proj), counted-vmcnt double-buffered ----------------
__global__ __launch_bounds__(256) void gemm_bt(const unsigned short* __restrict__ A,
                                               const unsigned short* __restrict__ B,
                                               float* __restrict__ C,
                                               int M, int N, int K) {
  __shared__ __align__(16) unsigned short As[2][4096];
  __shared__ __align__(16) unsigned short Bs[2][4096];
  const int tid = threadIdx.x;
  const int w = tid >> 6, l = tid & 63;
  const int wm = w >> 1, wn = w & 1;
  const int lr = l & 15, lg = l >> 4;
  const long m0 = (long)blockIdx.y * 128, n0 = (long)blockIdx.x * 128;

  f32x4 acc[4][4] = {};

  const int c0 = w * 128 + l;
  const int c1 = c0 + 64;
  const unsigned short* gA0 = A + (m0 + (c0 >> 2)) * K + (c0 & 3) * 8;
  const unsigned short* gA1 = A + (m0 + (c1 >> 2)) * K + (c1 & 3) * 8;
  const unsigned short* gB0 = B + (n0 + (c0 >> 2)) * K + (c0 & 3) * 8;
  const unsigned short* gB1 = B + (n0 + (c1 >> 2)) * K + (c1 & 3) * 8;

#define STAGE1(t, b)                                   \
  {                                                    \
    long kt = (long)(t) * 32;                          \
    gload16(gA0 + kt, &As[b][w * 1024]);               \
    gload16(gA1 + kt, &As[b][w * 1024 + 512]);         \
    gload16(gB0 + kt, &Bs[b][w * 1024]);               \
    gload16(gB1 + kt, &Bs[b][w * 1024 + 512]);         \
  }

  const int nt = K >> 5;
  STAGE1(0, 0);
  if (nt > 1) STAGE1(1, 1);

  for (int t = 0; t < nt; ++t) {
    if (t + 1 < nt) asm volatile("s_waitcnt vmcnt(4)" ::: "memory");
    else            asm volatile("s_waitcnt vmcnt(0)" ::: "memory");
    __builtin_amdgcn_s_barrier();
    __builtin_amdgcn_sched_barrier(0);
    const int b = t & 1;
    bf16x8 af[4], bfr[4];
#pragma unroll
    for (int mi = 0; mi < 4; ++mi)
      af[mi] = *(const bf16x8*)&As[b][(wm * 64 + mi * 16 + lr) * 32 + lg * 8];
#pragma unroll
    for (int ni = 0; ni < 4; ++ni)
      bfr[ni] = *(const bf16x8*)&Bs[b][(wn * 64 + ni * 16 + lr) * 32 + lg * 8];
#pragma unroll
    for (int mi = 0; mi < 4; ++mi)
#pragma unroll
      for (int ni = 0; ni < 4; ++ni)
        acc[mi][ni] = __builtin_amdgcn_mfma_f32_16x16x32_bf16(af[mi], bfr[ni], acc[mi][ni], 0, 0, 0);
    __builtin_amdgcn_sched_barrier(0);
    __builtin_amdgcn_s_barrier();
    __builtin_amdgcn_sched_barrier(0);
    if (t + 2 < nt) STAGE1(t + 2, b);
  }
#undef STAGE1

#pragma unroll
  for (int mi = 0; mi < 4; ++mi)
#pragma unroll
    for (int ni = 0; ni < 4; ++ni)
#pragma unroll
      for (int j = 0; j < 4; ++j) {
        long r = m0 + wm * 64 + mi * 16 + lg * 4 + j;
        long cc = n0 + wn * 64 + ni * 16 + lr;
        C[r * N + cc] = acc[mi][ni][j];
      }
}

// ======== K1: cmax GEMM, 4-deep counted-vmcnt pipeline. ========
__global__ __launch_bounds__(256, 2) void cmax_gemm(const unsigned short* __restrict__ Qh,
                                                    const unsigned short* __restrict__ Ql,
                                                    const unsigned short* __restrict__ K2h,
                                                    const unsigned short* __restrict__ K2l,
                                                    float* __restrict__ cmaxg) {
  __shared__ __align__(16) unsigned short Ksh[4][4096];  // 4 x 8KB hi (32-tok panel)
  __shared__ __align__(16) unsigned short Ksl[4][4096];  // 4 x 8KB lo
  const int qp = 15 - (int)blockIdx.x;                   // heavy panels first
  const int h = blockIdx.y;
  const int kvh = h >> 2;
  const int q0 = qp * 128;
  const int tid = threadIdx.x;
  const int w = tid >> 6, l = tid & 63;
  const int lr = l & 15, lg = l >> 4;
  const int npan = 4 * (qp + 1);
  const float NEGINF = -__builtin_inff();

  bf16x8 qfh[2][4], qfl[2][4];
#pragma unroll
  for (int rg = 0; rg < 2; ++rg) {
    const unsigned short* qph = Qh + (long)(q0 + w * 32 + rg * 16 + lr) * 4096 + h * 128 + lg * 8;
    const unsigned short* qpl = Ql + (long)(q0 + w * 32 + rg * 16 + lr) * 4096 + h * 128 + lg * 8;
#pragma unroll
    for (int ks = 0; ks < 4; ++ks) {
      qfh[rg][ks] = *(const bf16x8*)(qph + ks * 32);
      qfl[rg][ks] = *(const bf16x8*)(qpl + ks * 32);
    }
  }

  const unsigned short* kbh = K2h + (long)kvh * 128 * 2048;
  const unsigned short* kbl = K2l + (long)kvh * 128 * 2048;

#define STAGE(kp, b)                                                       \
  {                                                                        \
    long off = (long)(kp) * 4096;                                          \
    _Pragma("unroll")                                                      \
    for (int i = 0; i < 2; ++i) {                                          \
      int cu = w * 128 + i * 64;                                           \
      gload16(kbh + off + (cu + l) * 8, &Ksh[b][cu * 8]);                  \
      gload16(kbl + off + (cu + l) * 8, &Ksl[b][cu * 8]);                  \
    }                                                                      \
  }

  STAGE(0, 0);
  if (1 < npan) STAGE(1, 1);
  if (2 < npan) STAGE(2, 2);

  for (int kp = 0; kp < npan; ++kp) {
    {
      int ahead = npan - 1 - kp; if (ahead > 2) ahead = 2;
      int st = kp; if (st > 3) st = 3;
      int tgt = 4 * ahead + 4 * st;
      if (tgt >= 20)      asm volatile("s_waitcnt vmcnt(20)" ::: "memory");
      else if (tgt >= 16) asm volatile("s_waitcnt vmcnt(16)" ::: "memory");
      else if (tgt >= 12) asm volatile("s_waitcnt vmcnt(12)" ::: "memory");
      else if (tgt >= 8)  asm volatile("s_waitcnt vmcnt(8)" ::: "memory");
      else                asm volatile("s_waitcnt vmcnt(0)" ::: "memory");
    }
    __builtin_amdgcn_s_barrier();
    __builtin_amdgcn_sched_barrier(0);
    if (kp + 3 < npan) STAGE(kp + 3, (kp + 3) & 3);
    const int b = kp & 3;
#pragma unroll
    for (int c2 = 0; c2 < 2; ++c2) {
      const int ct = kp * 2 + c2;
      bf16x8 kh[4], kl2[4];
#pragma unroll
      for (int ks = 0; ks < 4; ++ks) {
        kh[ks]  = *(const bf16x8*)&Ksh[b][(c2 * 4 + ks) * 512 + l * 8];
        kl2[ks] = *(const bf16x8*)&Ksl[b][(c2 * 4 + ks) * 512 + l * 8];
      }
#pragma unroll
      for (int rg = 0; rg < 2; ++rg) {
        f32x4 acc = {};
#pragma unroll
        for (int ks = 0; ks < 4; ++ks) {
          acc = __builtin_amdgcn_mfma_f32_16x16x32_bf16(kh[ks], qfh[rg][ks], acc, 0, 0, 0);
          acc = __builtin_amdgcn_mfma_f32_16x16x32_bf16(kh[ks], qfl[rg][ks], acc, 0, 0, 0);
          acc = __builtin_amdgcn_mfma_f32_16x16x32_bf16(kl2[ks], qfh[rg][ks], acc, 0, 0, 0);
        }
        const int rbase = q0 + w * 32 + rg * 16;
        float m;
        if (ct * 16 + 15 <= rbase) {
          m = fmaxf(fmaxf(acc[0], acc[1]), fmaxf(acc[2], acc[3]));
        } else {
          m = NEGINF;
#pragma unroll
          for (int j = 0; j < 4; ++j) {
            int tok = ct * 16 + lg * 4 + j;
            if (tok <= rbase + lr) m = fmaxf(m, acc[j]);
          }
        }
        m = fmaxf(m, __shfl_xor(m, 16));
        m = fmaxf(m, __shfl_xor(m, 32));
        if (l < 16) cmaxg[(long)(h * 128 + ct) * 2048 + rbase + l] = m;
      }
    }
  }
#undef STAGE
}

// ======== K2: per-row top-8 selection. block = (64-row group, head). ========
__global__ __launch_bounds__(256) void select_kernel(const float* __restrict__ cmaxg,
                                                     u64* __restrict__ selEg,
                                                     u64* __restrict__ selOg,
                                                     float* __restrict__ mxg) {
  __shared__ float Lc[128 * 65];                  // [ct][row], padded
  const int r0 = (int)blockIdx.x * 64;
  const int h = blockIdx.y;
  const int tid = threadIdx.x;
  const int w = tid >> 6, l = tid & 63;
  const float NEGINF = -__builtin_inff();

  for (int i = tid; i < 128 * 16; i += 256) {
    int ct = i >> 4, rq = (i & 15) * 4;
    float4 v = *(const float4*)&cmaxg[(long)(h * 128 + ct) * 2048 + r0 + rq];
    Lc[ct * 65 + rq]     = v.x;
    Lc[ct * 65 + rq + 1] = v.y;
    Lc[ct * 65 + rq + 2] = v.z;
    Lc[ct * 65 + rq + 3] = v.w;
  }
  __syncthreads();

  const int c0 = 2 * l, c1 = 2 * l + 1;
#pragma unroll 1
  for (int rs = 0; rs < 16; ++rs) {
    const int rloc = w * 16 + rs;
    const int qr = r0 + rloc;
    const int nctr = (qr >> 4) + 1;
    float v0 = (c0 < nctr) ? Lc[c0 * 65 + rloc] : NEGINF;
    float v1 = (c1 < nctr) ? Lc[c1 * 65 + rloc] : NEGINF;
    const float o0 = v0, o1 = v1;
    float T = NEGINF;
    for (int it = 0; it < 8; ++it) {
      float m = fmaxf(v0, v1);
#pragma unroll
      for (int o = 1; o < 64; o <<= 1) m = fmaxf(m, __shfl_xor(m, o));
      u64 bal = __ballot((v0 == m) || (v1 == m));
      int first = __ffsll(bal) - 1;
      if (l == first) { if (v0 == m) v0 = NEGINF; else v1 = NEGINF; }
      T = m;
    }
    bool okc0 = (c0 < nctr) && ((c0 < 8) || (o0 >= T));
    bool okc1 = (c1 < nctr) && ((c1 < 8) || (o1 >= T));
    u64 bE = __ballot(okc0);
    u64 bO = __ballot(okc1);
    bool al0 = (c0 < nctr) && (okc0 || (c0 * 16 + 15 > qr - 128));
    bool al1 = (c1 < nctr) && (okc1 || (c1 * 16 + 15 > qr - 128));
    float mv = fmaxf(al0 ? o0 : NEGINF, al1 ? o1 : NEGINF);
#pragma unroll
    for (int o = 1; o < 64; o <<= 1) mv = fmaxf(mv, __shfl_xor(mv, o));
    if (l == 0) {
      selEg[h * 2048 + qr] = bE;
      selOg[h * 2048 + qr] = bO;
      mxg[h * 2048 + qr] = mv;
    }
  }
}

// ---------------- P LDS swizzled index (per-wave slice): row, tok32 ----------------
__device__ __forceinline__ int pidx2(int r, int t) {
  return r * 32 + ((((t >> 3) ^ (r & 3)) << 3) | (t & 7));
}

// ======== K3: phase B — recompute selected chunks, exp, PV; K prefetched 1 pair ahead. ========
__global__ __launch_bounds__(256) void attnB(const unsigned short* __restrict__ Qh,
                                             const unsigned short* __restrict__ K2h,
                                             const unsigned short* __restrict__ V2,
                                             const u64* __restrict__ selEg,
                                             const u64* __restrict__ selOg,
                                             const float* __restrict__ mxg,
                                             unsigned short* __restrict__ AO) {
  __shared__ __align__(16) unsigned short Pls[4][512];
  __shared__ int clistS[4][128];

  const int qb = (int)gridDim.x - 1 - (int)blockIdx.x;   // heavy blocks first
  const int kvh = blockIdx.y;
  const int q0 = qb * 16;
  const int nct = qb + 1;
  const int tid = threadIdx.x;
  const int w = tid >> 6, l = tid & 63;
  const int lr = l & 15, lg = l >> 4;
  const int h = kvh * 4 + w;

  bf16x8 qfh[4];
  {
    const unsigned short* qph = Qh + (long)(q0 + lr) * 4096 + h * 128 + lg * 8;
#pragma unroll
    for (int ks = 0; ks < 4; ++ks) qfh[ks] = *(const bf16x8*)(qph + ks * 32);
  }

  u64 myE = selEg[h * 2048 + q0 + lr];
  u64 myO = selOg[h * 2048 + q0 + lr];
  float mymx = mxg[h * 2048 + q0 + lr];

  u64 uE = myE, uO = myO;
#pragma unroll
  for (int o = 1; o < 16; o <<= 1) {
    uE |= __shfl_xor(uE, o);
    uO |= __shfl_xor(uO, o);
  }
  float mxj[4];
  u64 selE[4], selO[4];
#pragma unroll
  for (int j = 0; j < 4; ++j) {
    mxj[j] = __shfl(mymx, lg * 4 + j);
    selE[j] = __shfl(myE, lg * 4 + j);
    selO[j] = __shfl(myO, lg * 4 + j);
  }

  unsigned short* Pw = Pls[w];
  int* cl = clistS[w];

  const int c0 = 2 * l, c1 = 2 * l + 1;
  bool s0ok = (c0 < nct) && (((uE >> l) & 1ull) || (c0 >= qb - 7));
  bool s1ok = (c1 < nct) && (((uO >> l) & 1ull) || (c1 >= qb - 7));
  u64 bA = __ballot(s0ok);
  u64 bB = __ballot(s1ok);
  const int cntA = __popcll(bA);
  const int nsel = cntA + __popcll(bB);
  if (s0ok) cl[__popcll(bA & ((1ull << l) - 1ull))] = c0;
  if (s1ok) cl[cntA + __popcll(bB & ((1ull << l) - 1ull))] = c1;

  const unsigned short* kbh = K2h + (long)kvh * 128 * 2048;

  f32x4 pacc[8] = {};
  float psum[4] = {0.f, 0.f, 0.f, 0.f};
  const int np = (nsel + 1) >> 1;

  bf16x8 kA[4], kB[4];
  {
    const int cA0 = cl[0];
    const int cB0 = (1 < nsel) ? cl[1] : cA0;
    const unsigned short* pA = kbh + (long)cA0 * 2048 + l * 8;
    const unsigned short* pB = kbh + (long)cB0 * 2048 + l * 8;
#pragma unroll
    for (int ks = 0; ks < 4; ++ks) {
      kA[ks] = *(const bf16x8*)(pA + ks * 512);
      kB[ks] = *(const bf16x8*)(pB + ks * 512);
    }
  }

  for (int pi = 0; pi < np; ++pi) {
    const int cA = cl[2 * pi];
    const int iB = 2 * pi + 1;
    const int cB = (iB < nsel) ? cl[iB] : cA;

    const int csel = (lg < 2) ? cA : cB;
    const unsigned short* vp = V2 + (long)(kvh * 128 + csel) * 2048 + ((lg & 1) * 16 + lr) * 8;
    bf16x8 vf[8];
#pragma unroll
    for (int dblk = 0; dblk < 8; ++dblk) vf[dblk] = *(const bf16x8*)(vp + dblk * 256);

    bf16x8 nA[4], nB[4];
    {
      const int pin = (pi + 1 < np) ? pi + 1 : pi;
      const int cA1 = cl[2 * pin];
      const int iB1 = 2 * pin + 1;
      const int cB1 = (iB1 < nsel) ? cl[iB1] : cA1;
      const unsigned short* pA = kbh + (long)cA1 * 2048 + l * 8;
      const unsigned short* pB = kbh + (long)cB1 * 2048 + l * 8;
#pragma unroll
      for (int ks = 0; ks < 4; ++ks) {
        nA[ks] = *(const bf16x8*)(pA + ks * 512);
        nB[ks] = *(const bf16x8*)(pB + ks * 512);
      }
    }

#pragma unroll
    for (int half = 0; half < 2; ++half) {
      const int c = half ? cB : cA;
      const bool vslot = (2 * pi + half) < nsel;
      f32x4 acc = {};
#pragma unroll
      for (int ks = 0; ks < 4; ++ks) {
        bf16x8 kf = half ? kB[ks] : kA[ks];
        acc = __builtin_amdgcn_mfma_f32_16x16x32_bf16(qfh[ks], kf, acc, 0, 0, 0);
      }
#pragma unroll
      for (int j = 0; j < 4; ++j) {
        const int r = lg * 4 + j;
        const int qrr = q0 + r;
        const int tok = c * 16 + lr;
        u64 sm = (c & 1) ? selO[j] : selE[j];
        bool sel = (sm >> (c >> 1)) & 1ull;
        bool al = vslot && (tok <= qrr) && (sel || (tok > qrr - 128));
        float p = al ? __expf(acc[j] - mxj[j]) : 0.f;
        unsigned short pb = f2bf(p);
        psum[j] += bf2f(pb);
        Pw[pidx2(r, half * 16 + lr)] = pb;
      }
    }
    bf16x8 pa = *(const bf16x8*)&Pw[pidx2(lr, lg * 8)];
#pragma unroll
    for (int dblk = 0; dblk < 8; ++dblk)
      pacc[dblk] = __builtin_amdgcn_mfma_f32_16x16x32_bf16(pa, vf[dblk], pacc[dblk], 0, 0, 0);

#pragma unroll
    for (int ks = 0; ks < 4; ++ks) { kA[ks] = nA[ks]; kB[ks] = nB[ks]; }
  }

#pragma unroll
  for (int j = 0; j < 4; ++j) {
    float s = psum[j];
    s += __shfl_xor(s, 1); s += __shfl_xor(s, 2);
    s += __shfl_xor(s, 4); s += __shfl_xor(s, 8);
    const float rd = 1.0f / s;
    const int r = lg * 4 + j;
#pragma unroll
    for (int dblk = 0; dblk < 8; ++dblk)
      AO[(long)(q0 + r) * 4096 + h * 128 + dblk * 16 + lr] = f2bf(pacc[dblk][j] * rd);
  }
}

// ---------------- launch ----------------
extern "C" void kernel_launch(void* const* d_in, const int* in_sizes, int n_in,
                              void* d_out, int out_size, void* d_ws, size_t ws_size,
                              hipStream_t stream) {
  const float* hidden = (const float*)d_in[0];
  const float* wq = (const float*)d_in[1];
  const float* wk = (const float*)d_in[2];
  const float* wv = (const float*)d_in[3];
  const float* wo = (const float*)d_in[4];
  float* out = (float*)d_out;

  unsigned short* hb_hi = (unsigned short*)d_ws;          // [2048][4096]
  unsigned short* hb_lo = hb_hi + (size_t)2048 * 4096;
  unsigned short* wq_hi = hb_lo + (size_t)2048 * 4096;    // [4096][4096]
  unsigned short* wq_lo = wq_hi + (size_t)4096 * 4096;
  unsigned short* wk_hi = wq_lo + (size_t)4096 * 4096;    // [1024][4096]
  unsigned short* wk_lo = wk_hi + (size_t)1024 * 4096;
  unsigned short* wv_b  = wk_lo + (size_t)1024 * 4096;    // [1024][4096]
  unsigned short* wo_b  = wv_b  + (size_t)1024 * 4096;    // [4096][4096]
  // dedicated qkv outputs (no aliasing with weights read by other blocks)
  unsigned short* Qhi = wo_b + (size_t)4096 * 4096;       // [2048][4096] bf16
  unsigned short* Qlo = Qhi + (size_t)2048 * 4096;
  unsigned short* K2h = Qlo + (size_t)2048 * 4096;        // frag-major, 2M elems
  unsigned short* K2l = K2h + (size_t)2048 * 1024;
  unsigned short* V2  = K2l + (size_t)2048 * 1024;        // frag-major, 2M elems
  // aliases (stream-ordered lifetimes):
  unsigned short* AO = hb_hi;         // hidden splits dead after QKV GEMM
  float* cmaxg = (float*)wq_hi;       // wq splits dead after QKV GEMM (33.5 MB <= 64 MB)
  u64* selEg = (u64*)wk_hi;           // wk splits dead after QKV GEMM
  u64* selOg = selEg + 32 * 2048;
  float* mxg = (float*)(selOg + 32 * 2048);
  float* ctab = out;                  // staged in d_out; fully overwritten by final GEMM
  float* stab = ctab + 2048 * 64;

  cvt_all<<<49152, 256, 0, stream>>>(hidden, wq, wk, wv, wo,
                                     hb_hi, hb_lo, wq_hi, wq_lo,
                                     wk_hi, wk_lo, wv_b, wo_b);
  rope_table<<<512, 256, 0, stream>>>(ctab, stab);

  qkv256<<<256, 512, 0, stream>>>(hb_hi, hb_lo, wq_hi, wq_lo,
                                  wk_hi, wk_lo, wv_b, ctab, stab,
                                  Qhi, Qlo, K2h, K2l, V2);

  cmax_gemm<<<dim3(16, 32), 256, 0, stream>>>(Qhi, Qlo, K2h, K2l, cmaxg);
  select_kernel<<<dim3(32, 32), 256, 0, stream>>>(cmaxg, selEg, selOg, mxg);
  attnB<<<dim3(128, 8), 256, 0, stream>>>(Qhi, K2h, V2, selEg, selOg, mxg, AO);

  gemm_bt<<<dim3(32, 16), 256, 0, stream>>>(AO, wo_b, out, 2048, 4096, 4096);
}

// Round 12
// 695.756 us; speedup vs baseline: 1.0380x; 1.0380x over previous
//
#include <hip/hip_runtime.h>
#include <math.h>

typedef __attribute__((ext_vector_type(4))) float f32x4;
typedef __attribute__((ext_vector_type(8))) __bf16 bf16x8;
typedef __attribute__((ext_vector_type(4))) unsigned short us4;
typedef unsigned long long u64;

__device__ __forceinline__ unsigned short f2bf(float f) {
  unsigned int u = __float_as_uint(f);
  u += 0x7fffu + ((u >> 16) & 1u);            // RNE
  return (unsigned short)(u >> 16);
}
__device__ __forceinline__ float bf2f(unsigned short h) {
  return __uint_as_float(((unsigned int)h) << 16);
}

__device__ __forceinline__ void gload16(const void* g, void* l) {
  __builtin_amdgcn_global_load_lds(
      (__attribute__((address_space(1))) void*)g,
      (__attribute__((address_space(3))) void*)l, 16, 0, 0);
}

// ---------------- K2 fragment-major index: K element (s, kvh, d) ----------------
__device__ __forceinline__ long k2idx(int kvh, int s, int d) {
  int ct = s >> 4;
  int lane = (((d & 31) >> 3) << 4) | (s & 15);
  return ((long)(kvh * 128 + ct) * 4 + (d >> 5)) * 512 + lane * 8 + (d & 7);
}

// ---------------- fused fp32 -> bf16 conversions (all 5 inputs, one kernel) ----------------
__device__ __forceinline__ void split1(const float* __restrict__ in,
                                       unsigned short* __restrict__ hi,
                                       unsigned short* __restrict__ lo, int i) {
  float4 v = ((const float4*)in)[i];
  us4 h, l;
  float vv[4] = {v.x, v.y, v.z, v.w};
#pragma unroll
  for (int j = 0; j < 4; ++j) {
    unsigned short hh = f2bf(vv[j]);
    h[j] = hh;
    l[j] = f2bf(vv[j] - bf2f(hh));
  }
  ((us4*)hi)[i] = h;
  ((us4*)lo)[i] = l;
}
__device__ __forceinline__ void plain1(const float* __restrict__ in,
                                       unsigned short* __restrict__ out, int i) {
  float4 v = ((const float4*)in)[i];
  us4 o;
  o[0] = f2bf(v.x); o[1] = f2bf(v.y); o[2] = f2bf(v.z); o[3] = f2bf(v.w);
  ((us4*)out)[i] = o;
}

__global__ __launch_bounds__(256) void cvt_all(const float* __restrict__ hidden,
                                               const float* __restrict__ wq,
                                               const float* __restrict__ wk,
                                               const float* __restrict__ wv,
                                               const float* __restrict__ wo,
                                               unsigned short* __restrict__ hb_hi,
                                               unsigned short* __restrict__ hb_lo,
                                               unsigned short* __restrict__ wq_hi,
                                               unsigned short* __restrict__ wq_lo,
                                               unsigned short* __restrict__ wk_hi,
                                               unsigned short* __restrict__ wk_lo,
                                               unsigned short* __restrict__ wv_b,
                                               unsigned short* __restrict__ wo_b) {
  int i = blockIdx.x * 256 + threadIdx.x;
  if (i < 2097152)       split1(hidden, hb_hi, hb_lo, i);
  else if (i < 6291456)  split1(wq, wq_hi, wq_lo, i - 2097152);
  else if (i < 7340032)  split1(wk, wk_hi, wk_lo, i - 6291456);
  else if (i < 8388608)  plain1(wv, wv_b, i - 7340032);
  else if (i < 12582912) plain1(wo, wo_b, i - 8388608);
}

// ---------------- RoPE angle table (staged in d_out; overwritten by final GEMM) ----------------
__global__ __launch_bounds__(256) void rope_table(float* __restrict__ ctab,
                                                  float* __restrict__ stab) {
  int idx = blockIdx.x * 256 + threadIdx.x;   // 2048*64
  if (idx >= 2048 * 64) return;
  int s = idx >> 6, d = idx & 63;
  float inv = powf(10000.0f, -(float)d * (1.0f / 64.0f));
  float ang = (float)s * inv;
  ctab[idx] = cosf(ang);
  stab[idx] = sinf(ang);
}

// ======== fused QKV projection GEMM + in-epilogue RoPE/split (128^2 tiles) ========
// A-pinned XCD mapping: each XCD x owns hidden m-panels {2x, 2x+1} (hi+lo = 4 MB, fits L2);
// Q/K/V blocks of that XCD all share this A set; weights stream through L3.
// bid [0,128): K-proj. bid [128,256): V-proj. bid [256,768): Q-proj.
__global__ __launch_bounds__(256) void qkv_gemm(const unsigned short* __restrict__ Ahg,
                                                const unsigned short* __restrict__ Alg,
                                                const unsigned short* __restrict__ wq_hi,
                                                const unsigned short* __restrict__ wq_lo,
                                                const unsigned short* __restrict__ wk_hi,
                                                const unsigned short* __restrict__ wk_lo,
                                                const unsigned short* __restrict__ wv_b,
                                                const float* __restrict__ ctab,
                                                const float* __restrict__ stab,
                                                unsigned short* __restrict__ Qh,
                                                unsigned short* __restrict__ Ql,
                                                unsigned short* __restrict__ K2h,
                                                unsigned short* __restrict__ K2l,
                                                unsigned short* __restrict__ V2) {
  __shared__ __align__(16) unsigned short shb[32768];   // 64 KB: staging, then fp32 C-tile
  const int bid = blockIdx.x;
  const int tid = threadIdx.x;
  const int w = tid >> 6, l = tid & 63;
  const int wm = w >> 1, wn = w & 1;
  const int lr = l & 15, lg = l >> 4;
  const int K = 4096;
  const int nt = K >> 5;   // 128

  if (bid >= 128 && bid < 256) {
    // ---------------- V-proj: 1-term bf16, V2 fragment-major store ----------------
    const int b3 = bid - 128;   // (bid&7)==(b3&7): 128%8==0
    const long m0 = (long)((b3 & 7) * 2 + ((b3 >> 3) & 1)) * 128;
    const long n0 = (long)(b3 >> 4) * 128;
    f32x4 acc[4][4] = {};
    const int c0 = w * 128 + l;
    const int c1 = c0 + 64;
    const unsigned short* gA0 = Ahg + (m0 + (c0 >> 2)) * K + (c0 & 3) * 8;
    const unsigned short* gA1 = Ahg + (m0 + (c1 >> 2)) * K + (c1 & 3) * 8;
    const unsigned short* gB0 = wv_b + (n0 + (c0 >> 2)) * K + (c0 & 3) * 8;
    const unsigned short* gB1 = wv_b + (n0 + (c1 >> 2)) * K + (c1 & 3) * 8;

#define STAGE1(t, b)                                         \
  {                                                          \
    long kt = (long)(t) * 32;                                \
    gload16(gA0 + kt, &shb[(b) * 4096 + w * 1024]);          \
    gload16(gA1 + kt, &shb[(b) * 4096 + w * 1024 + 512]);    \
    gload16(gB0 + kt, &shb[16384 + (b) * 4096 + w * 1024]);  \
    gload16(gB1 + kt, &shb[16384 + (b) * 4096 + w * 1024 + 512]); \
  }
    STAGE1(0, 0);
    STAGE1(1, 1);
    for (int t = 0; t < nt; ++t) {
      if (t + 1 < nt) asm volatile("s_waitcnt vmcnt(4)" ::: "memory");
      else            asm volatile("s_waitcnt vmcnt(0)" ::: "memory");
      __builtin_amdgcn_s_barrier();
      __builtin_amdgcn_sched_barrier(0);
      const int b = t & 1;
      bf16x8 af[4], bfr[4];
#pragma unroll
      for (int mi = 0; mi < 4; ++mi)
        af[mi] = *(const bf16x8*)&shb[b * 4096 + (wm * 64 + mi * 16 + lr) * 32 + lg * 8];
#pragma unroll
      for (int ni = 0; ni < 4; ++ni)
        bfr[ni] = *(const bf16x8*)&shb[16384 + b * 4096 + (wn * 64 + ni * 16 + lr) * 32 + lg * 8];
#pragma unroll
      for (int mi = 0; mi < 4; ++mi)
#pragma unroll
        for (int ni = 0; ni < 4; ++ni)
          acc[mi][ni] = __builtin_amdgcn_mfma_f32_16x16x32_bf16(af[mi], bfr[ni], acc[mi][ni], 0, 0, 0);
      __builtin_amdgcn_sched_barrier(0);
      __builtin_amdgcn_s_barrier();
      __builtin_amdgcn_sched_barrier(0);
      if (t + 2 < nt) STAGE1(t + 2, b);
    }
#undef STAGE1
#pragma unroll
    for (int mi = 0; mi < 4; ++mi)
#pragma unroll
      for (int ni = 0; ni < 4; ++ni)
#pragma unroll
        for (int j = 0; j < 4; ++j) {
          long r = m0 + wm * 64 + mi * 16 + lg * 4 + j;
          long cc = n0 + wn * 64 + ni * 16 + lr;
          int kvh = (int)(cc >> 7), d = (int)(cc & 127);
          int c = (int)(r >> 4), t2 = (int)(r & 15);
          long idx = ((long)(kvh * 128 + c) * 8 + (d >> 4)) * 256 + ((t2 >> 3) * 16 + (d & 15)) * 8 + (t2 & 7);
          V2[idx] = f2bf(acc[mi][ni][j]);
        }
    return;
  }

  // ---------------- Q-proj / K-proj: 3-term split GEMM + rope epilogue ----------------
  const unsigned short *Bh, *Bl;
  long m0, n0;
  bool isQ;
  if (bid < 128) {
    m0 = (long)((bid & 7) * 2 + ((bid >> 3) & 1)) * 128;   // A-pair pinned per XCD
    n0 = (long)(bid >> 4) * 128;
    Bh = wk_hi; Bl = wk_lo; isQ = false;
  } else {
    const int q = bid - 256;   // (bid&7)==(q&7): 256%8==0
    m0 = (long)((q & 7) * 2 + ((q >> 3) & 1)) * 128;       // same A-pair as K/V on this XCD
    n0 = (long)(q >> 4) * 128;
    Bh = wq_hi; Bl = wq_lo; isQ = true;
  }

  f32x4 acc[4][4] = {};
  const int c0 = w * 128 + l;
  const int c1 = c0 + 64;
  const long oA0 = (m0 + (c0 >> 2)) * K + (c0 & 3) * 8;
  const long oA1 = (m0 + (c1 >> 2)) * K + (c1 & 3) * 8;
  const long oB0 = (n0 + (c0 >> 2)) * K + (c0 & 3) * 8;
  const long oB1 = (n0 + (c1 >> 2)) * K + (c1 & 3) * 8;

#define STAGE3(t, b)                                               \
  {                                                                \
    long kt = (long)(t) * 32;                                      \
    gload16(Ahg + oA0 + kt, &shb[(b) * 4096 + w * 1024]);          \
    gload16(Ahg + oA1 + kt, &shb[(b) * 4096 + w * 1024 + 512]);    \
    gload16(Alg + oA0 + kt, &shb[8192 + (b) * 4096 + w * 1024]);   \
    gload16(Alg + oA1 + kt, &shb[8192 + (b) * 4096 + w * 1024 + 512]); \
    gload16(Bh + oB0 + kt, &shb[16384 + (b) * 4096 + w * 1024]);   \
    gload16(Bh + oB1 + kt, &shb[16384 + (b) * 4096 + w * 1024 + 512]); \
    gload16(Bl + oB0 + kt, &shb[24576 + (b) * 4096 + w * 1024]);   \
    gload16(Bl + oB1 + kt, &shb[24576 + (b) * 4096 + w * 1024 + 512]); \
  }
  STAGE3(0, 0);
  STAGE3(1, 1);
  for (int t = 0; t < nt; ++t) {
    if (t + 1 < nt) asm volatile("s_waitcnt vmcnt(8)" ::: "memory");
    else            asm volatile("s_waitcnt vmcnt(0)" ::: "memory");
    __builtin_amdgcn_s_barrier();
    __builtin_amdgcn_sched_barrier(0);
    const int b = t & 1;
    bf16x8 afh[4], afl[4], bfh[4], bfl[4];
#pragma unroll
    for (int mi = 0; mi < 4; ++mi) {
      afh[mi] = *(const bf16x8*)&shb[b * 4096 + (wm * 64 + mi * 16 + lr) * 32 + lg * 8];
      afl[mi] = *(const bf16x8*)&shb[8192 + b * 4096 + (wm * 64 + mi * 16 + lr) * 32 + lg * 8];
    }
#pragma unroll
    for (int ni = 0; ni < 4; ++ni) {
      bfh[ni] = *(const bf16x8*)&shb[16384 + b * 4096 + (wn * 64 + ni * 16 + lr) * 32 + lg * 8];
      bfl[ni] = *(const bf16x8*)&shb[24576 + b * 4096 + (wn * 64 + ni * 16 + lr) * 32 + lg * 8];
    }
#pragma unroll
    for (int mi = 0; mi < 4; ++mi)
#pragma unroll
      for (int ni = 0; ni < 4; ++ni) {
        acc[mi][ni] = __builtin_amdgcn_mfma_f32_16x16x32_bf16(afh[mi], bfh[ni], acc[mi][ni], 0, 0, 0);
        acc[mi][ni] = __builtin_amdgcn_mfma_f32_16x16x32_bf16(afl[mi], bfh[ni], acc[mi][ni], 0, 0, 0);
        acc[mi][ni] = __builtin_amdgcn_mfma_f32_16x16x32_bf16(afh[mi], bfl[ni], acc[mi][ni], 0, 0, 0);
      }
    __builtin_amdgcn_sched_barrier(0);
    __builtin_amdgcn_s_barrier();
    __builtin_amdgcn_sched_barrier(0);
    if (t + 2 < nt) STAGE3(t + 2, b);
  }
#undef STAGE3

  // ---- epilogue: C tile -> LDS fp32, then rope+split (bit-identical math) ----
  __syncthreads();
  float* Cls = (float*)shb;                    // 128 x 128 fp32 = 64 KB
#pragma unroll
  for (int mi = 0; mi < 4; ++mi)
#pragma unroll
    for (int ni = 0; ni < 4; ++ni)
#pragma unroll
      for (int j = 0; j < 4; ++j)
        Cls[(wm * 64 + mi * 16 + lg * 4 + j) * 128 + (wn * 64 + ni * 16 + lr)] = acc[mi][ni][j];
  __syncthreads();

  const int hqk = (int)(n0 >> 7);              // head (Q) or kv-head (K)
  const int r0l = tid >> 3;                    // 0..31
  const int d0 = (tid & 7) * 8;                // 0..56
  const float scale = isQ ? 0.08838834764831845f : 1.0f;
#pragma unroll
  for (int k = 0; k < 4; ++k) {
    const int r = r0l + 32 * k;
    const long s = m0 + r;
    float X1[8], X2[8], CC[8], SS[8];
    {
      f32x4 a = *(const f32x4*)&Cls[r * 128 + d0];
      f32x4 b = *(const f32x4*)&Cls[r * 128 + d0 + 4];
      f32x4 c = *(const f32x4*)&Cls[r * 128 + 64 + d0];
      f32x4 d = *(const f32x4*)&Cls[r * 128 + 64 + d0 + 4];
      f32x4 e = *(const f32x4*)&ctab[s * 64 + d0];
      f32x4 f = *(const f32x4*)&ctab[s * 64 + d0 + 4];
      f32x4 g = *(const f32x4*)&stab[s * 64 + d0];
      f32x4 h = *(const f32x4*)&stab[s * 64 + d0 + 4];
#pragma unroll
      for (int j = 0; j < 4; ++j) {
        X1[j] = a[j]; X1[j + 4] = b[j];
        X2[j] = c[j]; X2[j + 4] = d[j];
        CC[j] = e[j]; CC[j + 4] = f[j];
        SS[j] = g[j]; SS[j + 4] = h[j];
      }
    }
    us4 H1[2], L1[2], H2[2], L2[2];
#pragma unroll
    for (int j = 0; j < 8; ++j) {
      float y1 = (X1[j] * CC[j] - X2[j] * SS[j]) * scale;
      float y2 = (X2[j] * CC[j] + X1[j] * SS[j]) * scale;
      unsigned short h1 = f2bf(y1), h2 = f2bf(y2);
      H1[j >> 2][j & 3] = h1; L1[j >> 2][j & 3] = f2bf(y1 - bf2f(h1));
      H2[j >> 2][j & 3] = h2; L2[j >> 2][j & 3] = f2bf(y2 - bf2f(h2));
    }
    if (isQ) {
      long row = s * 4096 + hqk * 128;
      *(us4*)&Qh[row + d0] = H1[0];      *(us4*)&Qh[row + d0 + 4] = H1[1];
      *(us4*)&Ql[row + d0] = L1[0];      *(us4*)&Ql[row + d0 + 4] = L1[1];
      *(us4*)&Qh[row + 64 + d0] = H2[0]; *(us4*)&Qh[row + 64 + d0 + 4] = H2[1];
      *(us4*)&Ql[row + 64 + d0] = L2[0]; *(us4*)&Ql[row + 64 + d0 + 4] = L2[1];
    } else {
      long i1 = k2idx(hqk, (int)s, d0);
      long i2 = k2idx(hqk, (int)s, d0 + 64);
      *(us4*)&K2h[i1] = H1[0]; *(us4*)&K2h[i1 + 4] = H1[1];
      *(us4*)&K2l[i1] = L1[0]; *(us4*)&K2l[i1 + 4] = L1[1];
      *(us4*)&K2h[i2] = H2[0]; *(us4*)&K2h[i2 + 4] = H2[1];
      *(us4*)&K2l[i2] = L2[0]; *(us4*)&K2l[i2 + 4] = L2[1];
    }
  }
}

// ---------------- GEMM: C = A * B^T (O-proj), counted-vmcnt double-buffered ----------------
__global__ __launch_bounds__(256) void gemm_bt(const unsigned short* __restrict__ A,
                                               const unsigned short* __restrict__ B,
                                               float* __restrict__ C,
                                               int M, int N, int K) {
  __shared__ __align__(16) unsigned short As[2][4096];
  __shared__ __align__(16) unsigned short Bs[2][4096];
  const int tid = threadIdx.x;
  const int w = tid >> 6, l = tid & 63;
  const int wm = w >> 1, wn = w & 1;
  const int lr = l & 15, lg = l >> 4;
  const long m0 = (long)blockIdx.y * 128, n0 = (long)blockIdx.x * 128;

  f32x4 acc[4][4] = {};

  const int c0 = w * 128 + l;
  const int c1 = c0 + 64;
  const unsigned short* gA0 = A + (m0 + (c0 >> 2)) * K + (c0 & 3) * 8;
  const unsigned short* gA1 = A + (m0 + (c1 >> 2)) * K + (c1 & 3) * 8;
  const unsigned short* gB0 = B + (n0 + (c0 >> 2)) * K + (c0 & 3) * 8;
  const unsigned short* gB1 = B + (n0 + (c1 >> 2)) * K + (c1 & 3) * 8;

#define STAGE1(t, b)                                   \
  {                                                    \
    long kt = (long)(t) * 32;                          \
    gload16(gA0 + kt, &As[b][w * 1024]);               \
    gload16(gA1 + kt, &As[b][w * 1024 + 512]);         \
    gload16(gB0 + kt, &Bs[b][w * 1024]);               \
    gload16(gB1 + kt, &Bs[b][w * 1024 + 512]);         \
  }

  const int nt = K >> 5;
  STAGE1(0, 0);
  if (nt > 1) STAGE1(1, 1);

  for (int t = 0; t < nt; ++t) {
    if (t + 1 < nt) asm volatile("s_waitcnt vmcnt(4)" ::: "memory");
    else            asm volatile("s_waitcnt vmcnt(0)" ::: "memory");
    __builtin_amdgcn_s_barrier();
    __builtin_amdgcn_sched_barrier(0);
    const int b = t & 1;
    bf16x8 af[4], bfr[4];
#pragma unroll
    for (int mi = 0; mi < 4; ++mi)
      af[mi] = *(const bf16x8*)&As[b][(wm * 64 + mi * 16 + lr) * 32 + lg * 8];
#pragma unroll
    for (int ni = 0; ni < 4; ++ni)
      bfr[ni] = *(const bf16x8*)&Bs[b][(wn * 64 + ni * 16 + lr) * 32 + lg * 8];
#pragma unroll
    for (int mi = 0; mi < 4; ++mi)
#pragma unroll
      for (int ni = 0; ni < 4; ++ni)
        acc[mi][ni] = __builtin_amdgcn_mfma_f32_16x16x32_bf16(af[mi], bfr[ni], acc[mi][ni], 0, 0, 0);
    __builtin_amdgcn_sched_barrier(0);
    __builtin_amdgcn_s_barrier();
    __builtin_amdgcn_sched_barrier(0);
    if (t + 2 < nt) STAGE1(t + 2, b);
  }
#undef STAGE1

#pragma unroll
  for (int mi = 0; mi < 4; ++mi)
#pragma unroll
    for (int ni = 0; ni < 4; ++ni)
#pragma unroll
      for (int j = 0; j < 4; ++j) {
        long r = m0 + wm * 64 + mi * 16 + lg * 4 + j;
        long cc = n0 + wn * 64 + ni * 16 + lr;
        C[r * N + cc] = acc[mi][ni][j];
      }
}

// ======== K1: cmax GEMM, 4-deep counted-vmcnt pipeline. ========
__global__ __launch_bounds__(256, 2) void cmax_gemm(const unsigned short* __restrict__ Qh,
                                                    const unsigned short* __restrict__ Ql,
                                                    const unsigned short* __restrict__ K2h,
                                                    const unsigned short* __restrict__ K2l,
                                                    float* __restrict__ cmaxg) {
  __shared__ __align__(16) unsigned short Ksh[4][4096];  // 4 x 8KB hi (32-tok panel)
  __shared__ __align__(16) unsigned short Ksl[4][4096];  // 4 x 8KB lo
  const int qp = 15 - (int)blockIdx.x;                   // heavy panels first
  const int h = blockIdx.y;
  const int kvh = h >> 2;
  const int q0 = qp * 128;
  const int tid = threadIdx.x;
  const int w = tid >> 6, l = tid & 63;
  const int lr = l & 15, lg = l >> 4;
  const int npan = 4 * (qp + 1);
  const float NEGINF = -__builtin_inff();

  bf16x8 qfh[2][4], qfl[2][4];
#pragma unroll
  for (int rg = 0; rg < 2; ++rg) {
    const unsigned short* qph = Qh + (long)(q0 + w * 32 + rg * 16 + lr) * 4096 + h * 128 + lg * 8;
    const unsigned short* qpl = Ql + (long)(q0 + w * 32 + rg * 16 + lr) * 4096 + h * 128 + lg * 8;
#pragma unroll
    for (int ks = 0; ks < 4; ++ks) {
      qfh[rg][ks] = *(const bf16x8*)(qph + ks * 32);
      qfl[rg][ks] = *(const bf16x8*)(qpl + ks * 32);
    }
  }

  const unsigned short* kbh = K2h + (long)kvh * 128 * 2048;
  const unsigned short* kbl = K2l + (long)kvh * 128 * 2048;

#define STAGE(kp, b)                                                       \
  {                                                                        \
    long off = (long)(kp) * 4096;                                          \
    _Pragma("unroll")                                                      \
    for (int i = 0; i < 2; ++i) {                                          \
      int cu = w * 128 + i * 64;                                           \
      gload16(kbh + off + (cu + l) * 8, &Ksh[b][cu * 8]);                  \
      gload16(kbl + off + (cu + l) * 8, &Ksl[b][cu * 8]);                  \
    }                                                                      \
  }

  STAGE(0, 0);
  if (1 < npan) STAGE(1, 1);
  if (2 < npan) STAGE(2, 2);

  for (int kp = 0; kp < npan; ++kp) {
    {
      int ahead = npan - 1 - kp; if (ahead > 2) ahead = 2;
      int st = kp; if (st > 3) st = 3;
      int tgt = 4 * ahead + 4 * st;
      if (tgt >= 20)      asm volatile("s_waitcnt vmcnt(20)" ::: "memory");
      else if (tgt >= 16) asm volatile("s_waitcnt vmcnt(16)" ::: "memory");
      else if (tgt >= 12) asm volatile("s_waitcnt vmcnt(12)" ::: "memory");
      else if (tgt >= 8)  asm volatile("s_waitcnt vmcnt(8)" ::: "memory");
      else                asm volatile("s_waitcnt vmcnt(0)" ::: "memory");
    }
    __builtin_amdgcn_s_barrier();
    __builtin_amdgcn_sched_barrier(0);
    if (kp + 3 < npan) STAGE(kp + 3, (kp + 3) & 3);
    const int b = kp & 3;
#pragma unroll
    for (int c2 = 0; c2 < 2; ++c2) {
      const int ct = kp * 2 + c2;
      bf16x8 kh[4], kl2[4];
#pragma unroll
      for (int ks = 0; ks < 4; ++ks) {
        kh[ks]  = *(const bf16x8*)&Ksh[b][(c2 * 4 + ks) * 512 + l * 8];
        kl2[ks] = *(const bf16x8*)&Ksl[b][(c2 * 4 + ks) * 512 + l * 8];
      }
#pragma unroll
      for (int rg = 0; rg < 2; ++rg) {
        f32x4 acc = {};
#pragma unroll
        for (int ks = 0; ks < 4; ++ks) {
          acc = __builtin_amdgcn_mfma_f32_16x16x32_bf16(kh[ks], qfh[rg][ks], acc, 0, 0, 0);
          acc = __builtin_amdgcn_mfma_f32_16x16x32_bf16(kh[ks], qfl[rg][ks], acc, 0, 0, 0);
          acc = __builtin_amdgcn_mfma_f32_16x16x32_bf16(kl2[ks], qfh[rg][ks], acc, 0, 0, 0);
        }
        const int rbase = q0 + w * 32 + rg * 16;
        float m;
        if (ct * 16 + 15 <= rbase) {
          m = fmaxf(fmaxf(acc[0], acc[1]), fmaxf(acc[2], acc[3]));
        } else {
          m = NEGINF;
#pragma unroll
          for (int j = 0; j < 4; ++j) {
            int tok = ct * 16 + lg * 4 + j;
            if (tok <= rbase + lr) m = fmaxf(m, acc[j]);
          }
        }
        m = fmaxf(m, __shfl_xor(m, 16));
        m = fmaxf(m, __shfl_xor(m, 32));
        if (l < 16) cmaxg[(long)(h * 128 + ct) * 2048 + rbase + l] = m;
      }
    }
  }
#undef STAGE
}

// ======== K2: per-row top-8 selection. block = (64-row group, head). ========
__global__ __launch_bounds__(256) void select_kernel(const float* __restrict__ cmaxg,
                                                     u64* __restrict__ selEg,
                                                     u64* __restrict__ selOg,
                                                     float* __restrict__ mxg) {
  __shared__ float Lc[128 * 65];                  // [ct][row], padded
  const int r0 = (int)blockIdx.x * 64;
  const int h = blockIdx.y;
  const int tid = threadIdx.x;
  const int w = tid >> 6, l = tid & 63;
  const float NEGINF = -__builtin_inff();

  for (int i = tid; i < 128 * 16; i += 256) {
    int ct = i >> 4, rq = (i & 15) * 4;
    float4 v = *(const float4*)&cmaxg[(long)(h * 128 + ct) * 2048 + r0 + rq];
    Lc[ct * 65 + rq]     = v.x;
    Lc[ct * 65 + rq + 1] = v.y;
    Lc[ct * 65 + rq + 2] = v.z;
    Lc[ct * 65 + rq + 3] = v.w;
  }
  __syncthreads();

  const int c0 = 2 * l, c1 = 2 * l + 1;
#pragma unroll 1
  for (int rs = 0; rs < 16; ++rs) {
    const int rloc = w * 16 + rs;
    const int qr = r0 + rloc;
    const int nctr = (qr >> 4) + 1;
    float v0 = (c0 < nctr) ? Lc[c0 * 65 + rloc] : NEGINF;
    float v1 = (c1 < nctr) ? Lc[c1 * 65 + rloc] : NEGINF;
    const float o0 = v0, o1 = v1;
    float T = NEGINF;
    for (int it = 0; it < 8; ++it) {
      float m = fmaxf(v0, v1);
#pragma unroll
      for (int o = 1; o < 64; o <<= 1) m = fmaxf(m, __shfl_xor(m, o));
      u64 bal = __ballot((v0 == m) || (v1 == m));
      int first = __ffsll(bal) - 1;
      if (l == first) { if (v0 == m) v0 = NEGINF; else v1 = NEGINF; }
      T = m;
    }
    bool okc0 = (c0 < nctr) && ((c0 < 8) || (o0 >= T));
    bool okc1 = (c1 < nctr) && ((c1 < 8) || (o1 >= T));
    u64 bE = __ballot(okc0);
    u64 bO = __ballot(okc1);
    bool al0 = (c0 < nctr) && (okc0 || (c0 * 16 + 15 > qr - 128));
    bool al1 = (c1 < nctr) && (okc1 || (c1 * 16 + 15 > qr - 128));
    float mv = fmaxf(al0 ? o0 : NEGINF, al1 ? o1 : NEGINF);
#pragma unroll
    for (int o = 1; o < 64; o <<= 1) mv = fmaxf(mv, __shfl_xor(mv, o));
    if (l == 0) {
      selEg[h * 2048 + qr] = bE;
      selOg[h * 2048 + qr] = bO;
      mxg[h * 2048 + qr] = mv;
    }
  }
}

// ---------------- P LDS swizzled index (per-wave slice): row, tok32 ----------------
__device__ __forceinline__ int pidx2(int r, int t) {
  return r * 32 + ((((t >> 3) ^ (r & 3)) << 3) | (t & 7));
}

// ======== K3: phase B — recompute selected chunks, exp, PV; K prefetched 1 pair ahead. ========
__global__ __launch_bounds__(256) void attnB(const unsigned short* __restrict__ Qh,
                                             const unsigned short* __restrict__ K2h,
                                             const unsigned short* __restrict__ V2,
                                             const u64* __restrict__ selEg,
                                             const u64* __restrict__ selOg,
                                             const float* __restrict__ mxg,
                                             unsigned short* __restrict__ AO) {
  __shared__ __align__(16) unsigned short Pls[4][512];
  __shared__ int clistS[4][128];

  const int qb = (int)gridDim.x - 1 - (int)blockIdx.x;   // heavy blocks first
  const int kvh = blockIdx.y;
  const int q0 = qb * 16;
  const int nct = qb + 1;
  const int tid = threadIdx.x;
  const int w = tid >> 6, l = tid & 63;
  const int lr = l & 15, lg = l >> 4;
  const int h = kvh * 4 + w;

  bf16x8 qfh[4];
  {
    const unsigned short* qph = Qh + (long)(q0 + lr) * 4096 + h * 128 + lg * 8;
#pragma unroll
    for (int ks = 0; ks < 4; ++ks) qfh[ks] = *(const bf16x8*)(qph + ks * 32);
  }

  u64 myE = selEg[h * 2048 + q0 + lr];
  u64 myO = selOg[h * 2048 + q0 + lr];
  float mymx = mxg[h * 2048 + q0 + lr];

  u64 uE = myE, uO = myO;
#pragma unroll
  for (int o = 1; o < 16; o <<= 1) {
    uE |= __shfl_xor(uE, o);
    uO |= __shfl_xor(uO, o);
  }
  float mxj[4];
  u64 selE[4], selO[4];
#pragma unroll
  for (int j = 0; j < 4; ++j) {
    mxj[j] = __shfl(mymx, lg * 4 + j);
    selE[j] = __shfl(myE, lg * 4 + j);
    selO[j] = __shfl(myO, lg * 4 + j);
  }

  unsigned short* Pw = Pls[w];
  int* cl = clistS[w];

  const int c0 = 2 * l, c1 = 2 * l + 1;
  bool s0ok = (c0 < nct) && (((uE >> l) & 1ull) || (c0 >= qb - 7));
  bool s1ok = (c1 < nct) && (((uO >> l) & 1ull) || (c1 >= qb - 7));
  u64 bA = __ballot(s0ok);
  u64 bB = __ballot(s1ok);
  const int cntA = __popcll(bA);
  const int nsel = cntA + __popcll(bB);
  if (s0ok) cl[__popcll(bA & ((1ull << l) - 1ull))] = c0;
  if (s1ok) cl[cntA + __popcll(bB & ((1ull << l) - 1ull))] = c1;

  const unsigned short* kbh = K2h + (long)kvh * 128 * 2048;

  f32x4 pacc[8] = {};
  float psum[4] = {0.f, 0.f, 0.f, 0.f};
  const int np = (nsel + 1) >> 1;

  bf16x8 kA[4], kB[4];
  {
    const int cA0 = cl[0];
    const int cB0 = (1 < nsel) ? cl[1] : cA0;
    const unsigned short* pA = kbh + (long)cA0 * 2048 + l * 8;
    const unsigned short* pB = kbh + (long)cB0 * 2048 + l * 8;
#pragma unroll
    for (int ks = 0; ks < 4; ++ks) {
      kA[ks] = *(const bf16x8*)(pA + ks * 512);
      kB[ks] = *(const bf16x8*)(pB + ks * 512);
    }
  }

  for (int pi = 0; pi < np; ++pi) {
    const int cA = cl[2 * pi];
    const int iB = 2 * pi + 1;
    const int cB = (iB < nsel) ? cl[iB] : cA;

    const int csel = (lg < 2) ? cA : cB;
    const unsigned short* vp = V2 + (long)(kvh * 128 + csel) * 2048 + ((lg & 1) * 16 + lr) * 8;
    bf16x8 vf[8];
#pragma unroll
    for (int dblk = 0; dblk < 8; ++dblk) vf[dblk] = *(const bf16x8*)(vp + dblk * 256);

    bf16x8 nA[4], nB[4];
    {
      const int pin = (pi + 1 < np) ? pi + 1 : pi;
      const int cA1 = cl[2 * pin];
      const int iB1 = 2 * pin + 1;
      const int cB1 = (iB1 < nsel) ? cl[iB1] : cA1;
      const unsigned short* pA = kbh + (long)cA1 * 2048 + l * 8;
      const unsigned short* pB = kbh + (long)cB1 * 2048 + l * 8;
#pragma unroll
      for (int ks = 0; ks < 4; ++ks) {
        nA[ks] = *(const bf16x8*)(pA + ks * 512);
        nB[ks] = *(const bf16x8*)(pB + ks * 512);
      }
    }

#pragma unroll
    for (int half = 0; half < 2; ++half) {
      const int c = half ? cB : cA;
      const bool vslot = (2 * pi + half) < nsel;
      f32x4 acc = {};
#pragma unroll
      for (int ks = 0; ks < 4; ++ks) {
        bf16x8 kf = half ? kB[ks] : kA[ks];
        acc = __builtin_amdgcn_mfma_f32_16x16x32_bf16(qfh[ks], kf, acc, 0, 0, 0);
      }
#pragma unroll
      for (int j = 0; j < 4; ++j) {
        const int r = lg * 4 + j;
        const int qrr = q0 + r;
        const int tok = c * 16 + lr;
        u64 sm = (c & 1) ? selO[j] : selE[j];
        bool sel = (sm >> (c >> 1)) & 1ull;
        bool al = vslot && (tok <= qrr) && (sel || (tok > qrr - 128));
        float p = al ? __expf(acc[j] - mxj[j]) : 0.f;
        unsigned short pb = f2bf(p);
        psum[j] += bf2f(pb);
        Pw[pidx2(r, half * 16 + lr)] = pb;
      }
    }
    bf16x8 pa = *(const bf16x8*)&Pw[pidx2(lr, lg * 8)];
#pragma unroll
    for (int dblk = 0; dblk < 8; ++dblk)
      pacc[dblk] = __builtin_amdgcn_mfma_f32_16x16x32_bf16(pa, vf[dblk], pacc[dblk], 0, 0, 0);

#pragma unroll
    for (int ks = 0; ks < 4; ++ks) { kA[ks] = nA[ks]; kB[ks] = nB[ks]; }
  }

#pragma unroll
  for (int j = 0; j < 4; ++j) {
    float s = psum[j];
    s += __shfl_xor(s, 1); s += __shfl_xor(s, 2);
    s += __shfl_xor(s, 4); s += __shfl_xor(s, 8);
    const float rd = 1.0f / s;
    const int r = lg * 4 + j;
#pragma unroll
    for (int dblk = 0; dblk < 8; ++dblk)
      AO[(long)(q0 + r) * 4096 + h * 128 + dblk * 16 + lr] = f2bf(pacc[dblk][j] * rd);
  }
}

// ---------------- launch ----------------
extern "C" void kernel_launch(void* const* d_in, const int* in_sizes, int n_in,
                              void* d_out, int out_size, void* d_ws, size_t ws_size,
                              hipStream_t stream) {
  const float* hidden = (const float*)d_in[0];
  const float* wq = (const float*)d_in[1];
  const float* wk = (const float*)d_in[2];
  const float* wv = (const float*)d_in[3];
  const float* wo = (const float*)d_in[4];
  float* out = (float*)d_out;

  unsigned short* hb_hi = (unsigned short*)d_ws;          // [2048][4096]
  unsigned short* hb_lo = hb_hi + (size_t)2048 * 4096;
  unsigned short* wq_hi = hb_lo + (size_t)2048 * 4096;    // [4096][4096]
  unsigned short* wq_lo = wq_hi + (size_t)4096 * 4096;
  unsigned short* wk_hi = wq_lo + (size_t)4096 * 4096;    // [1024][4096]
  unsigned short* wk_lo = wk_hi + (size_t)1024 * 4096;
  unsigned short* wv_b  = wk_lo + (size_t)1024 * 4096;    // [1024][4096]
  unsigned short* wo_b  = wv_b  + (size_t)1024 * 4096;    // [4096][4096]
  // dedicated qkv outputs (no aliasing with weights read by other blocks)
  unsigned short* Qhi = wo_b + (size_t)4096 * 4096;       // [2048][4096] bf16
  unsigned short* Qlo = Qhi + (size_t)2048 * 4096;
  unsigned short* K2h = Qlo + (size_t)2048 * 4096;        // frag-major, 2M elems
  unsigned short* K2l = K2h + (size_t)2048 * 1024;
  unsigned short* V2  = K2l + (size_t)2048 * 1024;        // frag-major, 2M elems
  // aliases (stream-ordered lifetimes):
  unsigned short* AO = hb_hi;         // hidden splits dead after QKV GEMM
  float* cmaxg = (float*)wq_hi;       // wq splits dead after QKV GEMM (33.5 MB <= 64 MB)
  u64* selEg = (u64*)wk_hi;           // wk splits dead after QKV GEMM
  u64* selOg = selEg + 32 * 2048;
  float* mxg = (float*)(selOg + 32 * 2048);
  float* ctab = out;                  // staged in d_out; fully overwritten by final GEMM
  float* stab = ctab + 2048 * 64;

  cvt_all<<<49152, 256, 0, stream>>>(hidden, wq, wk, wv, wo,
                                     hb_hi, hb_lo, wq_hi, wq_lo,
                                     wk_hi, wk_lo, wv_b, wo_b);
  rope_table<<<512, 256, 0, stream>>>(ctab, stab);

  qkv_gemm<<<768, 256, 0, stream>>>(hb_hi, hb_lo, wq_hi, wq_lo,
                                    wk_hi, wk_lo, wv_b, ctab, stab,
                                    Qhi, Qlo, K2h, K2l, V2);

  cmax_gemm<<<dim3(16, 32), 256, 0, stream>>>(Qhi, Qlo, K2h, K2l, cmaxg);
  select_kernel<<<dim3(32, 32), 256, 0, stream>>>(cmaxg, selEg, selOg, mxg);
  attnB<<<dim3(128, 8), 256, 0, stream>>>(Qhi, K2h, V2, selEg, selOg, mxg, AO);

  gemm_bt<<<dim3(32, 16), 256, 0, stream>>>(AO, wo_b, out, 2048, 4096, 4096);
}

// Round 13
// 681.046 us; speedup vs baseline: 1.0604x; 1.0216x over previous
//
#include <hip/hip_runtime.h>
#include <math.h>

typedef __attribute__((ext_vector_type(4))) float f32x4;
typedef __attribute__((ext_vector_type(8))) __bf16 bf16x8;
typedef __attribute__((ext_vector_type(4))) unsigned short us4;
typedef unsigned long long u64;

__device__ __forceinline__ unsigned short f2bf(float f) {
  unsigned int u = __float_as_uint(f);
  u += 0x7fffu + ((u >> 16) & 1u);            // RNE
  return (unsigned short)(u >> 16);
}
__device__ __forceinline__ float bf2f(unsigned short h) {
  return __uint_as_float(((unsigned int)h) << 16);
}

__device__ __forceinline__ void gload16(const void* g, void* l) {
  __builtin_amdgcn_global_load_lds(
      (__attribute__((address_space(1))) void*)g,
      (__attribute__((address_space(3))) void*)l, 16, 0, 0);
}

// ---------------- K2 fragment-major index: K element (s, kvh, d) ----------------
__device__ __forceinline__ long k2idx(int kvh, int s, int d) {
  int ct = s >> 4;
  int lane = (((d & 31) >> 3) << 4) | (s & 15);
  return ((long)(kvh * 128 + ct) * 4 + (d >> 5)) * 512 + lane * 8 + (d & 7);
}

// ---------------- fused fp32 -> bf16 conversions ----------------
__device__ __forceinline__ void split1(const float* __restrict__ in,
                                       unsigned short* __restrict__ hi,
                                       unsigned short* __restrict__ lo, int i) {
  float4 v = ((const float4*)in)[i];
  us4 h, l;
  float vv[4] = {v.x, v.y, v.z, v.w};
#pragma unroll
  for (int j = 0; j < 4; ++j) {
    unsigned short hh = f2bf(vv[j]);
    h[j] = hh;
    l[j] = f2bf(vv[j] - bf2f(hh));
  }
  ((us4*)hi)[i] = h;
  ((us4*)lo)[i] = l;
}
__device__ __forceinline__ void plain1(const float* __restrict__ in,
                                       unsigned short* __restrict__ out, int i) {
  float4 v = ((const float4*)in)[i];
  us4 o;
  o[0] = f2bf(v.x); o[1] = f2bf(v.y); o[2] = f2bf(v.z); o[3] = f2bf(v.w);
  ((us4*)out)[i] = o;
}

__global__ __launch_bounds__(256) void cvt_all(const float* __restrict__ hidden,
                                               const float* __restrict__ wq,
                                               const float* __restrict__ wk,
                                               const float* __restrict__ wv,
                                               const float* __restrict__ wo,
                                               unsigned short* __restrict__ hb_hi,
                                               unsigned short* __restrict__ hb_lo,
                                               unsigned short* __restrict__ wq_hi,
                                               unsigned short* __restrict__ wq_lo,
                                               unsigned short* __restrict__ wk_hi,
                                               unsigned short* __restrict__ wk_lo,
                                               unsigned short* __restrict__ wv_b,
                                               unsigned short* __restrict__ wo_b) {
  int i = blockIdx.x * 256 + threadIdx.x;
  if (i < 2097152)       split1(hidden, hb_hi, hb_lo, i);
  else if (i < 6291456)  split1(wq, wq_hi, wq_lo, i - 2097152);
  else if (i < 7340032)  split1(wk, wk_hi, wk_lo, i - 6291456);
  else if (i < 8388608)  plain1(wv, wv_b, i - 7340032);
  else if (i < 12582912) plain1(wo, wo_b, i - 8388608);
}

// ---------------- RoPE angle table (staged in d_out; overwritten by final GEMM) ----------------
__global__ __launch_bounds__(256) void rope_table(float* __restrict__ ctab,
                                                  float* __restrict__ stab) {
  int idx = blockIdx.x * 256 + threadIdx.x;   // 2048*64
  if (idx >= 2048 * 64) return;
  int s = idx >> 6, d = idx & 63;
  float inv = powf(10000.0f, -(float)d * (1.0f / 64.0f));
  float ang = (float)s * inv;
  ctab[idx] = cosf(ang);
  stab[idx] = sinf(ang);
}

// ======== Q-proj: 8-phase counted-vmcnt 3-term GEMM + rope epilogue ========
// 256 blocks x 512 thr (8 waves 2x4). Tile 128x256, BK=32, triple-buffered LDS (144 KB).
// Per K-tile: 4 phases {ds_read frag || stage 2 gloads of t+2 -> barrier -> lgkmcnt(0)
// -> setprio(1) -> 12 MFMA -> setprio(0) -> barrier}; vmcnt(6) at phase 3 (never 0 till tail).
// LDS k-slot swizzle kc^(row&3)^((row>>2)&3) applied to src AND read (bank-conflict-free, data identical).
__global__ __launch_bounds__(512, 2) void q8ph(const unsigned short* __restrict__ Ahg,
                                               const unsigned short* __restrict__ Alg,
                                               const unsigned short* __restrict__ wq_hi,
                                               const unsigned short* __restrict__ wq_lo,
                                               const float* __restrict__ ctab,
                                               const float* __restrict__ stab,
                                               unsigned short* __restrict__ Qh,
                                               unsigned short* __restrict__ Ql) {
  __shared__ __align__(16) unsigned short shb[73728];   // 144 KB
  const int bid = blockIdx.x;
  const int tid = threadIdx.x;
  const int w = tid >> 6, l = tid & 63;
  const int lr = l & 15, lg = l >> 4;
  const int wr = w >> 2, wc = w & 3;
  const int nt = 128;

  const int m_idx = (bid & 7) * 2 + ((bid >> 3) & 1);   // A-pair pinned per XCD
  const int n_idx = bid >> 4;
  const long m0 = (long)m_idx * 128;
  const long n0 = (long)n_idx * 256;

  // staging addresses (per-lane global src with swizzled k-chunk; wave-uniform LDS dst)
  const int arow = tid >> 2;
  const int kg = ((tid & 3) ^ ((tid >> 2) & 3) ^ ((tid >> 4) & 3)) & 3;
  const long aoff  = (m0 + arow) * 4096 + kg * 8;
  const long boff0 = (n0 + arow) * 4096 + kg * 8;
  const long boff1 = (n0 + 128 + arow) * 4096 + kg * 8;
  const int dstw = w * 512;                              // ushort idx; lane adds 16B

  // ds_read k-slot swizzle (per-lane constant)
  const int xk = (lg ^ (lr & 3) ^ ((lr >> 2) & 3)) & 3;

  // LDS map (ushort idx): Ah @ bs*4096, Al @ 12288+bs*4096, Bh @ 24576+bs*8192, Bl @ 49152+bs*8192
#define QSTG_A(t, bs)                                                         \
  { gload16(Ahg + aoff + (long)(t) * 32, &shb[(bs) * 4096 + dstw]);           \
    gload16(Alg + aoff + (long)(t) * 32, &shb[12288 + (bs) * 4096 + dstw]); }
#define QSTG_BH(t, bs)                                                        \
  { gload16(wq_hi + boff0 + (long)(t) * 32, &shb[24576 + (bs) * 8192 + dstw]);\
    gload16(wq_hi + boff1 + (long)(t) * 32, &shb[24576 + (bs) * 8192 + 4096 + dstw]); }
#define QSTG_BL(t, bs)                                                        \
  { gload16(wq_lo + boff0 + (long)(t) * 32, &shb[49152 + (bs) * 8192 + dstw]);\
    gload16(wq_lo + boff1 + (long)(t) * 32, &shb[49152 + (bs) * 8192 + 4096 + dstw]); }

  f32x4 acc[4][4] = {};

  QSTG_A(0, 0); QSTG_BH(0, 0); QSTG_BL(0, 0);
  QSTG_A(1, 1); QSTG_BH(1, 1); QSTG_BL(1, 1);
  QSTG_A(2, 2); QSTG_BH(2, 2); QSTG_BL(2, 2);
  asm volatile("s_waitcnt vmcnt(12)" ::: "memory");      // tile 0 ready; 1,2 in flight
  __builtin_amdgcn_s_barrier();
  __builtin_amdgcn_sched_barrier(0);

#define QPH_ENTER                                        \
  __builtin_amdgcn_sched_barrier(0);                     \
  __builtin_amdgcn_s_barrier();                          \
  asm volatile("s_waitcnt lgkmcnt(0)" ::: "memory");     \
  __builtin_amdgcn_sched_barrier(0);                     \
  __builtin_amdgcn_s_setprio(1);
#define QPH_EXIT                                         \
  __builtin_amdgcn_s_setprio(0);                         \
  __builtin_amdgcn_sched_barrier(0);                     \
  __builtin_amdgcn_s_barrier();                          \
  __builtin_amdgcn_sched_barrier(0);
#define QPH_MFMA(p)                                                                            \
  _Pragma("unroll")                                                                            \
  for (int mi = 0; mi < 4; ++mi) {                                                             \
    acc[mi][p] = __builtin_amdgcn_mfma_f32_16x16x32_bf16(afh[mi], bfh, acc[mi][p], 0, 0, 0);   \
    acc[mi][p] = __builtin_amdgcn_mfma_f32_16x16x32_bf16(afl[mi], bfh, acc[mi][p], 0, 0, 0);   \
    acc[mi][p] = __builtin_amdgcn_mfma_f32_16x16x32_bf16(afh[mi], bfl, acc[mi][p], 0, 0, 0);   \
  }
#define QPH_RDB(p)                                                                  \
  { int rowb = wc * 64 + (p) * 16 + lr;                                             \
    bfh = *(const bf16x8*)&shb[24576 + bs * 8192 + rowb * 32 + xk * 8];             \
    bfl = *(const bf16x8*)&shb[49152 + bs * 8192 + rowb * 32 + xk * 8]; }

  for (int t = 0; t < nt; ++t) {
    const int bs = t % 3;
    const int bss = (t + 2) % 3;
    const bool st = (t + 2) < nt;
    bf16x8 afh[4], afl[4], bfh, bfl;
    // ---- phase 0: A frags + B(ni=0); stage A of t+2 ----
#pragma unroll
    for (int mi = 0; mi < 4; ++mi) {
      int rowa = wr * 64 + mi * 16 + lr;
      afh[mi] = *(const bf16x8*)&shb[bs * 4096 + rowa * 32 + xk * 8];
      afl[mi] = *(const bf16x8*)&shb[12288 + bs * 4096 + rowa * 32 + xk * 8];
    }
    QPH_RDB(0);
    if (st) QSTG_A(t + 2, bss);
    QPH_ENTER; QPH_MFMA(0); QPH_EXIT;
    // ---- phase 1: B(ni=1); stage Bh of t+2 ----
    QPH_RDB(1);
    if (st) QSTG_BH(t + 2, bss);
    QPH_ENTER; QPH_MFMA(1); QPH_EXIT;
    // ---- phase 2: B(ni=2); stage Bl of t+2 ----
    QPH_RDB(2);
    if (st) QSTG_BL(t + 2, bss);
    QPH_ENTER; QPH_MFMA(2); QPH_EXIT;
    // ---- phase 3: B(ni=3); counted vmcnt (next tile ready after barrier) ----
    QPH_RDB(3);
    if (st) asm volatile("s_waitcnt vmcnt(6)" ::: "memory");
    else    asm volatile("s_waitcnt vmcnt(0)" ::: "memory");
    QPH_ENTER; QPH_MFMA(3); QPH_EXIT;
  }
#undef QSTG_A
#undef QSTG_BH
#undef QSTG_BL
#undef QPH_ENTER
#undef QPH_EXIT
#undef QPH_MFMA
#undef QPH_RDB

  // ---- epilogue: C (128x256 fp32) -> LDS, rope+split (math identical to round 12) ----
  __syncthreads();
  float* Cls = (float*)shb;                              // 128x256 fp32 = 128 KB
#pragma unroll
  for (int mi = 0; mi < 4; ++mi)
#pragma unroll
    for (int ni = 0; ni < 4; ++ni)
#pragma unroll
      for (int j = 0; j < 4; ++j)
        Cls[(wr * 64 + mi * 16 + lg * 4 + j) * 256 + wc * 64 + ni * 16 + lr] = acc[mi][ni][j];
  __syncthreads();

  const int r0l = tid >> 3;                              // 0..63
  const int d0 = (tid & 7) * 8;                          // 0..56
#pragma unroll
  for (int h = 0; h < 2; ++h) {
    const int head = n_idx * 2 + h;
#pragma unroll
    for (int k = 0; k < 2; ++k) {
      const int r = r0l + 64 * k;
      const long s = m0 + r;
      float X1[8], X2[8], CC[8], SS[8];
      {
        f32x4 a = *(const f32x4*)&Cls[r * 256 + h * 128 + d0];
        f32x4 b = *(const f32x4*)&Cls[r * 256 + h * 128 + d0 + 4];
        f32x4 c = *(const f32x4*)&Cls[r * 256 + h * 128 + 64 + d0];
        f32x4 d = *(const f32x4*)&Cls[r * 256 + h * 128 + 64 + d0 + 4];
        f32x4 e = *(const f32x4*)&ctab[s * 64 + d0];
        f32x4 f = *(const f32x4*)&ctab[s * 64 + d0 + 4];
        f32x4 g = *(const f32x4*)&stab[s * 64 + d0];
        f32x4 hh = *(const f32x4*)&stab[s * 64 + d0 + 4];
#pragma unroll
        for (int j = 0; j < 4; ++j) {
          X1[j] = a[j]; X1[j + 4] = b[j];
          X2[j] = c[j]; X2[j + 4] = d[j];
          CC[j] = e[j]; CC[j + 4] = f[j];
          SS[j] = g[j]; SS[j + 4] = hh[j];
        }
      }
      us4 H1[2], L1[2], H2[2], L2[2];
#pragma unroll
      for (int j = 0; j < 8; ++j) {
        float y1 = (X1[j] * CC[j] - X2[j] * SS[j]) * 0.08838834764831845f;
        float y2 = (X2[j] * CC[j] + X1[j] * SS[j]) * 0.08838834764831845f;
        unsigned short h1 = f2bf(y1), h2 = f2bf(y2);
        H1[j >> 2][j & 3] = h1; L1[j >> 2][j & 3] = f2bf(y1 - bf2f(h1));
        H2[j >> 2][j & 3] = h2; L2[j >> 2][j & 3] = f2bf(y2 - bf2f(h2));
      }
      long row = s * 4096 + head * 128;
      *(us4*)&Qh[row + d0] = H1[0];      *(us4*)&Qh[row + d0 + 4] = H1[1];
      *(us4*)&Ql[row + d0] = L1[0];      *(us4*)&Ql[row + d0 + 4] = L1[1];
      *(us4*)&Qh[row + 64 + d0] = H2[0]; *(us4*)&Qh[row + 64 + d0 + 4] = H2[1];
      *(us4*)&Ql[row + 64 + d0] = L2[0]; *(us4*)&Ql[row + 64 + d0 + 4] = L2[1];
    }
  }
}

// ======== K/V projection (round-12 qkv_gemm, Q branch unreachable at grid 256) ========
__global__ __launch_bounds__(256) void qkv_gemm(const unsigned short* __restrict__ Ahg,
                                                const unsigned short* __restrict__ Alg,
                                                const unsigned short* __restrict__ wk_hi,
                                                const unsigned short* __restrict__ wk_lo,
                                                const unsigned short* __restrict__ wv_b,
                                                const float* __restrict__ ctab,
                                                const float* __restrict__ stab,
                                                unsigned short* __restrict__ K2h,
                                                unsigned short* __restrict__ K2l,
                                                unsigned short* __restrict__ V2) {
  __shared__ __align__(16) unsigned short shb[32768];   // 64 KB
  const int bid = blockIdx.x;
  const int tid = threadIdx.x;
  const int w = tid >> 6, l = tid & 63;
  const int wm = w >> 1, wn = w & 1;
  const int lr = l & 15, lg = l >> 4;
  const int K = 4096;
  const int nt = K >> 5;

  if (bid >= 128) {
    // ---------------- V-proj: 1-term bf16, V2 fragment-major store ----------------
    const int b3 = bid - 128;
    const long m0 = (long)((b3 & 7) * 2 + ((b3 >> 3) & 1)) * 128;
    const long n0 = (long)(b3 >> 4) * 128;
    f32x4 acc[4][4] = {};
    const int c0 = w * 128 + l;
    const int c1 = c0 + 64;
    const unsigned short* gA0 = Ahg + (m0 + (c0 >> 2)) * K + (c0 & 3) * 8;
    const unsigned short* gA1 = Ahg + (m0 + (c1 >> 2)) * K + (c1 & 3) * 8;
    const unsigned short* gB0 = wv_b + (n0 + (c0 >> 2)) * K + (c0 & 3) * 8;
    const unsigned short* gB1 = wv_b + (n0 + (c1 >> 2)) * K + (c1 & 3) * 8;

#define STAGE1(t, b)                                         \
  {                                                          \
    long kt = (long)(t) * 32;                                \
    gload16(gA0 + kt, &shb[(b) * 4096 + w * 1024]);          \
    gload16(gA1 + kt, &shb[(b) * 4096 + w * 1024 + 512]);    \
    gload16(gB0 + kt, &shb[16384 + (b) * 4096 + w * 1024]);  \
    gload16(gB1 + kt, &shb[16384 + (b) * 4096 + w * 1024 + 512]); \
  }
    STAGE1(0, 0);
    STAGE1(1, 1);
    for (int t = 0; t < nt; ++t) {
      if (t + 1 < nt) asm volatile("s_waitcnt vmcnt(4)" ::: "memory");
      else            asm volatile("s_waitcnt vmcnt(0)" ::: "memory");
      __builtin_amdgcn_s_barrier();
      __builtin_amdgcn_sched_barrier(0);
      const int b = t & 1;
      bf16x8 af[4], bfr[4];
#pragma unroll
      for (int mi = 0; mi < 4; ++mi)
        af[mi] = *(const bf16x8*)&shb[b * 4096 + (wm * 64 + mi * 16 + lr) * 32 + lg * 8];
#pragma unroll
      for (int ni = 0; ni < 4; ++ni)
        bfr[ni] = *(const bf16x8*)&shb[16384 + b * 4096 + (wn * 64 + ni * 16 + lr) * 32 + lg * 8];
#pragma unroll
      for (int mi = 0; mi < 4; ++mi)
#pragma unroll
        for (int ni = 0; ni < 4; ++ni)
          acc[mi][ni] = __builtin_amdgcn_mfma_f32_16x16x32_bf16(af[mi], bfr[ni], acc[mi][ni], 0, 0, 0);
      __builtin_amdgcn_sched_barrier(0);
      __builtin_amdgcn_s_barrier();
      __builtin_amdgcn_sched_barrier(0);
      if (t + 2 < nt) STAGE1(t + 2, b);
    }
#undef STAGE1
#pragma unroll
    for (int mi = 0; mi < 4; ++mi)
#pragma unroll
      for (int ni = 0; ni < 4; ++ni)
#pragma unroll
        for (int j = 0; j < 4; ++j) {
          long r = m0 + wm * 64 + mi * 16 + lg * 4 + j;
          long cc = n0 + wn * 64 + ni * 16 + lr;
          int kvh = (int)(cc >> 7), d = (int)(cc & 127);
          int c = (int)(r >> 4), t2 = (int)(r & 15);
          long idx = ((long)(kvh * 128 + c) * 8 + (d >> 4)) * 256 + ((t2 >> 3) * 16 + (d & 15)) * 8 + (t2 & 7);
          V2[idx] = f2bf(acc[mi][ni][j]);
        }
    return;
  }

  // ---------------- K-proj: 3-term split GEMM + rope epilogue ----------------
  const long m0 = (long)((bid & 7) * 2 + ((bid >> 3) & 1)) * 128;
  const long n0 = (long)(bid >> 4) * 128;

  f32x4 acc[4][4] = {};
  const int c0 = w * 128 + l;
  const int c1 = c0 + 64;
  const long oA0 = (m0 + (c0 >> 2)) * K + (c0 & 3) * 8;
  const long oA1 = (m0 + (c1 >> 2)) * K + (c1 & 3) * 8;
  const long oB0 = (n0 + (c0 >> 2)) * K + (c0 & 3) * 8;
  const long oB1 = (n0 + (c1 >> 2)) * K + (c1 & 3) * 8;

#define STAGE3(t, b)                                               \
  {                                                                \
    long kt = (long)(t) * 32;                                      \
    gload16(Ahg + oA0 + kt, &shb[(b) * 4096 + w * 1024]);          \
    gload16(Ahg + oA1 + kt, &shb[(b) * 4096 + w * 1024 + 512]);    \
    gload16(Alg + oA0 + kt, &shb[8192 + (b) * 4096 + w * 1024]);   \
    gload16(Alg + oA1 + kt, &shb[8192 + (b) * 4096 + w * 1024 + 512]); \
    gload16(wk_hi + oB0 + kt, &shb[16384 + (b) * 4096 + w * 1024]);   \
    gload16(wk_hi + oB1 + kt, &shb[16384 + (b) * 4096 + w * 1024 + 512]); \
    gload16(wk_lo + oB0 + kt, &shb[24576 + (b) * 4096 + w * 1024]);   \
    gload16(wk_lo + oB1 + kt, &shb[24576 + (b) * 4096 + w * 1024 + 512]); \
  }
  STAGE3(0, 0);
  STAGE3(1, 1);
  for (int t = 0; t < nt; ++t) {
    if (t + 1 < nt) asm volatile("s_waitcnt vmcnt(8)" ::: "memory");
    else            asm volatile("s_waitcnt vmcnt(0)" ::: "memory");
    __builtin_amdgcn_s_barrier();
    __builtin_amdgcn_sched_barrier(0);
    const int b = t & 1;
    bf16x8 afh[4], afl[4], bfh[4], bfl[4];
#pragma unroll
    for (int mi = 0; mi < 4; ++mi) {
      afh[mi] = *(const bf16x8*)&shb[b * 4096 + (wm * 64 + mi * 16 + lr) * 32 + lg * 8];
      afl[mi] = *(const bf16x8*)&shb[8192 + b * 4096 + (wm * 64 + mi * 16 + lr) * 32 + lg * 8];
    }
#pragma unroll
    for (int ni = 0; ni < 4; ++ni) {
      bfh[ni] = *(const bf16x8*)&shb[16384 + b * 4096 + (wn * 64 + ni * 16 + lr) * 32 + lg * 8];
      bfl[ni] = *(const bf16x8*)&shb[24576 + b * 4096 + (wn * 64 + ni * 16 + lr) * 32 + lg * 8];
    }
#pragma unroll
    for (int mi = 0; mi < 4; ++mi)
#pragma unroll
      for (int ni = 0; ni < 4; ++ni) {
        acc[mi][ni] = __builtin_amdgcn_mfma_f32_16x16x32_bf16(afh[mi], bfh[ni], acc[mi][ni], 0, 0, 0);
        acc[mi][ni] = __builtin_amdgcn_mfma_f32_16x16x32_bf16(afl[mi], bfh[ni], acc[mi][ni], 0, 0, 0);
        acc[mi][ni] = __builtin_amdgcn_mfma_f32_16x16x32_bf16(afh[mi], bfl[ni], acc[mi][ni], 0, 0, 0);
      }
    __builtin_amdgcn_sched_barrier(0);
    __builtin_amdgcn_s_barrier();
    __builtin_amdgcn_sched_barrier(0);
    if (t + 2 < nt) STAGE3(t + 2, b);
  }
#undef STAGE3

  __syncthreads();
  float* Cls = (float*)shb;
#pragma unroll
  for (int mi = 0; mi < 4; ++mi)
#pragma unroll
    for (int ni = 0; ni < 4; ++ni)
#pragma unroll
      for (int j = 0; j < 4; ++j)
        Cls[(wm * 64 + mi * 16 + lg * 4 + j) * 128 + (wn * 64 + ni * 16 + lr)] = acc[mi][ni][j];
  __syncthreads();

  const int kvh = (int)(n0 >> 7);
  const int r0l = tid >> 3;
  const int d0 = (tid & 7) * 8;
#pragma unroll
  for (int k = 0; k < 4; ++k) {
    const int r = r0l + 32 * k;
    const long s = m0 + r;
    float X1[8], X2[8], CC[8], SS[8];
    {
      f32x4 a = *(const f32x4*)&Cls[r * 128 + d0];
      f32x4 b = *(const f32x4*)&Cls[r * 128 + d0 + 4];
      f32x4 c = *(const f32x4*)&Cls[r * 128 + 64 + d0];
      f32x4 d = *(const f32x4*)&Cls[r * 128 + 64 + d0 + 4];
      f32x4 e = *(const f32x4*)&ctab[s * 64 + d0];
      f32x4 f = *(const f32x4*)&ctab[s * 64 + d0 + 4];
      f32x4 g = *(const f32x4*)&stab[s * 64 + d0];
      f32x4 h = *(const f32x4*)&stab[s * 64 + d0 + 4];
#pragma unroll
      for (int j = 0; j < 4; ++j) {
        X1[j] = a[j]; X1[j + 4] = b[j];
        X2[j] = c[j]; X2[j + 4] = d[j];
        CC[j] = e[j]; CC[j + 4] = f[j];
        SS[j] = g[j]; SS[j + 4] = h[j];
      }
    }
    us4 H1[2], L1[2], H2[2], L2[2];
#pragma unroll
    for (int j = 0; j < 8; ++j) {
      float y1 = X1[j] * CC[j] - X2[j] * SS[j];
      float y2 = X2[j] * CC[j] + X1[j] * SS[j];
      unsigned short h1 = f2bf(y1), h2 = f2bf(y2);
      H1[j >> 2][j & 3] = h1; L1[j >> 2][j & 3] = f2bf(y1 - bf2f(h1));
      H2[j >> 2][j & 3] = h2; L2[j >> 2][j & 3] = f2bf(y2 - bf2f(h2));
    }
    long i1 = k2idx(kvh, (int)s, d0);
    long i2 = k2idx(kvh, (int)s, d0 + 64);
    *(us4*)&K2h[i1] = H1[0]; *(us4*)&K2h[i1 + 4] = H1[1];
    *(us4*)&K2l[i1] = L1[0]; *(us4*)&K2l[i1 + 4] = L1[1];
    *(us4*)&K2h[i2] = H2[0]; *(us4*)&K2h[i2 + 4] = H2[1];
    *(us4*)&K2l[i2] = L2[0]; *(us4*)&K2l[i2 + 4] = L2[1];
  }
}

// ---------------- GEMM: C = A * B^T (O-proj), counted-vmcnt double-buffered ----------------
__global__ __launch_bounds__(256) void gemm_bt(const unsigned short* __restrict__ A,
                                               const unsigned short* __restrict__ B,
                                               float* __restrict__ C,
                                               int M, int N, int K) {
  __shared__ __align__(16) unsigned short As[2][4096];
  __shared__ __align__(16) unsigned short Bs[2][4096];
  const int tid = threadIdx.x;
  const int w = tid >> 6, l = tid & 63;
  const int wm = w >> 1, wn = w & 1;
  const int lr = l & 15, lg = l >> 4;
  const long m0 = (long)blockIdx.y * 128, n0 = (long)blockIdx.x * 128;

  f32x4 acc[4][4] = {};

  const int c0 = w * 128 + l;
  const int c1 = c0 + 64;
  const unsigned short* gA0 = A + (m0 + (c0 >> 2)) * K + (c0 & 3) * 8;
  const unsigned short* gA1 = A + (m0 + (c1 >> 2)) * K + (c1 & 3) * 8;
  const unsigned short* gB0 = B + (n0 + (c0 >> 2)) * K + (c0 & 3) * 8;
  const unsigned short* gB1 = B + (n0 + (c1 >> 2)) * K + (c1 & 3) * 8;

#define STAGE1(t, b)                                   \
  {                                                    \
    long kt = (long)(t) * 32;                          \
    gload16(gA0 + kt, &As[b][w * 1024]);               \
    gload16(gA1 + kt, &As[b][w * 1024 + 512]);         \
    gload16(gB0 + kt, &Bs[b][w * 1024]);               \
    gload16(gB1 + kt, &Bs[b][w * 1024 + 512]);         \
  }

  const int nt = K >> 5;
  STAGE1(0, 0);
  if (nt > 1) STAGE1(1, 1);

  for (int t = 0; t < nt; ++t) {
    if (t + 1 < nt) asm volatile("s_waitcnt vmcnt(4)" ::: "memory");
    else            asm volatile("s_waitcnt vmcnt(0)" ::: "memory");
    __builtin_amdgcn_s_barrier();
    __builtin_amdgcn_sched_barrier(0);
    const int b = t & 1;
    bf16x8 af[4], bfr[4];
#pragma unroll
    for (int mi = 0; mi < 4; ++mi)
      af[mi] = *(const bf16x8*)&As[b][(wm * 64 + mi * 16 + lr) * 32 + lg * 8];
#pragma unroll
    for (int ni = 0; ni < 4; ++ni)
      bfr[ni] = *(const bf16x8*)&Bs[b][(wn * 64 + ni * 16 + lr) * 32 + lg * 8];
#pragma unroll
    for (int mi = 0; mi < 4; ++mi)
#pragma unroll
      for (int ni = 0; ni < 4; ++ni)
        acc[mi][ni] = __builtin_amdgcn_mfma_f32_16x16x32_bf16(af[mi], bfr[ni], acc[mi][ni], 0, 0, 0);
    __builtin_amdgcn_sched_barrier(0);
    __builtin_amdgcn_s_barrier();
    __builtin_amdgcn_sched_barrier(0);
    if (t + 2 < nt) STAGE1(t + 2, b);
  }
#undef STAGE1

#pragma unroll
  for (int mi = 0; mi < 4; ++mi)
#pragma unroll
    for (int ni = 0; ni < 4; ++ni)
#pragma unroll
      for (int j = 0; j < 4; ++j) {
        long r = m0 + wm * 64 + mi * 16 + lg * 4 + j;
        long cc = n0 + wn * 64 + ni * 16 + lr;
        C[r * N + cc] = acc[mi][ni][j];
      }
}

// ======== K1: cmax GEMM, 4-deep counted-vmcnt pipeline. ========
__global__ __launch_bounds__(256, 2) void cmax_gemm(const unsigned short* __restrict__ Qh,
                                                    const unsigned short* __restrict__ Ql,
                                                    const unsigned short* __restrict__ K2h,
                                                    const unsigned short* __restrict__ K2l,
                                                    float* __restrict__ cmaxg) {
  __shared__ __align__(16) unsigned short Ksh[4][4096];
  __shared__ __align__(16) unsigned short Ksl[4][4096];
  const int qp = 15 - (int)blockIdx.x;
  const int h = blockIdx.y;
  const int kvh = h >> 2;
  const int q0 = qp * 128;
  const int tid = threadIdx.x;
  const int w = tid >> 6, l = tid & 63;
  const int lr = l & 15, lg = l >> 4;
  const int npan = 4 * (qp + 1);
  const float NEGINF = -__builtin_inff();

  bf16x8 qfh[2][4], qfl[2][4];
#pragma unroll
  for (int rg = 0; rg < 2; ++rg) {
    const unsigned short* qph = Qh + (long)(q0 + w * 32 + rg * 16 + lr) * 4096 + h * 128 + lg * 8;
    const unsigned short* qpl = Ql + (long)(q0 + w * 32 + rg * 16 + lr) * 4096 + h * 128 + lg * 8;
#pragma unroll
    for (int ks = 0; ks < 4; ++ks) {
      qfh[rg][ks] = *(const bf16x8*)(qph + ks * 32);
      qfl[rg][ks] = *(const bf16x8*)(qpl + ks * 32);
    }
  }

  const unsigned short* kbh = K2h + (long)kvh * 128 * 2048;
  const unsigned short* kbl = K2l + (long)kvh * 128 * 2048;

#define STAGE(kp, b)                                                       \
  {                                                                        \
    long off = (long)(kp) * 4096;                                          \
    _Pragma("unroll")                                                      \
    for (int i = 0; i < 2; ++i) {                                          \
      int cu = w * 128 + i * 64;                                           \
      gload16(kbh + off + (cu + l) * 8, &Ksh[b][cu * 8]);                  \
      gload16(kbl + off + (cu + l) * 8, &Ksl[b][cu * 8]);                  \
    }                                                                      \
  }

  STAGE(0, 0);
  if (1 < npan) STAGE(1, 1);
  if (2 < npan) STAGE(2, 2);

  for (int kp = 0; kp < npan; ++kp) {
    {
      int ahead = npan - 1 - kp; if (ahead > 2) ahead = 2;
      int st = kp; if (st > 3) st = 3;
      int tgt = 4 * ahead + 4 * st;
      if (tgt >= 20)      asm volatile("s_waitcnt vmcnt(20)" ::: "memory");
      else if (tgt >= 16) asm volatile("s_waitcnt vmcnt(16)" ::: "memory");
      else if (tgt >= 12) asm volatile("s_waitcnt vmcnt(12)" ::: "memory");
      else if (tgt >= 8)  asm volatile("s_waitcnt vmcnt(8)" ::: "memory");
      else                asm volatile("s_waitcnt vmcnt(0)" ::: "memory");
    }
    __builtin_amdgcn_s_barrier();
    __builtin_amdgcn_sched_barrier(0);
    if (kp + 3 < npan) STAGE(kp + 3, (kp + 3) & 3);
    const int b = kp & 3;
#pragma unroll
    for (int c2 = 0; c2 < 2; ++c2) {
      const int ct = kp * 2 + c2;
      bf16x8 kh[4], kl2[4];
#pragma unroll
      for (int ks = 0; ks < 4; ++ks) {
        kh[ks]  = *(const bf16x8*)&Ksh[b][(c2 * 4 + ks) * 512 + l * 8];
        kl2[ks] = *(const bf16x8*)&Ksl[b][(c2 * 4 + ks) * 512 + l * 8];
      }
#pragma unroll
      for (int rg = 0; rg < 2; ++rg) {
        f32x4 acc = {};
#pragma unroll
        for (int ks = 0; ks < 4; ++ks) {
          acc = __builtin_amdgcn_mfma_f32_16x16x32_bf16(kh[ks], qfh[rg][ks], acc, 0, 0, 0);
          acc = __builtin_amdgcn_mfma_f32_16x16x32_bf16(kh[ks], qfl[rg][ks], acc, 0, 0, 0);
          acc = __builtin_amdgcn_mfma_f32_16x16x32_bf16(kl2[ks], qfh[rg][ks], acc, 0, 0, 0);
        }
        const int rbase = q0 + w * 32 + rg * 16;
        float m;
        if (ct * 16 + 15 <= rbase) {
          m = fmaxf(fmaxf(acc[0], acc[1]), fmaxf(acc[2], acc[3]));
        } else {
          m = NEGINF;
#pragma unroll
          for (int j = 0; j < 4; ++j) {
            int tok = ct * 16 + lg * 4 + j;
            if (tok <= rbase + lr) m = fmaxf(m, acc[j]);
          }
        }
        m = fmaxf(m, __shfl_xor(m, 16));
        m = fmaxf(m, __shfl_xor(m, 32));
        if (l < 16) cmaxg[(long)(h * 128 + ct) * 2048 + rbase + l] = m;
      }
    }
  }
#undef STAGE
}

// ======== K2: per-row top-8 selection. ========
__global__ __launch_bounds__(256) void select_kernel(const float* __restrict__ cmaxg,
                                                     u64* __restrict__ selEg,
                                                     u64* __restrict__ selOg,
                                                     float* __restrict__ mxg) {
  __shared__ float Lc[128 * 65];
  const int r0 = (int)blockIdx.x * 64;
  const int h = blockIdx.y;
  const int tid = threadIdx.x;
  const int w = tid >> 6, l = tid & 63;
  const float NEGINF = -__builtin_inff();

  for (int i = tid; i < 128 * 16; i += 256) {
    int ct = i >> 4, rq = (i & 15) * 4;
    float4 v = *(const float4*)&cmaxg[(long)(h * 128 + ct) * 2048 + r0 + rq];
    Lc[ct * 65 + rq]     = v.x;
    Lc[ct * 65 + rq + 1] = v.y;
    Lc[ct * 65 + rq + 2] = v.z;
    Lc[ct * 65 + rq + 3] = v.w;
  }
  __syncthreads();

  const int c0 = 2 * l, c1 = 2 * l + 1;
#pragma unroll 1
  for (int rs = 0; rs < 16; ++rs) {
    const int rloc = w * 16 + rs;
    const int qr = r0 + rloc;
    const int nctr = (qr >> 4) + 1;
    float v0 = (c0 < nctr) ? Lc[c0 * 65 + rloc] : NEGINF;
    float v1 = (c1 < nctr) ? Lc[c1 * 65 + rloc] : NEGINF;
    const float o0 = v0, o1 = v1;
    float T = NEGINF;
    for (int it = 0; it < 8; ++it) {
      float m = fmaxf(v0, v1);
#pragma unroll
      for (int o = 1; o < 64; o <<= 1) m = fmaxf(m, __shfl_xor(m, o));
      u64 bal = __ballot((v0 == m) || (v1 == m));
      int first = __ffsll(bal) - 1;
      if (l == first) { if (v0 == m) v0 = NEGINF; else v1 = NEGINF; }
      T = m;
    }
    bool okc0 = (c0 < nctr) && ((c0 < 8) || (o0 >= T));
    bool okc1 = (c1 < nctr) && ((c1 < 8) || (o1 >= T));
    u64 bE = __ballot(okc0);
    u64 bO = __ballot(okc1);
    bool al0 = (c0 < nctr) && (okc0 || (c0 * 16 + 15 > qr - 128));
    bool al1 = (c1 < nctr) && (okc1 || (c1 * 16 + 15 > qr - 128));
    float mv = fmaxf(al0 ? o0 : NEGINF, al1 ? o1 : NEGINF);
#pragma unroll
    for (int o = 1; o < 64; o <<= 1) mv = fmaxf(mv, __shfl_xor(mv, o));
    if (l == 0) {
      selEg[h * 2048 + qr] = bE;
      selOg[h * 2048 + qr] = bO;
      mxg[h * 2048 + qr] = mv;
    }
  }
}

// ---------------- P LDS swizzled index ----------------
__device__ __forceinline__ int pidx2(int r, int t) {
  return r * 32 + ((((t >> 3) ^ (r & 3)) << 3) | (t & 7));
}

// ======== K3: phase B ========
__global__ __launch_bounds__(256) void attnB(const unsigned short* __restrict__ Qh,
                                             const unsigned short* __restrict__ K2h,
                                             const unsigned short* __restrict__ V2,
                                             const u64* __restrict__ selEg,
                                             const u64* __restrict__ selOg,
                                             const float* __restrict__ mxg,
                                             unsigned short* __restrict__ AO) {
  __shared__ __align__(16) unsigned short Pls[4][512];
  __shared__ int clistS[4][128];

  const int qb = (int)gridDim.x - 1 - (int)blockIdx.x;
  const int kvh = blockIdx.y;
  const int q0 = qb * 16;
  const int nct = qb + 1;
  const int tid = threadIdx.x;
  const int w = tid >> 6, l = tid & 63;
  const int lr = l & 15, lg = l >> 4;
  const int h = kvh * 4 + w;

  bf16x8 qfh[4];
  {
    const unsigned short* qph = Qh + (long)(q0 + lr) * 4096 + h * 128 + lg * 8;
#pragma unroll
    for (int ks = 0; ks < 4; ++ks) qfh[ks] = *(const bf16x8*)(qph + ks * 32);
  }

  u64 myE = selEg[h * 2048 + q0 + lr];
  u64 myO = selOg[h * 2048 + q0 + lr];
  float mymx = mxg[h * 2048 + q0 + lr];

  u64 uE = myE, uO = myO;
#pragma unroll
  for (int o = 1; o < 16; o <<= 1) {
    uE |= __shfl_xor(uE, o);
    uO |= __shfl_xor(uO, o);
  }
  float mxj[4];
  u64 selE[4], selO[4];
#pragma unroll
  for (int j = 0; j < 4; ++j) {
    mxj[j] = __shfl(mymx, lg * 4 + j);
    selE[j] = __shfl(myE, lg * 4 + j);
    selO[j] = __shfl(myO, lg * 4 + j);
  }

  unsigned short* Pw = Pls[w];
  int* cl = clistS[w];

  const int c0 = 2 * l, c1 = 2 * l + 1;
  bool s0ok = (c0 < nct) && (((uE >> l) & 1ull) || (c0 >= qb - 7));
  bool s1ok = (c1 < nct) && (((uO >> l) & 1ull) || (c1 >= qb - 7));
  u64 bA = __ballot(s0ok);
  u64 bB = __ballot(s1ok);
  const int cntA = __popcll(bA);
  const int nsel = cntA + __popcll(bB);
  if (s0ok) cl[__popcll(bA & ((1ull << l) - 1ull))] = c0;
  if (s1ok) cl[cntA + __popcll(bB & ((1ull << l) - 1ull))] = c1;

  const unsigned short* kbh = K2h + (long)kvh * 128 * 2048;

  f32x4 pacc[8] = {};
  float psum[4] = {0.f, 0.f, 0.f, 0.f};
  const int np = (nsel + 1) >> 1;

  bf16x8 kA[4], kB[4];
  {
    const int cA0 = cl[0];
    const int cB0 = (1 < nsel) ? cl[1] : cA0;
    const unsigned short* pA = kbh + (long)cA0 * 2048 + l * 8;
    const unsigned short* pB = kbh + (long)cB0 * 2048 + l * 8;
#pragma unroll
    for (int ks = 0; ks < 4; ++ks) {
      kA[ks] = *(const bf16x8*)(pA + ks * 512);
      kB[ks] = *(const bf16x8*)(pB + ks * 512);
    }
  }

  for (int pi = 0; pi < np; ++pi) {
    const int cA = cl[2 * pi];
    const int iB = 2 * pi + 1;
    const int cB = (iB < nsel) ? cl[iB] : cA;

    const int csel = (lg < 2) ? cA : cB;
    const unsigned short* vp = V2 + (long)(kvh * 128 + csel) * 2048 + ((lg & 1) * 16 + lr) * 8;
    bf16x8 vf[8];
#pragma unroll
    for (int dblk = 0; dblk < 8; ++dblk) vf[dblk] = *(const bf16x8*)(vp + dblk * 256);

    bf16x8 nA[4], nB[4];
    {
      const int pin = (pi + 1 < np) ? pi + 1 : pi;
      const int cA1 = cl[2 * pin];
      const int iB1 = 2 * pin + 1;
      const int cB1 = (iB1 < nsel) ? cl[iB1] : cA1;
      const unsigned short* pA = kbh + (long)cA1 * 2048 + l * 8;
      const unsigned short* pB = kbh + (long)cB1 * 2048 + l * 8;
#pragma unroll
      for (int ks = 0; ks < 4; ++ks) {
        nA[ks] = *(const bf16x8*)(pA + ks * 512);
        nB[ks] = *(const bf16x8*)(pB + ks * 512);
      }
    }

#pragma unroll
    for (int half = 0; half < 2; ++half) {
      const int c = half ? cB : cA;
      const bool vslot = (2 * pi + half) < nsel;
      f32x4 acc = {};
#pragma unroll
      for (int ks = 0; ks < 4; ++ks) {
        bf16x8 kf = half ? kB[ks] : kA[ks];
        acc = __builtin_amdgcn_mfma_f32_16x16x32_bf16(qfh[ks], kf, acc, 0, 0, 0);
      }
#pragma unroll
      for (int j = 0; j < 4; ++j) {
        const int r = lg * 4 + j;
        const int qrr = q0 + r;
        const int tok = c * 16 + lr;
        u64 sm = (c & 1) ? selO[j] : selE[j];
        bool sel = (sm >> (c >> 1)) & 1ull;
        bool al = vslot && (tok <= qrr) && (sel || (tok > qrr - 128));
        float p = al ? __expf(acc[j] - mxj[j]) : 0.f;
        unsigned short pb = f2bf(p);
        psum[j] += bf2f(pb);
        Pw[pidx2(r, half * 16 + lr)] = pb;
      }
    }
    bf16x8 pa = *(const bf16x8*)&Pw[pidx2(lr, lg * 8)];
#pragma unroll
    for (int dblk = 0; dblk < 8; ++dblk)
      pacc[dblk] = __builtin_amdgcn_mfma_f32_16x16x32_bf16(pa, vf[dblk], pacc[dblk], 0, 0, 0);

#pragma unroll
    for (int ks = 0; ks < 4; ++ks) { kA[ks] = nA[ks]; kB[ks] = nB[ks]; }
  }

#pragma unroll
  for (int j = 0; j < 4; ++j) {
    float s = psum[j];
    s += __shfl_xor(s, 1); s += __shfl_xor(s, 2);
    s += __shfl_xor(s, 4); s += __shfl_xor(s, 8);
    const float rd = 1.0f / s;
    const int r = lg * 4 + j;
#pragma unroll
    for (int dblk = 0; dblk < 8; ++dblk)
      AO[(long)(q0 + r) * 4096 + h * 128 + dblk * 16 + lr] = f2bf(pacc[dblk][j] * rd);
  }
}

// ---------------- launch ----------------
extern "C" void kernel_launch(void* const* d_in, const int* in_sizes, int n_in,
                              void* d_out, int out_size, void* d_ws, size_t ws_size,
                              hipStream_t stream) {
  const float* hidden = (const float*)d_in[0];
  const float* wq = (const float*)d_in[1];
  const float* wk = (const float*)d_in[2];
  const float* wv = (const float*)d_in[3];
  const float* wo = (const float*)d_in[4];
  float* out = (float*)d_out;

  unsigned short* hb_hi = (unsigned short*)d_ws;          // [2048][4096]
  unsigned short* hb_lo = hb_hi + (size_t)2048 * 4096;
  unsigned short* wq_hi = hb_lo + (size_t)2048 * 4096;    // [4096][4096]
  unsigned short* wq_lo = wq_hi + (size_t)4096 * 4096;
  unsigned short* wk_hi = wq_lo + (size_t)4096 * 4096;    // [1024][4096]
  unsigned short* wk_lo = wk_hi + (size_t)1024 * 4096;
  unsigned short* wv_b  = wk_lo + (size_t)1024 * 4096;    // [1024][4096]
  unsigned short* wo_b  = wv_b  + (size_t)1024 * 4096;    // [4096][4096]
  // dedicated qkv outputs (no aliasing with weights read by other blocks)
  unsigned short* Qhi = wo_b + (size_t)4096 * 4096;       // [2048][4096] bf16
  unsigned short* Qlo = Qhi + (size_t)2048 * 4096;
  unsigned short* K2h = Qlo + (size_t)2048 * 4096;        // frag-major
  unsigned short* K2l = K2h + (size_t)2048 * 1024;
  unsigned short* V2  = K2l + (size_t)2048 * 1024;        // frag-major
  // aliases (stream-ordered lifetimes):
  unsigned short* AO = hb_hi;         // hidden splits dead after projections
  float* cmaxg = (float*)wq_hi;       // wq splits dead after projections
  u64* selEg = (u64*)wk_hi;           // wk splits dead after projections
  u64* selOg = selEg + 32 * 2048;
  float* mxg = (float*)(selOg + 32 * 2048);
  float* ctab = out;                  // staged in d_out; fully overwritten by final GEMM
  float* stab = ctab + 2048 * 64;

  cvt_all<<<49152, 256, 0, stream>>>(hidden, wq, wk, wv, wo,
                                     hb_hi, hb_lo, wq_hi, wq_lo,
                                     wk_hi, wk_lo, wv_b, wo_b);
  rope_table<<<512, 256, 0, stream>>>(ctab, stab);

  qkv_gemm<<<256, 256, 0, stream>>>(hb_hi, hb_lo, wk_hi, wk_lo, wv_b,
                                    ctab, stab, K2h, K2l, V2);
  q8ph<<<256, 512, 0, stream>>>(hb_hi, hb_lo, wq_hi, wq_lo,
                                ctab, stab, Qhi, Qlo);

  cmax_gemm<<<dim3(16, 32), 256, 0, stream>>>(Qhi, Qlo, K2h, K2l, cmaxg);
  select_kernel<<<dim3(32, 32), 256, 0, stream>>>(cmaxg, selEg, selOg, mxg);
  attnB<<<dim3(128, 8), 256, 0, stream>>>(Qhi, K2h, V2, selEg, selOg, mxg, AO);

  gemm_bt<<<dim3(32, 16), 256, 0, stream>>>(AO, wo_b, out, 2048, 4096, 4096);
}

// Round 14
// 678.555 us; speedup vs baseline: 1.0643x; 1.0037x over previous
//
#include <hip/hip_runtime.h>
#include <math.h>

typedef __attribute__((ext_vector_type(4))) float f32x4;
typedef __attribute__((ext_vector_type(8))) __bf16 bf16x8;
typedef __attribute__((ext_vector_type(4))) unsigned short us4;
typedef unsigned long long u64;

__device__ __forceinline__ unsigned short f2bf(float f) {
  unsigned int u = __float_as_uint(f);
  u += 0x7fffu + ((u >> 16) & 1u);            // RNE
  return (unsigned short)(u >> 16);
}
__device__ __forceinline__ float bf2f(unsigned short h) {
  return __uint_as_float(((unsigned int)h) << 16);
}

__device__ __forceinline__ void gload16(const void* g, void* l) {
  __builtin_amdgcn_global_load_lds(
      (__attribute__((address_space(1))) void*)g,
      (__attribute__((address_space(3))) void*)l, 16, 0, 0);
}

// ---------------- K2 fragment-major index: K element (s, kvh, d) ----------------
__device__ __forceinline__ long k2idx(int kvh, int s, int d) {
  int ct = s >> 4;
  int lane = (((d & 31) >> 3) << 4) | (s & 15);
  return ((long)(kvh * 128 + ct) * 4 + (d >> 5)) * 512 + lane * 8 + (d & 7);
}

// ---------------- fused fp32 -> bf16 conversions ----------------
__device__ __forceinline__ void split1(const float* __restrict__ in,
                                       unsigned short* __restrict__ hi,
                                       unsigned short* __restrict__ lo, int i) {
  float4 v = ((const float4*)in)[i];
  us4 h, l;
  float vv[4] = {v.x, v.y, v.z, v.w};
#pragma unroll
  for (int j = 0; j < 4; ++j) {
    unsigned short hh = f2bf(vv[j]);
    h[j] = hh;
    l[j] = f2bf(vv[j] - bf2f(hh));
  }
  ((us4*)hi)[i] = h;
  ((us4*)lo)[i] = l;
}
__device__ __forceinline__ void plain1(const float* __restrict__ in,
                                       unsigned short* __restrict__ out, int i) {
  float4 v = ((const float4*)in)[i];
  us4 o;
  o[0] = f2bf(v.x); o[1] = f2bf(v.y); o[2] = f2bf(v.z); o[3] = f2bf(v.w);
  ((us4*)out)[i] = o;
}

__global__ __launch_bounds__(256) void cvt_all(const float* __restrict__ hidden,
                                               const float* __restrict__ wq,
                                               const float* __restrict__ wk,
                                               const float* __restrict__ wv,
                                               const float* __restrict__ wo,
                                               unsigned short* __restrict__ hb_hi,
                                               unsigned short* __restrict__ hb_lo,
                                               unsigned short* __restrict__ wq_hi,
                                               unsigned short* __restrict__ wq_lo,
                                               unsigned short* __restrict__ wk_hi,
                                               unsigned short* __restrict__ wk_lo,
                                               unsigned short* __restrict__ wv_b,
                                               unsigned short* __restrict__ wo_b) {
  int i = blockIdx.x * 256 + threadIdx.x;
  if (i < 2097152)       split1(hidden, hb_hi, hb_lo, i);
  else if (i < 6291456)  split1(wq, wq_hi, wq_lo, i - 2097152);
  else if (i < 7340032)  split1(wk, wk_hi, wk_lo, i - 6291456);
  else if (i < 8388608)  plain1(wv, wv_b, i - 7340032);
  else if (i < 12582912) plain1(wo, wo_b, i - 8388608);
}

// ---------------- RoPE angle table (staged in d_out; overwritten by final GEMM) ----------------
__global__ __launch_bounds__(256) void rope_table(float* __restrict__ ctab,
                                                  float* __restrict__ stab) {
  int idx = blockIdx.x * 256 + threadIdx.x;   // 2048*64
  if (idx >= 2048 * 64) return;
  int s = idx >> 6, d = idx & 63;
  float inv = powf(10000.0f, -(float)d * (1.0f / 64.0f));
  float ang = (float)s * inv;
  ctab[idx] = cosf(ang);
  stab[idx] = sinf(ang);
}

// ======== Q-proj: 8-phase counted-vmcnt 3-term GEMM + rope epilogue (round-13, proven) ========
__global__ __launch_bounds__(512, 2) void q8ph(const unsigned short* __restrict__ Ahg,
                                               const unsigned short* __restrict__ Alg,
                                               const unsigned short* __restrict__ wq_hi,
                                               const unsigned short* __restrict__ wq_lo,
                                               const float* __restrict__ ctab,
                                               const float* __restrict__ stab,
                                               unsigned short* __restrict__ Qh,
                                               unsigned short* __restrict__ Ql) {
  __shared__ __align__(16) unsigned short shb[73728];   // 144 KB
  const int bid = blockIdx.x;
  const int tid = threadIdx.x;
  const int w = tid >> 6, l = tid & 63;
  const int lr = l & 15, lg = l >> 4;
  const int wr = w >> 2, wc = w & 3;
  const int nt = 128;

  const int m_idx = (bid & 7) * 2 + ((bid >> 3) & 1);   // A-pair pinned per XCD
  const int n_idx = bid >> 4;
  const long m0 = (long)m_idx * 128;
  const long n0 = (long)n_idx * 256;

  const int arow = tid >> 2;
  const int kg = ((tid & 3) ^ ((tid >> 2) & 3) ^ ((tid >> 4) & 3)) & 3;
  const long aoff  = (m0 + arow) * 4096 + kg * 8;
  const long boff0 = (n0 + arow) * 4096 + kg * 8;
  const long boff1 = (n0 + 128 + arow) * 4096 + kg * 8;
  const int dstw = w * 512;

  const int xk = (lg ^ (lr & 3) ^ ((lr >> 2) & 3)) & 3;

#define QSTG_A(t, bs)                                                         \
  { gload16(Ahg + aoff + (long)(t) * 32, &shb[(bs) * 4096 + dstw]);           \
    gload16(Alg + aoff + (long)(t) * 32, &shb[12288 + (bs) * 4096 + dstw]); }
#define QSTG_BH(t, bs)                                                        \
  { gload16(wq_hi + boff0 + (long)(t) * 32, &shb[24576 + (bs) * 8192 + dstw]);\
    gload16(wq_hi + boff1 + (long)(t) * 32, &shb[24576 + (bs) * 8192 + 4096 + dstw]); }
#define QSTG_BL(t, bs)                                                        \
  { gload16(wq_lo + boff0 + (long)(t) * 32, &shb[49152 + (bs) * 8192 + dstw]);\
    gload16(wq_lo + boff1 + (long)(t) * 32, &shb[49152 + (bs) * 8192 + 4096 + dstw]); }

  f32x4 acc[4][4] = {};

  QSTG_A(0, 0); QSTG_BH(0, 0); QSTG_BL(0, 0);
  QSTG_A(1, 1); QSTG_BH(1, 1); QSTG_BL(1, 1);
  QSTG_A(2, 2); QSTG_BH(2, 2); QSTG_BL(2, 2);
  asm volatile("s_waitcnt vmcnt(12)" ::: "memory");
  __builtin_amdgcn_s_barrier();
  __builtin_amdgcn_sched_barrier(0);

#define QPH_ENTER                                        \
  __builtin_amdgcn_sched_barrier(0);                     \
  __builtin_amdgcn_s_barrier();                          \
  asm volatile("s_waitcnt lgkmcnt(0)" ::: "memory");     \
  __builtin_amdgcn_sched_barrier(0);                     \
  __builtin_amdgcn_s_setprio(1);
#define QPH_EXIT                                         \
  __builtin_amdgcn_s_setprio(0);                         \
  __builtin_amdgcn_sched_barrier(0);                     \
  __builtin_amdgcn_s_barrier();                          \
  __builtin_amdgcn_sched_barrier(0);
#define QPH_MFMA(p)                                                                            \
  _Pragma("unroll")                                                                            \
  for (int mi = 0; mi < 4; ++mi) {                                                             \
    acc[mi][p] = __builtin_amdgcn_mfma_f32_16x16x32_bf16(afh[mi], bfh, acc[mi][p], 0, 0, 0);   \
    acc[mi][p] = __builtin_amdgcn_mfma_f32_16x16x32_bf16(afl[mi], bfh, acc[mi][p], 0, 0, 0);   \
    acc[mi][p] = __builtin_amdgcn_mfma_f32_16x16x32_bf16(afh[mi], bfl, acc[mi][p], 0, 0, 0);   \
  }
#define QPH_RDB(p)                                                                  \
  { int rowb = wc * 64 + (p) * 16 + lr;                                             \
    bfh = *(const bf16x8*)&shb[24576 + bs * 8192 + rowb * 32 + xk * 8];             \
    bfl = *(const bf16x8*)&shb[49152 + bs * 8192 + rowb * 32 + xk * 8]; }

  for (int t = 0; t < nt; ++t) {
    const int bs = t % 3;
    const int bss = (t + 2) % 3;
    const bool st = (t + 2) < nt;
    bf16x8 afh[4], afl[4], bfh, bfl;
#pragma unroll
    for (int mi = 0; mi < 4; ++mi) {
      int rowa = wr * 64 + mi * 16 + lr;
      afh[mi] = *(const bf16x8*)&shb[bs * 4096 + rowa * 32 + xk * 8];
      afl[mi] = *(const bf16x8*)&shb[12288 + bs * 4096 + rowa * 32 + xk * 8];
    }
    QPH_RDB(0);
    if (st) QSTG_A(t + 2, bss);
    QPH_ENTER; QPH_MFMA(0); QPH_EXIT;
    QPH_RDB(1);
    if (st) QSTG_BH(t + 2, bss);
    QPH_ENTER; QPH_MFMA(1); QPH_EXIT;
    QPH_RDB(2);
    if (st) QSTG_BL(t + 2, bss);
    QPH_ENTER; QPH_MFMA(2); QPH_EXIT;
    QPH_RDB(3);
    if (st) asm volatile("s_waitcnt vmcnt(6)" ::: "memory");
    else    asm volatile("s_waitcnt vmcnt(0)" ::: "memory");
    QPH_ENTER; QPH_MFMA(3); QPH_EXIT;
  }
#undef QSTG_A
#undef QSTG_BH
#undef QSTG_BL
#undef QPH_ENTER
#undef QPH_EXIT
#undef QPH_MFMA
#undef QPH_RDB

  __syncthreads();
  float* Cls = (float*)shb;                              // 128x256 fp32 = 128 KB
#pragma unroll
  for (int mi = 0; mi < 4; ++mi)
#pragma unroll
    for (int ni = 0; ni < 4; ++ni)
#pragma unroll
      for (int j = 0; j < 4; ++j)
        Cls[(wr * 64 + mi * 16 + lg * 4 + j) * 256 + wc * 64 + ni * 16 + lr] = acc[mi][ni][j];
  __syncthreads();

  const int r0l = tid >> 3;
  const int d0 = (tid & 7) * 8;
#pragma unroll
  for (int h = 0; h < 2; ++h) {
    const int head = n_idx * 2 + h;
#pragma unroll
    for (int k = 0; k < 2; ++k) {
      const int r = r0l + 64 * k;
      const long s = m0 + r;
      float X1[8], X2[8], CC[8], SS[8];
      {
        f32x4 a = *(const f32x4*)&Cls[r * 256 + h * 128 + d0];
        f32x4 b = *(const f32x4*)&Cls[r * 256 + h * 128 + d0 + 4];
        f32x4 c = *(const f32x4*)&Cls[r * 256 + h * 128 + 64 + d0];
        f32x4 d = *(const f32x4*)&Cls[r * 256 + h * 128 + 64 + d0 + 4];
        f32x4 e = *(const f32x4*)&ctab[s * 64 + d0];
        f32x4 f = *(const f32x4*)&ctab[s * 64 + d0 + 4];
        f32x4 g = *(const f32x4*)&stab[s * 64 + d0];
        f32x4 hh = *(const f32x4*)&stab[s * 64 + d0 + 4];
#pragma unroll
        for (int j = 0; j < 4; ++j) {
          X1[j] = a[j]; X1[j + 4] = b[j];
          X2[j] = c[j]; X2[j + 4] = d[j];
          CC[j] = e[j]; CC[j + 4] = f[j];
          SS[j] = g[j]; SS[j + 4] = hh[j];
        }
      }
      us4 H1[2], L1[2], H2[2], L2[2];
#pragma unroll
      for (int j = 0; j < 8; ++j) {
        float y1 = (X1[j] * CC[j] - X2[j] * SS[j]) * 0.08838834764831845f;
        float y2 = (X2[j] * CC[j] + X1[j] * SS[j]) * 0.08838834764831845f;
        unsigned short h1 = f2bf(y1), h2 = f2bf(y2);
        H1[j >> 2][j & 3] = h1; L1[j >> 2][j & 3] = f2bf(y1 - bf2f(h1));
        H2[j >> 2][j & 3] = h2; L2[j >> 2][j & 3] = f2bf(y2 - bf2f(h2));
      }
      long row = s * 4096 + head * 128;
      *(us4*)&Qh[row + d0] = H1[0];      *(us4*)&Qh[row + d0 + 4] = H1[1];
      *(us4*)&Ql[row + d0] = L1[0];      *(us4*)&Ql[row + d0 + 4] = L1[1];
      *(us4*)&Qh[row + 64 + d0] = H2[0]; *(us4*)&Qh[row + 64 + d0 + 4] = H2[1];
      *(us4*)&Ql[row + 64 + d0] = L2[0]; *(us4*)&Ql[row + 64 + d0 + 4] = L2[1];
    }
  }
}

// ======== O-proj: 8-phase counted-vmcnt 1-term GEMM (q8ph skeleton, 72 KB -> 2 blk/CU) ========
// 256 blocks x 512 thr. Tile 128x256, BK=32, triple-buffered. 2 phases/tile x 8 MFMA.
// 3 gloads/tile; steady-state vmcnt(3). A-pinned XCD mapping. Same accumulation order as gemm_bt.
__global__ __launch_bounds__(512, 2) void o8ph(const unsigned short* __restrict__ A,
                                               const unsigned short* __restrict__ B,
                                               float* __restrict__ C) {
  __shared__ __align__(16) unsigned short shb[36864];   // 72 KB
  const int bid = blockIdx.x;
  const int tid = threadIdx.x;
  const int w = tid >> 6, l = tid & 63;
  const int lr = l & 15, lg = l >> 4;
  const int wr = w >> 2, wc = w & 3;
  const int nt = 128;

  const int m_idx = (bid & 7) * 2 + ((bid >> 3) & 1);   // AO-pair pinned per XCD
  const int n_idx = bid >> 4;
  const long m0 = (long)m_idx * 128;
  const long n0 = (long)n_idx * 256;

  const int arow = tid >> 2;
  const int kg = ((tid & 3) ^ ((tid >> 2) & 3) ^ ((tid >> 4) & 3)) & 3;
  const long aoff  = (m0 + arow) * 4096 + kg * 8;
  const long boff0 = (n0 + arow) * 4096 + kg * 8;
  const long boff1 = (n0 + 128 + arow) * 4096 + kg * 8;
  const int dstw = w * 512;

  const int xk = (lg ^ (lr & 3) ^ ((lr >> 2) & 3)) & 3;

  // LDS map (ushort idx): A[bs] @ bs*4096 (3x8KB); B[bs] @ 12288 + bs*8192 (3x16KB)
#define OSTG_A(t, bs)                                                        \
  gload16(A + aoff + (long)(t) * 32, &shb[(bs) * 4096 + dstw]);
#define OSTG_B0(t, bs)                                                       \
  gload16(B + boff0 + (long)(t) * 32, &shb[12288 + (bs) * 8192 + dstw]);
#define OSTG_B1(t, bs)                                                       \
  gload16(B + boff1 + (long)(t) * 32, &shb[12288 + (bs) * 8192 + 4096 + dstw]);

  f32x4 acc[4][4] = {};

  OSTG_A(0, 0); OSTG_B0(0, 0); OSTG_B1(0, 0);
  OSTG_A(1, 1); OSTG_B0(1, 1); OSTG_B1(1, 1);
  OSTG_A(2, 2); OSTG_B0(2, 2); OSTG_B1(2, 2);
  asm volatile("s_waitcnt vmcnt(6)" ::: "memory");       // tile 0 ready; 1,2 in flight
  __builtin_amdgcn_s_barrier();
  __builtin_amdgcn_sched_barrier(0);

#define OPH_ENTER                                        \
  __builtin_amdgcn_sched_barrier(0);                     \
  __builtin_amdgcn_s_barrier();                          \
  asm volatile("s_waitcnt lgkmcnt(0)" ::: "memory");     \
  __builtin_amdgcn_sched_barrier(0);                     \
  __builtin_amdgcn_s_setprio(1);
#define OPH_EXIT                                         \
  __builtin_amdgcn_s_setprio(0);                         \
  __builtin_amdgcn_sched_barrier(0);                     \
  __builtin_amdgcn_s_barrier();                          \
  __builtin_amdgcn_sched_barrier(0);
#define OPH_RDB(p, dst)                                                             \
  { int rowb = wc * 64 + (p) * 16 + lr;                                             \
    dst = *(const bf16x8*)&shb[12288 + bs * 8192 + (rowb & 127) * 32 +              \
                               ((rowb >> 7) & 1) * 4096 + xk * 8]; }

  for (int t = 0; t < nt; ++t) {
    const int bs = t % 3;
    const int bss = (t + 2) % 3;
    const bool st = (t + 2) < nt;
    bf16x8 af[4], bf0, bf1, bf2, bf3;
    // ---- phase 0: A frags + B(0,1); stage A, B0 of t+2 ----
#pragma unroll
    for (int mi = 0; mi < 4; ++mi) {
      int rowa = wr * 64 + mi * 16 + lr;
      af[mi] = *(const bf16x8*)&shb[bs * 4096 + rowa * 32 + xk * 8];
    }
    OPH_RDB(0, bf0);
    OPH_RDB(1, bf1);
    if (st) { OSTG_A(t + 2, bss); OSTG_B0(t + 2, bss); }
    OPH_ENTER;
#pragma unroll
    for (int mi = 0; mi < 4; ++mi) {
      acc[mi][0] = __builtin_amdgcn_mfma_f32_16x16x32_bf16(af[mi], bf0, acc[mi][0], 0, 0, 0);
      acc[mi][1] = __builtin_amdgcn_mfma_f32_16x16x32_bf16(af[mi], bf1, acc[mi][1], 0, 0, 0);
    }
    OPH_EXIT;
    // ---- phase 1: B(2,3); stage B1 of t+2; counted vmcnt ----
    OPH_RDB(2, bf2);
    OPH_RDB(3, bf3);
    if (st) OSTG_B1(t + 2, bss);
    if (st) asm volatile("s_waitcnt vmcnt(3)" ::: "memory");
    else    asm volatile("s_waitcnt vmcnt(0)" ::: "memory");
    OPH_ENTER;
#pragma unroll
    for (int mi = 0; mi < 4; ++mi) {
      acc[mi][2] = __builtin_amdgcn_mfma_f32_16x16x32_bf16(af[mi], bf2, acc[mi][2], 0, 0, 0);
      acc[mi][3] = __builtin_amdgcn_mfma_f32_16x16x32_bf16(af[mi], bf3, acc[mi][3], 0, 0, 0);
    }
    OPH_EXIT;
  }
#undef OSTG_A
#undef OSTG_B0
#undef OSTG_B1
#undef OPH_ENTER
#undef OPH_EXIT
#undef OPH_RDB

  // direct fp32 stores (same values/positions as old gemm_bt)
#pragma unroll
  for (int mi = 0; mi < 4; ++mi)
#pragma unroll
    for (int ni = 0; ni < 4; ++ni)
#pragma unroll
      for (int j = 0; j < 4; ++j) {
        long r = m0 + wr * 64 + mi * 16 + lg * 4 + j;
        long cc = n0 + wc * 64 + ni * 16 + lr;
        C[r * 4096 + cc] = acc[mi][ni][j];
      }
}

// ======== K/V projection (round-12/13 qkv_gemm) ========
__global__ __launch_bounds__(256) void qkv_gemm(const unsigned short* __restrict__ Ahg,
                                                const unsigned short* __restrict__ Alg,
                                                const unsigned short* __restrict__ wk_hi,
                                                const unsigned short* __restrict__ wk_lo,
                                                const unsigned short* __restrict__ wv_b,
                                                const float* __restrict__ ctab,
                                                const float* __restrict__ stab,
                                                unsigned short* __restrict__ K2h,
                                                unsigned short* __restrict__ K2l,
                                                unsigned short* __restrict__ V2) {
  __shared__ __align__(16) unsigned short shb[32768];   // 64 KB
  const int bid = blockIdx.x;
  const int tid = threadIdx.x;
  const int w = tid >> 6, l = tid & 63;
  const int wm = w >> 1, wn = w & 1;
  const int lr = l & 15, lg = l >> 4;
  const int K = 4096;
  const int nt = K >> 5;

  if (bid >= 128) {
    const int b3 = bid - 128;
    const long m0 = (long)((b3 & 7) * 2 + ((b3 >> 3) & 1)) * 128;
    const long n0 = (long)(b3 >> 4) * 128;
    f32x4 acc[4][4] = {};
    const int c0 = w * 128 + l;
    const int c1 = c0 + 64;
    const unsigned short* gA0 = Ahg + (m0 + (c0 >> 2)) * K + (c0 & 3) * 8;
    const unsigned short* gA1 = Ahg + (m0 + (c1 >> 2)) * K + (c1 & 3) * 8;
    const unsigned short* gB0 = wv_b + (n0 + (c0 >> 2)) * K + (c0 & 3) * 8;
    const unsigned short* gB1 = wv_b + (n0 + (c1 >> 2)) * K + (c1 & 3) * 8;

#define STAGE1(t, b)                                         \
  {                                                          \
    long kt = (long)(t) * 32;                                \
    gload16(gA0 + kt, &shb[(b) * 4096 + w * 1024]);          \
    gload16(gA1 + kt, &shb[(b) * 4096 + w * 1024 + 512]);    \
    gload16(gB0 + kt, &shb[16384 + (b) * 4096 + w * 1024]);  \
    gload16(gB1 + kt, &shb[16384 + (b) * 4096 + w * 1024 + 512]); \
  }
    STAGE1(0, 0);
    STAGE1(1, 1);
    for (int t = 0; t < nt; ++t) {
      if (t + 1 < nt) asm volatile("s_waitcnt vmcnt(4)" ::: "memory");
      else            asm volatile("s_waitcnt vmcnt(0)" ::: "memory");
      __builtin_amdgcn_s_barrier();
      __builtin_amdgcn_sched_barrier(0);
      const int b = t & 1;
      bf16x8 af[4], bfr[4];
#pragma unroll
      for (int mi = 0; mi < 4; ++mi)
        af[mi] = *(const bf16x8*)&shb[b * 4096 + (wm * 64 + mi * 16 + lr) * 32 + lg * 8];
#pragma unroll
      for (int ni = 0; ni < 4; ++ni)
        bfr[ni] = *(const bf16x8*)&shb[16384 + b * 4096 + (wn * 64 + ni * 16 + lr) * 32 + lg * 8];
#pragma unroll
      for (int mi = 0; mi < 4; ++mi)
#pragma unroll
        for (int ni = 0; ni < 4; ++ni)
          acc[mi][ni] = __builtin_amdgcn_mfma_f32_16x16x32_bf16(af[mi], bfr[ni], acc[mi][ni], 0, 0, 0);
      __builtin_amdgcn_sched_barrier(0);
      __builtin_amdgcn_s_barrier();
      __builtin_amdgcn_sched_barrier(0);
      if (t + 2 < nt) STAGE1(t + 2, b);
    }
#undef STAGE1
#pragma unroll
    for (int mi = 0; mi < 4; ++mi)
#pragma unroll
      for (int ni = 0; ni < 4; ++ni)
#pragma unroll
        for (int j = 0; j < 4; ++j) {
          long r = m0 + wm * 64 + mi * 16 + lg * 4 + j;
          long cc = n0 + wn * 64 + ni * 16 + lr;
          int kvh = (int)(cc >> 7), d = (int)(cc & 127);
          int c = (int)(r >> 4), t2 = (int)(r & 15);
          long idx = ((long)(kvh * 128 + c) * 8 + (d >> 4)) * 256 + ((t2 >> 3) * 16 + (d & 15)) * 8 + (t2 & 7);
          V2[idx] = f2bf(acc[mi][ni][j]);
        }
    return;
  }

  const long m0 = (long)((bid & 7) * 2 + ((bid >> 3) & 1)) * 128;
  const long n0 = (long)(bid >> 4) * 128;

  f32x4 acc[4][4] = {};
  const int c0 = w * 128 + l;
  const int c1 = c0 + 64;
  const long oA0 = (m0 + (c0 >> 2)) * K + (c0 & 3) * 8;
  const long oA1 = (m0 + (c1 >> 2)) * K + (c1 & 3) * 8;
  const long oB0 = (n0 + (c0 >> 2)) * K + (c0 & 3) * 8;
  const long oB1 = (n0 + (c1 >> 2)) * K + (c1 & 3) * 8;

#define STAGE3(t, b)                                               \
  {                                                                \
    long kt = (long)(t) * 32;                                      \
    gload16(Ahg + oA0 + kt, &shb[(b) * 4096 + w * 1024]);          \
    gload16(Ahg + oA1 + kt, &shb[(b) * 4096 + w * 1024 + 512]);    \
    gload16(Alg + oA0 + kt, &shb[8192 + (b) * 4096 + w * 1024]);   \
    gload16(Alg + oA1 + kt, &shb[8192 + (b) * 4096 + w * 1024 + 512]); \
    gload16(wk_hi + oB0 + kt, &shb[16384 + (b) * 4096 + w * 1024]);   \
    gload16(wk_hi + oB1 + kt, &shb[16384 + (b) * 4096 + w * 1024 + 512]); \
    gload16(wk_lo + oB0 + kt, &shb[24576 + (b) * 4096 + w * 1024]);   \
    gload16(wk_lo + oB1 + kt, &shb[24576 + (b) * 4096 + w * 1024 + 512]); \
  }
  STAGE3(0, 0);
  STAGE3(1, 1);
  for (int t = 0; t < nt; ++t) {
    if (t + 1 < nt) asm volatile("s_waitcnt vmcnt(8)" ::: "memory");
    else            asm volatile("s_waitcnt vmcnt(0)" ::: "memory");
    __builtin_amdgcn_s_barrier();
    __builtin_amdgcn_sched_barrier(0);
    const int b = t & 1;
    bf16x8 afh[4], afl[4], bfh[4], bfl[4];
#pragma unroll
    for (int mi = 0; mi < 4; ++mi) {
      afh[mi] = *(const bf16x8*)&shb[b * 4096 + (wm * 64 + mi * 16 + lr) * 32 + lg * 8];
      afl[mi] = *(const bf16x8*)&shb[8192 + b * 4096 + (wm * 64 + mi * 16 + lr) * 32 + lg * 8];
    }
#pragma unroll
    for (int ni = 0; ni < 4; ++ni) {
      bfh[ni] = *(const bf16x8*)&shb[16384 + b * 4096 + (wn * 64 + ni * 16 + lr) * 32 + lg * 8];
      bfl[ni] = *(const bf16x8*)&shb[24576 + b * 4096 + (wn * 64 + ni * 16 + lr) * 32 + lg * 8];
    }
#pragma unroll
    for (int mi = 0; mi < 4; ++mi)
#pragma unroll
      for (int ni = 0; ni < 4; ++ni) {
        acc[mi][ni] = __builtin_amdgcn_mfma_f32_16x16x32_bf16(afh[mi], bfh[ni], acc[mi][ni], 0, 0, 0);
        acc[mi][ni] = __builtin_amdgcn_mfma_f32_16x16x32_bf16(afl[mi], bfh[ni], acc[mi][ni], 0, 0, 0);
        acc[mi][ni] = __builtin_amdgcn_mfma_f32_16x16x32_bf16(afh[mi], bfl[ni], acc[mi][ni], 0, 0, 0);
      }
    __builtin_amdgcn_sched_barrier(0);
    __builtin_amdgcn_s_barrier();
    __builtin_amdgcn_sched_barrier(0);
    if (t + 2 < nt) STAGE3(t + 2, b);
  }
#undef STAGE3

  __syncthreads();
  float* Cls = (float*)shb;
#pragma unroll
  for (int mi = 0; mi < 4; ++mi)
#pragma unroll
    for (int ni = 0; ni < 4; ++ni)
#pragma unroll
      for (int j = 0; j < 4; ++j)
        Cls[(wm * 64 + mi * 16 + lg * 4 + j) * 128 + (wn * 64 + ni * 16 + lr)] = acc[mi][ni][j];
  __syncthreads();

  const int kvh = (int)(n0 >> 7);
  const int r0l = tid >> 3;
  const int d0 = (tid & 7) * 8;
#pragma unroll
  for (int k = 0; k < 4; ++k) {
    const int r = r0l + 32 * k;
    const long s = m0 + r;
    float X1[8], X2[8], CC[8], SS[8];
    {
      f32x4 a = *(const f32x4*)&Cls[r * 128 + d0];
      f32x4 b = *(const f32x4*)&Cls[r * 128 + d0 + 4];
      f32x4 c = *(const f32x4*)&Cls[r * 128 + 64 + d0];
      f32x4 d = *(const f32x4*)&Cls[r * 128 + 64 + d0 + 4];
      f32x4 e = *(const f32x4*)&ctab[s * 64 + d0];
      f32x4 f = *(const f32x4*)&ctab[s * 64 + d0 + 4];
      f32x4 g = *(const f32x4*)&stab[s * 64 + d0];
      f32x4 h = *(const f32x4*)&stab[s * 64 + d0 + 4];
#pragma unroll
      for (int j = 0; j < 4; ++j) {
        X1[j] = a[j]; X1[j + 4] = b[j];
        X2[j] = c[j]; X2[j + 4] = d[j];
        CC[j] = e[j]; CC[j + 4] = f[j];
        SS[j] = g[j]; SS[j + 4] = h[j];
      }
    }
    us4 H1[2], L1[2], H2[2], L2[2];
#pragma unroll
    for (int j = 0; j < 8; ++j) {
      float y1 = X1[j] * CC[j] - X2[j] * SS[j];
      float y2 = X2[j] * CC[j] + X1[j] * SS[j];
      unsigned short h1 = f2bf(y1), h2 = f2bf(y2);
      H1[j >> 2][j & 3] = h1; L1[j >> 2][j & 3] = f2bf(y1 - bf2f(h1));
      H2[j >> 2][j & 3] = h2; L2[j >> 2][j & 3] = f2bf(y2 - bf2f(h2));
    }
    long i1 = k2idx(kvh, (int)s, d0);
    long i2 = k2idx(kvh, (int)s, d0 + 64);
    *(us4*)&K2h[i1] = H1[0]; *(us4*)&K2h[i1 + 4] = H1[1];
    *(us4*)&K2l[i1] = L1[0]; *(us4*)&K2l[i1 + 4] = L1[1];
    *(us4*)&K2h[i2] = H2[0]; *(us4*)&K2h[i2 + 4] = H2[1];
    *(us4*)&K2l[i2] = L2[0]; *(us4*)&K2l[i2 + 4] = L2[1];
  }
}

// ======== K1: cmax GEMM, 4-deep counted-vmcnt pipeline. ========
__global__ __launch_bounds__(256, 2) void cmax_gemm(const unsigned short* __restrict__ Qh,
                                                    const unsigned short* __restrict__ Ql,
                                                    const unsigned short* __restrict__ K2h,
                                                    const unsigned short* __restrict__ K2l,
                                                    float* __restrict__ cmaxg) {
  __shared__ __align__(16) unsigned short Ksh[4][4096];
  __shared__ __align__(16) unsigned short Ksl[4][4096];
  const int qp = 15 - (int)blockIdx.x;
  const int h = blockIdx.y;
  const int kvh = h >> 2;
  const int q0 = qp * 128;
  const int tid = threadIdx.x;
  const int w = tid >> 6, l = tid & 63;
  const int lr = l & 15, lg = l >> 4;
  const int npan = 4 * (qp + 1);
  const float NEGINF = -__builtin_inff();

  bf16x8 qfh[2][4], qfl[2][4];
#pragma unroll
  for (int rg = 0; rg < 2; ++rg) {
    const unsigned short* qph = Qh + (long)(q0 + w * 32 + rg * 16 + lr) * 4096 + h * 128 + lg * 8;
    const unsigned short* qpl = Ql + (long)(q0 + w * 32 + rg * 16 + lr) * 4096 + h * 128 + lg * 8;
#pragma unroll
    for (int ks = 0; ks < 4; ++ks) {
      qfh[rg][ks] = *(const bf16x8*)(qph + ks * 32);
      qfl[rg][ks] = *(const bf16x8*)(qpl + ks * 32);
    }
  }

  const unsigned short* kbh = K2h + (long)kvh * 128 * 2048;
  const unsigned short* kbl = K2l + (long)kvh * 128 * 2048;

#define STAGE(kp, b)                                                       \
  {                                                                        \
    long off = (long)(kp) * 4096;                                          \
    _Pragma("unroll")                                                      \
    for (int i = 0; i < 2; ++i) {                                          \
      int cu = w * 128 + i * 64;                                           \
      gload16(kbh + off + (cu + l) * 8, &Ksh[b][cu * 8]);                  \
      gload16(kbl + off + (cu + l) * 8, &Ksl[b][cu * 8]);                  \
    }                                                                      \
  }

  STAGE(0, 0);
  if (1 < npan) STAGE(1, 1);
  if (2 < npan) STAGE(2, 2);

  for (int kp = 0; kp < npan; ++kp) {
    {
      int ahead = npan - 1 - kp; if (ahead > 2) ahead = 2;
      int st = kp; if (st > 3) st = 3;
      int tgt = 4 * ahead + 4 * st;
      if (tgt >= 20)      asm volatile("s_waitcnt vmcnt(20)" ::: "memory");
      else if (tgt >= 16) asm volatile("s_waitcnt vmcnt(16)" ::: "memory");
      else if (tgt >= 12) asm volatile("s_waitcnt vmcnt(12)" ::: "memory");
      else if (tgt >= 8)  asm volatile("s_waitcnt vmcnt(8)" ::: "memory");
      else                asm volatile("s_waitcnt vmcnt(0)" ::: "memory");
    }
    __builtin_amdgcn_s_barrier();
    __builtin_amdgcn_sched_barrier(0);
    if (kp + 3 < npan) STAGE(kp + 3, (kp + 3) & 3);
    const int b = kp & 3;
#pragma unroll
    for (int c2 = 0; c2 < 2; ++c2) {
      const int ct = kp * 2 + c2;
      bf16x8 kh[4], kl2[4];
#pragma unroll
      for (int ks = 0; ks < 4; ++ks) {
        kh[ks]  = *(const bf16x8*)&Ksh[b][(c2 * 4 + ks) * 512 + l * 8];
        kl2[ks] = *(const bf16x8*)&Ksl[b][(c2 * 4 + ks) * 512 + l * 8];
      }
#pragma unroll
      for (int rg = 0; rg < 2; ++rg) {
        f32x4 acc = {};
#pragma unroll
        for (int ks = 0; ks < 4; ++ks) {
          acc = __builtin_amdgcn_mfma_f32_16x16x32_bf16(kh[ks], qfh[rg][ks], acc, 0, 0, 0);
          acc = __builtin_amdgcn_mfma_f32_16x16x32_bf16(kh[ks], qfl[rg][ks], acc, 0, 0, 0);
          acc = __builtin_amdgcn_mfma_f32_16x16x32_bf16(kl2[ks], qfh[rg][ks], acc, 0, 0, 0);
        }
        const int rbase = q0 + w * 32 + rg * 16;
        float m;
        if (ct * 16 + 15 <= rbase) {
          m = fmaxf(fmaxf(acc[0], acc[1]), fmaxf(acc[2], acc[3]));
        } else {
          m = NEGINF;
#pragma unroll
          for (int j = 0; j < 4; ++j) {
            int tok = ct * 16 + lg * 4 + j;
            if (tok <= rbase + lr) m = fmaxf(m, acc[j]);
          }
        }
        m = fmaxf(m, __shfl_xor(m, 16));
        m = fmaxf(m, __shfl_xor(m, 32));
        if (l < 16) cmaxg[(long)(h * 128 + ct) * 2048 + rbase + l] = m;
      }
    }
  }
#undef STAGE
}

// ======== K2: per-row top-8 selection. ========
__global__ __launch_bounds__(256) void select_kernel(const float* __restrict__ cmaxg,
                                                     u64* __restrict__ selEg,
                                                     u64* __restrict__ selOg,
                                                     float* __restrict__ mxg) {
  __shared__ float Lc[128 * 65];
  const int r0 = (int)blockIdx.x * 64;
  const int h = blockIdx.y;
  const int tid = threadIdx.x;
  const int w = tid >> 6, l = tid & 63;
  const float NEGINF = -__builtin_inff();

  for (int i = tid; i < 128 * 16; i += 256) {
    int ct = i >> 4, rq = (i & 15) * 4;
    float4 v = *(const float4*)&cmaxg[(long)(h * 128 + ct) * 2048 + r0 + rq];
    Lc[ct * 65 + rq]     = v.x;
    Lc[ct * 65 + rq + 1] = v.y;
    Lc[ct * 65 + rq + 2] = v.z;
    Lc[ct * 65 + rq + 3] = v.w;
  }
  __syncthreads();

  const int c0 = 2 * l, c1 = 2 * l + 1;
#pragma unroll 1
  for (int rs = 0; rs < 16; ++rs) {
    const int rloc = w * 16 + rs;
    const int qr = r0 + rloc;
    const int nctr = (qr >> 4) + 1;
    float v0 = (c0 < nctr) ? Lc[c0 * 65 + rloc] : NEGINF;
    float v1 = (c1 < nctr) ? Lc[c1 * 65 + rloc] : NEGINF;
    const float o0 = v0, o1 = v1;
    float T = NEGINF;
    for (int it = 0; it < 8; ++it) {
      float m = fmaxf(v0, v1);
#pragma unroll
      for (int o = 1; o < 64; o <<= 1) m = fmaxf(m, __shfl_xor(m, o));
      u64 bal = __ballot((v0 == m) || (v1 == m));
      int first = __ffsll(bal) - 1;
      if (l == first) { if (v0 == m) v0 = NEGINF; else v1 = NEGINF; }
      T = m;
    }
    bool okc0 = (c0 < nctr) && ((c0 < 8) || (o0 >= T));
    bool okc1 = (c1 < nctr) && ((c1 < 8) || (o1 >= T));
    u64 bE = __ballot(okc0);
    u64 bO = __ballot(okc1);
    bool al0 = (c0 < nctr) && (okc0 || (c0 * 16 + 15 > qr - 128));
    bool al1 = (c1 < nctr) && (okc1 || (c1 * 16 + 15 > qr - 128));
    float mv = fmaxf(al0 ? o0 : NEGINF, al1 ? o1 : NEGINF);
#pragma unroll
    for (int o = 1; o < 64; o <<= 1) mv = fmaxf(mv, __shfl_xor(mv, o));
    if (l == 0) {
      selEg[h * 2048 + qr] = bE;
      selOg[h * 2048 + qr] = bO;
      mxg[h * 2048 + qr] = mv;
    }
  }
}

// ---------------- P LDS swizzled index ----------------
__device__ __forceinline__ int pidx2(int r, int t) {
  return r * 32 + ((((t >> 3) ^ (r & 3)) << 3) | (t & 7));
}

// ======== K3: phase B ========
__global__ __launch_bounds__(256) void attnB(const unsigned short* __restrict__ Qh,
                                             const unsigned short* __restrict__ K2h,
                                             const unsigned short* __restrict__ V2,
                                             const u64* __restrict__ selEg,
                                             const u64* __restrict__ selOg,
                                             const float* __restrict__ mxg,
                                             unsigned short* __restrict__ AO) {
  __shared__ __align__(16) unsigned short Pls[4][512];
  __shared__ int clistS[4][128];

  const int qb = (int)gridDim.x - 1 - (int)blockIdx.x;
  const int kvh = blockIdx.y;
  const int q0 = qb * 16;
  const int nct = qb + 1;
  const int tid = threadIdx.x;
  const int w = tid >> 6, l = tid & 63;
  const int lr = l & 15, lg = l >> 4;
  const int h = kvh * 4 + w;

  bf16x8 qfh[4];
  {
    const unsigned short* qph = Qh + (long)(q0 + lr) * 4096 + h * 128 + lg * 8;
#pragma unroll
    for (int ks = 0; ks < 4; ++ks) qfh[ks] = *(const bf16x8*)(qph + ks * 32);
  }

  u64 myE = selEg[h * 2048 + q0 + lr];
  u64 myO = selOg[h * 2048 + q0 + lr];
  float mymx = mxg[h * 2048 + q0 + lr];

  u64 uE = myE, uO = myO;
#pragma unroll
  for (int o = 1; o < 16; o <<= 1) {
    uE |= __shfl_xor(uE, o);
    uO |= __shfl_xor(uO, o);
  }
  float mxj[4];
  u64 selE[4], selO[4];
#pragma unroll
  for (int j = 0; j < 4; ++j) {
    mxj[j] = __shfl(mymx, lg * 4 + j);
    selE[j] = __shfl(myE, lg * 4 + j);
    selO[j] = __shfl(myO, lg * 4 + j);
  }

  unsigned short* Pw = Pls[w];
  int* cl = clistS[w];

  const int c0 = 2 * l, c1 = 2 * l + 1;
  bool s0ok = (c0 < nct) && (((uE >> l) & 1ull) || (c0 >= qb - 7));
  bool s1ok = (c1 < nct) && (((uO >> l) & 1ull) || (c1 >= qb - 7));
  u64 bA = __ballot(s0ok);
  u64 bB = __ballot(s1ok);
  const int cntA = __popcll(bA);
  const int nsel = cntA + __popcll(bB);
  if (s0ok) cl[__popcll(bA & ((1ull << l) - 1ull))] = c0;
  if (s1ok) cl[cntA + __popcll(bB & ((1ull << l) - 1ull))] = c1;

  const unsigned short* kbh = K2h + (long)kvh * 128 * 2048;

  f32x4 pacc[8] = {};
  float psum[4] = {0.f, 0.f, 0.f, 0.f};
  const int np = (nsel + 1) >> 1;

  bf16x8 kA[4], kB[4];
  {
    const int cA0 = cl[0];
    const int cB0 = (1 < nsel) ? cl[1] : cA0;
    const unsigned short* pA = kbh + (long)cA0 * 2048 + l * 8;
    const unsigned short* pB = kbh + (long)cB0 * 2048 + l * 8;
#pragma unroll
    for (int ks = 0; ks < 4; ++ks) {
      kA[ks] = *(const bf16x8*)(pA + ks * 512);
      kB[ks] = *(const bf16x8*)(pB + ks * 512);
    }
  }

  for (int pi = 0; pi < np; ++pi) {
    const int cA = cl[2 * pi];
    const int iB = 2 * pi + 1;
    const int cB = (iB < nsel) ? cl[iB] : cA;

    const int csel = (lg < 2) ? cA : cB;
    const unsigned short* vp = V2 + (long)(kvh * 128 + csel) * 2048 + ((lg & 1) * 16 + lr) * 8;
    bf16x8 vf[8];
#pragma unroll
    for (int dblk = 0; dblk < 8; ++dblk) vf[dblk] = *(const bf16x8*)(vp + dblk * 256);

    bf16x8 nA[4], nB[4];
    {
      const int pin = (pi + 1 < np) ? pi + 1 : pi;
      const int cA1 = cl[2 * pin];
      const int iB1 = 2 * pin + 1;
      const int cB1 = (iB1 < nsel) ? cl[iB1] : cA1;
      const unsigned short* pA = kbh + (long)cA1 * 2048 + l * 8;
      const unsigned short* pB = kbh + (long)cB1 * 2048 + l * 8;
#pragma unroll
      for (int ks = 0; ks < 4; ++ks) {
        nA[ks] = *(const bf16x8*)(pA + ks * 512);
        nB[ks] = *(const bf16x8*)(pB + ks * 512);
      }
    }

#pragma unroll
    for (int half = 0; half < 2; ++half) {
      const int c = half ? cB : cA;
      const bool vslot = (2 * pi + half) < nsel;
      f32x4 acc = {};
#pragma unroll
      for (int ks = 0; ks < 4; ++ks) {
        bf16x8 kf = half ? kB[ks] : kA[ks];
        acc = __builtin_amdgcn_mfma_f32_16x16x32_bf16(qfh[ks], kf, acc, 0, 0, 0);
      }
#pragma unroll
      for (int j = 0; j < 4; ++j) {
        const int r = lg * 4 + j;
        const int qrr = q0 + r;
        const int tok = c * 16 + lr;
        u64 sm = (c & 1) ? selO[j] : selE[j];
        bool sel = (sm >> (c >> 1)) & 1ull;
        bool al = vslot && (tok <= qrr) && (sel || (tok > qrr - 128));
        float p = al ? __expf(acc[j] - mxj[j]) : 0.f;
        unsigned short pb = f2bf(p);
        psum[j] += bf2f(pb);
        Pw[pidx2(r, half * 16 + lr)] = pb;
      }
    }
    bf16x8 pa = *(const bf16x8*)&Pw[pidx2(lr, lg * 8)];
#pragma unroll
    for (int dblk = 0; dblk < 8; ++dblk)
      pacc[dblk] = __builtin_amdgcn_mfma_f32_16x16x32_bf16(pa, vf[dblk], pacc[dblk], 0, 0, 0);

#pragma unroll
    for (int ks = 0; ks < 4; ++ks) { kA[ks] = nA[ks]; kB[ks] = nB[ks]; }
  }

#pragma unroll
  for (int j = 0; j < 4; ++j) {
    float s = psum[j];
    s += __shfl_xor(s, 1); s += __shfl_xor(s, 2);
    s += __shfl_xor(s, 4); s += __shfl_xor(s, 8);
    const float rd = 1.0f / s;
    const int r = lg * 4 + j;
#pragma unroll
    for (int dblk = 0; dblk < 8; ++dblk)
      AO[(long)(q0 + r) * 4096 + h * 128 + dblk * 16 + lr] = f2bf(pacc[dblk][j] * rd);
  }
}

// ---------------- launch ----------------
extern "C" void kernel_launch(void* const* d_in, const int* in_sizes, int n_in,
                              void* d_out, int out_size, void* d_ws, size_t ws_size,
                              hipStream_t stream) {
  const float* hidden = (const float*)d_in[0];
  const float* wq = (const float*)d_in[1];
  const float* wk = (const float*)d_in[2];
  const float* wv = (const float*)d_in[3];
  const float* wo = (const float*)d_in[4];
  float* out = (float*)d_out;

  unsigned short* hb_hi = (unsigned short*)d_ws;          // [2048][4096]
  unsigned short* hb_lo = hb_hi + (size_t)2048 * 4096;
  unsigned short* wq_hi = hb_lo + (size_t)2048 * 4096;    // [4096][4096]
  unsigned short* wq_lo = wq_hi + (size_t)4096 * 4096;
  unsigned short* wk_hi = wq_lo + (size_t)4096 * 4096;    // [1024][4096]
  unsigned short* wk_lo = wk_hi + (size_t)1024 * 4096;
  unsigned short* wv_b  = wk_lo + (size_t)1024 * 4096;    // [1024][4096]
  unsigned short* wo_b  = wv_b  + (size_t)1024 * 4096;    // [4096][4096]
  unsigned short* Qhi = wo_b + (size_t)4096 * 4096;       // [2048][4096] bf16
  unsigned short* Qlo = Qhi + (size_t)2048 * 4096;
  unsigned short* K2h = Qlo + (size_t)2048 * 4096;        // frag-major
  unsigned short* K2l = K2h + (size_t)2048 * 1024;
  unsigned short* V2  = K2l + (size_t)2048 * 1024;        // frag-major
  unsigned short* AO = hb_hi;         // hidden splits dead after projections
  float* cmaxg = (float*)wq_hi;       // wq splits dead after projections
  u64* selEg = (u64*)wk_hi;           // wk splits dead after projections
  u64* selOg = selEg + 32 * 2048;
  float* mxg = (float*)(selOg + 32 * 2048);
  float* ctab = out;                  // staged in d_out; fully overwritten by o8ph
  float* stab = ctab + 2048 * 64;

  cvt_all<<<49152, 256, 0, stream>>>(hidden, wq, wk, wv, wo,
                                     hb_hi, hb_lo, wq_hi, wq_lo,
                                     wk_hi, wk_lo, wv_b, wo_b);
  rope_table<<<512, 256, 0, stream>>>(ctab, stab);

  qkv_gemm<<<256, 256, 0, stream>>>(hb_hi, hb_lo, wk_hi, wk_lo, wv_b,
                                    ctab, stab, K2h, K2l, V2);
  q8ph<<<256, 512, 0, stream>>>(hb_hi, hb_lo, wq_hi, wq_lo,
                                ctab, stab, Qhi, Qlo);

  cmax_gemm<<<dim3(16, 32), 256, 0, stream>>>(Qhi, Qlo, K2h, K2l, cmaxg);
  select_kernel<<<dim3(32, 32), 256, 0, stream>>>(cmaxg, selEg, selOg, mxg);
  attnB<<<dim3(128, 8), 256, 0, stream>>>(Qhi, K2h, V2, selEg, selOg, mxg, AO);

  o8ph<<<256, 512, 0, stream>>>(AO, wo_b, out);
}

// Round 15
// 673.149 us; speedup vs baseline: 1.0729x; 1.0080x over previous
//
#include <hip/hip_runtime.h>
#include <math.h>

typedef __attribute__((ext_vector_type(4))) float f32x4;
typedef __attribute__((ext_vector_type(8))) __bf16 bf16x8;
typedef __attribute__((ext_vector_type(4))) unsigned short us4;
typedef unsigned long long u64;

__device__ __forceinline__ unsigned short f2bf(float f) {
  unsigned int u = __float_as_uint(f);
  u += 0x7fffu + ((u >> 16) & 1u);            // RNE
  return (unsigned short)(u >> 16);
}
__device__ __forceinline__ float bf2f(unsigned short h) {
  return __uint_as_float(((unsigned int)h) << 16);
}

__device__ __forceinline__ void gload16(const void* g, void* l) {
  __builtin_amdgcn_global_load_lds(
      (__attribute__((address_space(1))) void*)g,
      (__attribute__((address_space(3))) void*)l, 16, 0, 0);
}

// ---------------- K2 fragment-major index: K element (s, kvh, d) ----------------
__device__ __forceinline__ long k2idx(int kvh, int s, int d) {
  int ct = s >> 4;
  int lane = (((d & 31) >> 3) << 4) | (s & 15);
  return ((long)(kvh * 128 + ct) * 4 + (d >> 5)) * 512 + lane * 8 + (d & 7);
}

// ---------------- fused fp32 -> bf16 conversions ----------------
__device__ __forceinline__ void split1(const float* __restrict__ in,
                                       unsigned short* __restrict__ hi,
                                       unsigned short* __restrict__ lo, int i) {
  float4 v = ((const float4*)in)[i];
  us4 h, l;
  float vv[4] = {v.x, v.y, v.z, v.w};
#pragma unroll
  for (int j = 0; j < 4; ++j) {
    unsigned short hh = f2bf(vv[j]);
    h[j] = hh;
    l[j] = f2bf(vv[j] - bf2f(hh));
  }
  ((us4*)hi)[i] = h;
  ((us4*)lo)[i] = l;
}
__device__ __forceinline__ void plain1(const float* __restrict__ in,
                                       unsigned short* __restrict__ out, int i) {
  float4 v = ((const float4*)in)[i];
  us4 o;
  o[0] = f2bf(v.x); o[1] = f2bf(v.y); o[2] = f2bf(v.z); o[3] = f2bf(v.w);
  ((us4*)out)[i] = o;
}

__global__ __launch_bounds__(256) void cvt_all(const float* __restrict__ hidden,
                                               const float* __restrict__ wq,
                                               const float* __restrict__ wk,
                                               const float* __restrict__ wv,
                                               const float* __restrict__ wo,
                                               unsigned short* __restrict__ hb_hi,
                                               unsigned short* __restrict__ hb_lo,
                                               unsigned short* __restrict__ wq_hi,
                                               unsigned short* __restrict__ wq_lo,
                                               unsigned short* __restrict__ wk_hi,
                                               unsigned short* __restrict__ wk_lo,
                                               unsigned short* __restrict__ wv_b,
                                               unsigned short* __restrict__ wo_b) {
  int i = blockIdx.x * 256 + threadIdx.x;
  if (i < 2097152)       split1(hidden, hb_hi, hb_lo, i);
  else if (i < 6291456)  split1(wq, wq_hi, wq_lo, i - 2097152);
  else if (i < 7340032)  split1(wk, wk_hi, wk_lo, i - 6291456);
  else if (i < 8388608)  plain1(wv, wv_b, i - 7340032);
  else if (i < 12582912) plain1(wo, wo_b, i - 8388608);
}

// ---------------- RoPE angle table (staged in d_out; overwritten by final GEMM) ----------------
__global__ __launch_bounds__(256) void rope_table(float* __restrict__ ctab,
                                                  float* __restrict__ stab) {
  int idx = blockIdx.x * 256 + threadIdx.x;   // 2048*64
  if (idx >= 2048 * 64) return;
  int s = idx >> 6, d = idx & 63;
  float inv = powf(10000.0f, -(float)d * (1.0f / 64.0f));
  float ang = (float)s * inv;
  ctab[idx] = cosf(ang);
  stab[idx] = sinf(ang);
}

// ======== Q-proj: 2-coarse-phase counted-vmcnt 3-term GEMM + rope epilogue ========
// (round-13 q8ph with phases merged 4->2: 24 MFMA per barrier-pair, identical math/order)
__global__ __launch_bounds__(512, 2) void q8ph(const unsigned short* __restrict__ Ahg,
                                               const unsigned short* __restrict__ Alg,
                                               const unsigned short* __restrict__ wq_hi,
                                               const unsigned short* __restrict__ wq_lo,
                                               const float* __restrict__ ctab,
                                               const float* __restrict__ stab,
                                               unsigned short* __restrict__ Qh,
                                               unsigned short* __restrict__ Ql) {
  __shared__ __align__(16) unsigned short shb[73728];   // 144 KB
  const int bid = blockIdx.x;
  const int tid = threadIdx.x;
  const int w = tid >> 6, l = tid & 63;
  const int lr = l & 15, lg = l >> 4;
  const int wr = w >> 2, wc = w & 3;
  const int nt = 128;

  const int m_idx = (bid & 7) * 2 + ((bid >> 3) & 1);   // A-pair pinned per XCD
  const int n_idx = bid >> 4;
  const long m0 = (long)m_idx * 128;
  const long n0 = (long)n_idx * 256;

  const int arow = tid >> 2;
  const int kg = ((tid & 3) ^ ((tid >> 2) & 3) ^ ((tid >> 4) & 3)) & 3;
  const long aoff  = (m0 + arow) * 4096 + kg * 8;
  const long boff0 = (n0 + arow) * 4096 + kg * 8;
  const long boff1 = (n0 + 128 + arow) * 4096 + kg * 8;
  const int dstw = w * 512;

  const int xk = (lg ^ (lr & 3) ^ ((lr >> 2) & 3)) & 3;

#define QSTG_A(t, bs)                                                         \
  { gload16(Ahg + aoff + (long)(t) * 32, &shb[(bs) * 4096 + dstw]);           \
    gload16(Alg + aoff + (long)(t) * 32, &shb[12288 + (bs) * 4096 + dstw]); }
#define QSTG_BH(t, bs)                                                        \
  { gload16(wq_hi + boff0 + (long)(t) * 32, &shb[24576 + (bs) * 8192 + dstw]);\
    gload16(wq_hi + boff1 + (long)(t) * 32, &shb[24576 + (bs) * 8192 + 4096 + dstw]); }
#define QSTG_BL(t, bs)                                                        \
  { gload16(wq_lo + boff0 + (long)(t) * 32, &shb[49152 + (bs) * 8192 + dstw]);\
    gload16(wq_lo + boff1 + (long)(t) * 32, &shb[49152 + (bs) * 8192 + 4096 + dstw]); }

  f32x4 acc[4][4] = {};

  QSTG_A(0, 0); QSTG_BH(0, 0); QSTG_BL(0, 0);
  QSTG_A(1, 1); QSTG_BH(1, 1); QSTG_BL(1, 1);
  QSTG_A(2, 2); QSTG_BH(2, 2); QSTG_BL(2, 2);
  asm volatile("s_waitcnt vmcnt(12)" ::: "memory");
  __builtin_amdgcn_s_barrier();
  __builtin_amdgcn_sched_barrier(0);

#define QPH_ENTER                                        \
  __builtin_amdgcn_sched_barrier(0);                     \
  __builtin_amdgcn_s_barrier();                          \
  asm volatile("s_waitcnt lgkmcnt(0)" ::: "memory");     \
  __builtin_amdgcn_sched_barrier(0);                     \
  __builtin_amdgcn_s_setprio(1);
#define QPH_EXIT                                         \
  __builtin_amdgcn_s_setprio(0);                         \
  __builtin_amdgcn_sched_barrier(0);                     \
  __builtin_amdgcn_s_barrier();                          \
  __builtin_amdgcn_sched_barrier(0);
#define QPH_MFMA(p, bh, bl)                                                                    \
  _Pragma("unroll")                                                                            \
  for (int mi = 0; mi < 4; ++mi) {                                                             \
    acc[mi][p] = __builtin_amdgcn_mfma_f32_16x16x32_bf16(afh[mi], bh, acc[mi][p], 0, 0, 0);    \
    acc[mi][p] = __builtin_amdgcn_mfma_f32_16x16x32_bf16(afl[mi], bh, acc[mi][p], 0, 0, 0);    \
    acc[mi][p] = __builtin_amdgcn_mfma_f32_16x16x32_bf16(afh[mi], bl, acc[mi][p], 0, 0, 0);    \
  }
#define QPH_RDB(p, bh, bl)                                                          \
  { int rowb = wc * 64 + (p) * 16 + lr;                                             \
    bh = *(const bf16x8*)&shb[24576 + bs * 8192 + rowb * 32 + xk * 8];              \
    bl = *(const bf16x8*)&shb[49152 + bs * 8192 + rowb * 32 + xk * 8]; }

  for (int t = 0; t < nt; ++t) {
    const int bs = t % 3;
    const int bss = (t + 2) % 3;
    const bool st = (t + 2) < nt;
    bf16x8 afh[4], afl[4], bh0, bl0, bh1, bl1, bh2, bl2, bh3, bl3;
    // ---- coarse phase A: A frags + B(0,1); stage A+BH of t+2; 24 MFMA ----
#pragma unroll
    for (int mi = 0; mi < 4; ++mi) {
      int rowa = wr * 64 + mi * 16 + lr;
      afh[mi] = *(const bf16x8*)&shb[bs * 4096 + rowa * 32 + xk * 8];
      afl[mi] = *(const bf16x8*)&shb[12288 + bs * 4096 + rowa * 32 + xk * 8];
    }
    QPH_RDB(0, bh0, bl0);
    QPH_RDB(1, bh1, bl1);
    if (st) { QSTG_A(t + 2, bss); QSTG_BH(t + 2, bss); }
    QPH_ENTER;
    QPH_MFMA(0, bh0, bl0);
    QPH_MFMA(1, bh1, bl1);
    QPH_EXIT;
    // ---- coarse phase B: B(2,3); stage BL of t+2; counted vmcnt; 24 MFMA ----
    QPH_RDB(2, bh2, bl2);
    QPH_RDB(3, bh3, bl3);
    if (st) QSTG_BL(t + 2, bss);
    if (st) asm volatile("s_waitcnt vmcnt(6)" ::: "memory");
    else    asm volatile("s_waitcnt vmcnt(0)" ::: "memory");
    QPH_ENTER;
    QPH_MFMA(2, bh2, bl2);
    QPH_MFMA(3, bh3, bl3);
    QPH_EXIT;
  }
#undef QSTG_A
#undef QSTG_BH
#undef QSTG_BL
#undef QPH_ENTER
#undef QPH_EXIT
#undef QPH_MFMA
#undef QPH_RDB

  __syncthreads();
  float* Cls = (float*)shb;                              // 128x256 fp32 = 128 KB
#pragma unroll
  for (int mi = 0; mi < 4; ++mi)
#pragma unroll
    for (int ni = 0; ni < 4; ++ni)
#pragma unroll
      for (int j = 0; j < 4; ++j)
        Cls[(wr * 64 + mi * 16 + lg * 4 + j) * 256 + wc * 64 + ni * 16 + lr] = acc[mi][ni][j];
  __syncthreads();

  const int r0l = tid >> 3;
  const int d0 = (tid & 7) * 8;
#pragma unroll
  for (int h = 0; h < 2; ++h) {
    const int head = n_idx * 2 + h;
#pragma unroll
    for (int k = 0; k < 2; ++k) {
      const int r = r0l + 64 * k;
      const long s = m0 + r;
      float X1[8], X2[8], CC[8], SS[8];
      {
        f32x4 a = *(const f32x4*)&Cls[r * 256 + h * 128 + d0];
        f32x4 b = *(const f32x4*)&Cls[r * 256 + h * 128 + d0 + 4];
        f32x4 c = *(const f32x4*)&Cls[r * 256 + h * 128 + 64 + d0];
        f32x4 d = *(const f32x4*)&Cls[r * 256 + h * 128 + 64 + d0 + 4];
        f32x4 e = *(const f32x4*)&ctab[s * 64 + d0];
        f32x4 f = *(const f32x4*)&ctab[s * 64 + d0 + 4];
        f32x4 g = *(const f32x4*)&stab[s * 64 + d0];
        f32x4 hh = *(const f32x4*)&stab[s * 64 + d0 + 4];
#pragma unroll
        for (int j = 0; j < 4; ++j) {
          X1[j] = a[j]; X1[j + 4] = b[j];
          X2[j] = c[j]; X2[j + 4] = d[j];
          CC[j] = e[j]; CC[j + 4] = f[j];
          SS[j] = g[j]; SS[j + 4] = hh[j];
        }
      }
      us4 H1[2], L1[2], H2[2], L2[2];
#pragma unroll
      for (int j = 0; j < 8; ++j) {
        float y1 = (X1[j] * CC[j] - X2[j] * SS[j]) * 0.08838834764831845f;
        float y2 = (X2[j] * CC[j] + X1[j] * SS[j]) * 0.08838834764831845f;
        unsigned short h1 = f2bf(y1), h2 = f2bf(y2);
        H1[j >> 2][j & 3] = h1; L1[j >> 2][j & 3] = f2bf(y1 - bf2f(h1));
        H2[j >> 2][j & 3] = h2; L2[j >> 2][j & 3] = f2bf(y2 - bf2f(h2));
      }
      long row = s * 4096 + head * 128;
      *(us4*)&Qh[row + d0] = H1[0];      *(us4*)&Qh[row + d0 + 4] = H1[1];
      *(us4*)&Ql[row + d0] = L1[0];      *(us4*)&Ql[row + d0 + 4] = L1[1];
      *(us4*)&Qh[row + 64 + d0] = H2[0]; *(us4*)&Qh[row + 64 + d0 + 4] = H2[1];
      *(us4*)&Ql[row + 64 + d0] = L2[0]; *(us4*)&Ql[row + 64 + d0 + 4] = L2[1];
    }
  }
}

// ======== O-proj: 8-phase counted-vmcnt 1-term GEMM (round-14, unchanged) ========
__global__ __launch_bounds__(512, 2) void o8ph(const unsigned short* __restrict__ A,
                                               const unsigned short* __restrict__ B,
                                               float* __restrict__ C) {
  __shared__ __align__(16) unsigned short shb[36864];   // 72 KB
  const int bid = blockIdx.x;
  const int tid = threadIdx.x;
  const int w = tid >> 6, l = tid & 63;
  const int lr = l & 15, lg = l >> 4;
  const int wr = w >> 2, wc = w & 3;
  const int nt = 128;

  const int m_idx = (bid & 7) * 2 + ((bid >> 3) & 1);
  const int n_idx = bid >> 4;
  const long m0 = (long)m_idx * 128;
  const long n0 = (long)n_idx * 256;

  const int arow = tid >> 2;
  const int kg = ((tid & 3) ^ ((tid >> 2) & 3) ^ ((tid >> 4) & 3)) & 3;
  const long aoff  = (m0 + arow) * 4096 + kg * 8;
  const long boff0 = (n0 + arow) * 4096 + kg * 8;
  const long boff1 = (n0 + 128 + arow) * 4096 + kg * 8;
  const int dstw = w * 512;

  const int xk = (lg ^ (lr & 3) ^ ((lr >> 2) & 3)) & 3;

#define OSTG_A(t, bs)                                                        \
  gload16(A + aoff + (long)(t) * 32, &shb[(bs) * 4096 + dstw]);
#define OSTG_B0(t, bs)                                                       \
  gload16(B + boff0 + (long)(t) * 32, &shb[12288 + (bs) * 8192 + dstw]);
#define OSTG_B1(t, bs)                                                       \
  gload16(B + boff1 + (long)(t) * 32, &shb[12288 + (bs) * 8192 + 4096 + dstw]);

  f32x4 acc[4][4] = {};

  OSTG_A(0, 0); OSTG_B0(0, 0); OSTG_B1(0, 0);
  OSTG_A(1, 1); OSTG_B0(1, 1); OSTG_B1(1, 1);
  OSTG_A(2, 2); OSTG_B0(2, 2); OSTG_B1(2, 2);
  asm volatile("s_waitcnt vmcnt(6)" ::: "memory");
  __builtin_amdgcn_s_barrier();
  __builtin_amdgcn_sched_barrier(0);

#define OPH_ENTER                                        \
  __builtin_amdgcn_sched_barrier(0);                     \
  __builtin_amdgcn_s_barrier();                          \
  asm volatile("s_waitcnt lgkmcnt(0)" ::: "memory");     \
  __builtin_amdgcn_sched_barrier(0);                     \
  __builtin_amdgcn_s_setprio(1);
#define OPH_EXIT                                         \
  __builtin_amdgcn_s_setprio(0);                         \
  __builtin_amdgcn_sched_barrier(0);                     \
  __builtin_amdgcn_s_barrier();                          \
  __builtin_amdgcn_sched_barrier(0);
#define OPH_RDB(p, dst)                                                             \
  { int rowb = wc * 64 + (p) * 16 + lr;                                             \
    dst = *(const bf16x8*)&shb[12288 + bs * 8192 + (rowb & 127) * 32 +              \
                               ((rowb >> 7) & 1) * 4096 + xk * 8]; }

  for (int t = 0; t < nt; ++t) {
    const int bs = t % 3;
    const int bss = (t + 2) % 3;
    const bool st = (t + 2) < nt;
    bf16x8 af[4], bf0, bf1, bf2, bf3;
#pragma unroll
    for (int mi = 0; mi < 4; ++mi) {
      int rowa = wr * 64 + mi * 16 + lr;
      af[mi] = *(const bf16x8*)&shb[bs * 4096 + rowa * 32 + xk * 8];
    }
    OPH_RDB(0, bf0);
    OPH_RDB(1, bf1);
    if (st) { OSTG_A(t + 2, bss); OSTG_B0(t + 2, bss); }
    OPH_ENTER;
#pragma unroll
    for (int mi = 0; mi < 4; ++mi) {
      acc[mi][0] = __builtin_amdgcn_mfma_f32_16x16x32_bf16(af[mi], bf0, acc[mi][0], 0, 0, 0);
      acc[mi][1] = __builtin_amdgcn_mfma_f32_16x16x32_bf16(af[mi], bf1, acc[mi][1], 0, 0, 0);
    }
    OPH_EXIT;
    OPH_RDB(2, bf2);
    OPH_RDB(3, bf3);
    if (st) OSTG_B1(t + 2, bss);
    if (st) asm volatile("s_waitcnt vmcnt(3)" ::: "memory");
    else    asm volatile("s_waitcnt vmcnt(0)" ::: "memory");
    OPH_ENTER;
#pragma unroll
    for (int mi = 0; mi < 4; ++mi) {
      acc[mi][2] = __builtin_amdgcn_mfma_f32_16x16x32_bf16(af[mi], bf2, acc[mi][2], 0, 0, 0);
      acc[mi][3] = __builtin_amdgcn_mfma_f32_16x16x32_bf16(af[mi], bf3, acc[mi][3], 0, 0, 0);
    }
    OPH_EXIT;
  }
#undef OSTG_A
#undef OSTG_B0
#undef OSTG_B1
#undef OPH_ENTER
#undef OPH_EXIT
#undef OPH_RDB

#pragma unroll
  for (int mi = 0; mi < 4; ++mi)
#pragma unroll
    for (int ni = 0; ni < 4; ++ni)
#pragma unroll
      for (int j = 0; j < 4; ++j) {
        long r = m0 + wr * 64 + mi * 16 + lg * 4 + j;
        long cc = n0 + wc * 64 + ni * 16 + lr;
        C[r * 4096 + cc] = acc[mi][ni][j];
      }
}

// ======== K/V projection (round-12/13 qkv_gemm, unchanged) ========
__global__ __launch_bounds__(256) void qkv_gemm(const unsigned short* __restrict__ Ahg,
                                                const unsigned short* __restrict__ Alg,
                                                const unsigned short* __restrict__ wk_hi,
                                                const unsigned short* __restrict__ wk_lo,
                                                const unsigned short* __restrict__ wv_b,
                                                const float* __restrict__ ctab,
                                                const float* __restrict__ stab,
                                                unsigned short* __restrict__ K2h,
                                                unsigned short* __restrict__ K2l,
                                                unsigned short* __restrict__ V2) {
  __shared__ __align__(16) unsigned short shb[32768];   // 64 KB
  const int bid = blockIdx.x;
  const int tid = threadIdx.x;
  const int w = tid >> 6, l = tid & 63;
  const int wm = w >> 1, wn = w & 1;
  const int lr = l & 15, lg = l >> 4;
  const int K = 4096;
  const int nt = K >> 5;

  if (bid >= 128) {
    const int b3 = bid - 128;
    const long m0 = (long)((b3 & 7) * 2 + ((b3 >> 3) & 1)) * 128;
    const long n0 = (long)(b3 >> 4) * 128;
    f32x4 acc[4][4] = {};
    const int c0 = w * 128 + l;
    const int c1 = c0 + 64;
    const unsigned short* gA0 = Ahg + (m0 + (c0 >> 2)) * K + (c0 & 3) * 8;
    const unsigned short* gA1 = Ahg + (m0 + (c1 >> 2)) * K + (c1 & 3) * 8;
    const unsigned short* gB0 = wv_b + (n0 + (c0 >> 2)) * K + (c0 & 3) * 8;
    const unsigned short* gB1 = wv_b + (n0 + (c1 >> 2)) * K + (c1 & 3) * 8;

#define STAGE1(t, b)                                         \
  {                                                          \
    long kt = (long)(t) * 32;                                \
    gload16(gA0 + kt, &shb[(b) * 4096 + w * 1024]);          \
    gload16(gA1 + kt, &shb[(b) * 4096 + w * 1024 + 512]);    \
    gload16(gB0 + kt, &shb[16384 + (b) * 4096 + w * 1024]);  \
    gload16(gB1 + kt, &shb[16384 + (b) * 4096 + w * 1024 + 512]); \
  }
    STAGE1(0, 0);
    STAGE1(1, 1);
    for (int t = 0; t < nt; ++t) {
      if (t + 1 < nt) asm volatile("s_waitcnt vmcnt(4)" ::: "memory");
      else            asm volatile("s_waitcnt vmcnt(0)" ::: "memory");
      __builtin_amdgcn_s_barrier();
      __builtin_amdgcn_sched_barrier(0);
      const int b = t & 1;
      bf16x8 af[4], bfr[4];
#pragma unroll
      for (int mi = 0; mi < 4; ++mi)
        af[mi] = *(const bf16x8*)&shb[b * 4096 + (wm * 64 + mi * 16 + lr) * 32 + lg * 8];
#pragma unroll
      for (int ni = 0; ni < 4; ++ni)
        bfr[ni] = *(const bf16x8*)&shb[16384 + b * 4096 + (wn * 64 + ni * 16 + lr) * 32 + lg * 8];
#pragma unroll
      for (int mi = 0; mi < 4; ++mi)
#pragma unroll
        for (int ni = 0; ni < 4; ++ni)
          acc[mi][ni] = __builtin_amdgcn_mfma_f32_16x16x32_bf16(af[mi], bfr[ni], acc[mi][ni], 0, 0, 0);
      __builtin_amdgcn_sched_barrier(0);
      __builtin_amdgcn_s_barrier();
      __builtin_amdgcn_sched_barrier(0);
      if (t + 2 < nt) STAGE1(t + 2, b);
    }
#undef STAGE1
#pragma unroll
    for (int mi = 0; mi < 4; ++mi)
#pragma unroll
      for (int ni = 0; ni < 4; ++ni)
#pragma unroll
        for (int j = 0; j < 4; ++j) {
          long r = m0 + wm * 64 + mi * 16 + lg * 4 + j;
          long cc = n0 + wn * 64 + ni * 16 + lr;
          int kvh = (int)(cc >> 7), d = (int)(cc & 127);
          int c = (int)(r >> 4), t2 = (int)(r & 15);
          long idx = ((long)(kvh * 128 + c) * 8 + (d >> 4)) * 256 + ((t2 >> 3) * 16 + (d & 15)) * 8 + (t2 & 7);
          V2[idx] = f2bf(acc[mi][ni][j]);
        }
    return;
  }

  const long m0 = (long)((bid & 7) * 2 + ((bid >> 3) & 1)) * 128;
  const long n0 = (long)(bid >> 4) * 128;

  f32x4 acc[4][4] = {};
  const int c0 = w * 128 + l;
  const int c1 = c0 + 64;
  const long oA0 = (m0 + (c0 >> 2)) * K + (c0 & 3) * 8;
  const long oA1 = (m0 + (c1 >> 2)) * K + (c1 & 3) * 8;
  const long oB0 = (n0 + (c0 >> 2)) * K + (c0 & 3) * 8;
  const long oB1 = (n0 + (c1 >> 2)) * K + (c1 & 3) * 8;

#define STAGE3(t, b)                                               \
  {                                                                \
    long kt = (long)(t) * 32;                                      \
    gload16(Ahg + oA0 + kt, &shb[(b) * 4096 + w * 1024]);          \
    gload16(Ahg + oA1 + kt, &shb[(b) * 4096 + w * 1024 + 512]);    \
    gload16(Alg + oA0 + kt, &shb[8192 + (b) * 4096 + w * 1024]);   \
    gload16(Alg + oA1 + kt, &shb[8192 + (b) * 4096 + w * 1024 + 512]); \
    gload16(wk_hi + oB0 + kt, &shb[16384 + (b) * 4096 + w * 1024]);   \
    gload16(wk_hi + oB1 + kt, &shb[16384 + (b) * 4096 + w * 1024 + 512]); \
    gload16(wk_lo + oB0 + kt, &shb[24576 + (b) * 4096 + w * 1024]);   \
    gload16(wk_lo + oB1 + kt, &shb[24576 + (b) * 4096 + w * 1024 + 512]); \
  }
  STAGE3(0, 0);
  STAGE3(1, 1);
  for (int t = 0; t < nt; ++t) {
    if (t + 1 < nt) asm volatile("s_waitcnt vmcnt(8)" ::: "memory");
    else            asm volatile("s_waitcnt vmcnt(0)" ::: "memory");
    __builtin_amdgcn_s_barrier();
    __builtin_amdgcn_sched_barrier(0);
    const int b = t & 1;
    bf16x8 afh[4], afl[4], bfh[4], bfl[4];
#pragma unroll
    for (int mi = 0; mi < 4; ++mi) {
      afh[mi] = *(const bf16x8*)&shb[b * 4096 + (wm * 64 + mi * 16 + lr) * 32 + lg * 8];
      afl[mi] = *(const bf16x8*)&shb[8192 + b * 4096 + (wm * 64 + mi * 16 + lr) * 32 + lg * 8];
    }
#pragma unroll
    for (int ni = 0; ni < 4; ++ni) {
      bfh[ni] = *(const bf16x8*)&shb[16384 + b * 4096 + (wn * 64 + ni * 16 + lr) * 32 + lg * 8];
      bfl[ni] = *(const bf16x8*)&shb[24576 + b * 4096 + (wn * 64 + ni * 16 + lr) * 32 + lg * 8];
    }
#pragma unroll
    for (int mi = 0; mi < 4; ++mi)
#pragma unroll
      for (int ni = 0; ni < 4; ++ni) {
        acc[mi][ni] = __builtin_amdgcn_mfma_f32_16x16x32_bf16(afh[mi], bfh[ni], acc[mi][ni], 0, 0, 0);
        acc[mi][ni] = __builtin_amdgcn_mfma_f32_16x16x32_bf16(afl[mi], bfh[ni], acc[mi][ni], 0, 0, 0);
        acc[mi][ni] = __builtin_amdgcn_mfma_f32_16x16x32_bf16(afh[mi], bfl[ni], acc[mi][ni], 0, 0, 0);
      }
    __builtin_amdgcn_sched_barrier(0);
    __builtin_amdgcn_s_barrier();
    __builtin_amdgcn_sched_barrier(0);
    if (t + 2 < nt) STAGE3(t + 2, b);
  }
#undef STAGE3

  __syncthreads();
  float* Cls = (float*)shb;
#pragma unroll
  for (int mi = 0; mi < 4; ++mi)
#pragma unroll
    for (int ni = 0; ni < 4; ++ni)
#pragma unroll
      for (int j = 0; j < 4; ++j)
        Cls[(wm * 64 + mi * 16 + lg * 4 + j) * 128 + (wn * 64 + ni * 16 + lr)] = acc[mi][ni][j];
  __syncthreads();

  const int kvh = (int)(n0 >> 7);
  const int r0l = tid >> 3;
  const int d0 = (tid & 7) * 8;
#pragma unroll
  for (int k = 0; k < 4; ++k) {
    const int r = r0l + 32 * k;
    const long s = m0 + r;
    float X1[8], X2[8], CC[8], SS[8];
    {
      f32x4 a = *(const f32x4*)&Cls[r * 128 + d0];
      f32x4 b = *(const f32x4*)&Cls[r * 128 + d0 + 4];
      f32x4 c = *(const f32x4*)&Cls[r * 128 + 64 + d0];
      f32x4 d = *(const f32x4*)&Cls[r * 128 + 64 + d0 + 4];
      f32x4 e = *(const f32x4*)&ctab[s * 64 + d0];
      f32x4 f = *(const f32x4*)&ctab[s * 64 + d0 + 4];
      f32x4 g = *(const f32x4*)&stab[s * 64 + d0];
      f32x4 h = *(const f32x4*)&stab[s * 64 + d0 + 4];
#pragma unroll
      for (int j = 0; j < 4; ++j) {
        X1[j] = a[j]; X1[j + 4] = b[j];
        X2[j] = c[j]; X2[j + 4] = d[j];
        CC[j] = e[j]; CC[j + 4] = f[j];
        SS[j] = g[j]; SS[j + 4] = h[j];
      }
    }
    us4 H1[2], L1[2], H2[2], L2[2];
#pragma unroll
    for (int j = 0; j < 8; ++j) {
      float y1 = X1[j] * CC[j] - X2[j] * SS[j];
      float y2 = X2[j] * CC[j] + X1[j] * SS[j];
      unsigned short h1 = f2bf(y1), h2 = f2bf(y2);
      H1[j >> 2][j & 3] = h1; L1[j >> 2][j & 3] = f2bf(y1 - bf2f(h1));
      H2[j >> 2][j & 3] = h2; L2[j >> 2][j & 3] = f2bf(y2 - bf2f(h2));
    }
    long i1 = k2idx(kvh, (int)s, d0);
    long i2 = k2idx(kvh, (int)s, d0 + 64);
    *(us4*)&K2h[i1] = H1[0]; *(us4*)&K2h[i1 + 4] = H1[1];
    *(us4*)&K2l[i1] = L1[0]; *(us4*)&K2l[i1 + 4] = L1[1];
    *(us4*)&K2h[i2] = H2[0]; *(us4*)&K2h[i2 + 4] = H2[1];
    *(us4*)&K2l[i2] = L2[0]; *(us4*)&K2l[i2 + 4] = L2[1];
  }
}

// ======== K1: cmax GEMM, 4-deep counted-vmcnt pipeline. ========
__global__ __launch_bounds__(256, 2) void cmax_gemm(const unsigned short* __restrict__ Qh,
                                                    const unsigned short* __restrict__ Ql,
                                                    const unsigned short* __restrict__ K2h,
                                                    const unsigned short* __restrict__ K2l,
                                                    float* __restrict__ cmaxg) {
  __shared__ __align__(16) unsigned short Ksh[4][4096];
  __shared__ __align__(16) unsigned short Ksl[4][4096];
  const int qp = 15 - (int)blockIdx.x;
  const int h = blockIdx.y;
  const int kvh = h >> 2;
  const int q0 = qp * 128;
  const int tid = threadIdx.x;
  const int w = tid >> 6, l = tid & 63;
  const int lr = l & 15, lg = l >> 4;
  const int npan = 4 * (qp + 1);
  const float NEGINF = -__builtin_inff();

  bf16x8 qfh[2][4], qfl[2][4];
#pragma unroll
  for (int rg = 0; rg < 2; ++rg) {
    const unsigned short* qph = Qh + (long)(q0 + w * 32 + rg * 16 + lr) * 4096 + h * 128 + lg * 8;
    const unsigned short* qpl = Ql + (long)(q0 + w * 32 + rg * 16 + lr) * 4096 + h * 128 + lg * 8;
#pragma unroll
    for (int ks = 0; ks < 4; ++ks) {
      qfh[rg][ks] = *(const bf16x8*)(qph + ks * 32);
      qfl[rg][ks] = *(const bf16x8*)(qpl + ks * 32);
    }
  }

  const unsigned short* kbh = K2h + (long)kvh * 128 * 2048;
  const unsigned short* kbl = K2l + (long)kvh * 128 * 2048;

#define STAGE(kp, b)                                                       \
  {                                                                        \
    long off = (long)(kp) * 4096;                                          \
    _Pragma("unroll")                                                      \
    for (int i = 0; i < 2; ++i) {                                          \
      int cu = w * 128 + i * 64;                                           \
      gload16(kbh + off + (cu + l) * 8, &Ksh[b][cu * 8]);                  \
      gload16(kbl + off + (cu + l) * 8, &Ksl[b][cu * 8]);                  \
    }                                                                      \
  }

  STAGE(0, 0);
  if (1 < npan) STAGE(1, 1);
  if (2 < npan) STAGE(2, 2);

  for (int kp = 0; kp < npan; ++kp) {
    {
      int ahead = npan - 1 - kp; if (ahead > 2) ahead = 2;
      int st = kp; if (st > 3) st = 3;
      int tgt = 4 * ahead + 4 * st;
      if (tgt >= 20)      asm volatile("s_waitcnt vmcnt(20)" ::: "memory");
      else if (tgt >= 16) asm volatile("s_waitcnt vmcnt(16)" ::: "memory");
      else if (tgt >= 12) asm volatile("s_waitcnt vmcnt(12)" ::: "memory");
      else if (tgt >= 8)  asm volatile("s_waitcnt vmcnt(8)" ::: "memory");
      else                asm volatile("s_waitcnt vmcnt(0)" ::: "memory");
    }
    __builtin_amdgcn_s_barrier();
    __builtin_amdgcn_sched_barrier(0);
    if (kp + 3 < npan) STAGE(kp + 3, (kp + 3) & 3);
    const int b = kp & 3;
#pragma unroll
    for (int c2 = 0; c2 < 2; ++c2) {
      const int ct = kp * 2 + c2;
      bf16x8 kh[4], kl2[4];
#pragma unroll
      for (int ks = 0; ks < 4; ++ks) {
        kh[ks]  = *(const bf16x8*)&Ksh[b][(c2 * 4 + ks) * 512 + l * 8];
        kl2[ks] = *(const bf16x8*)&Ksl[b][(c2 * 4 + ks) * 512 + l * 8];
      }
#pragma unroll
      for (int rg = 0; rg < 2; ++rg) {
        f32x4 acc = {};
#pragma unroll
        for (int ks = 0; ks < 4; ++ks) {
          acc = __builtin_amdgcn_mfma_f32_16x16x32_bf16(kh[ks], qfh[rg][ks], acc, 0, 0, 0);
          acc = __builtin_amdgcn_mfma_f32_16x16x32_bf16(kh[ks], qfl[rg][ks], acc, 0, 0, 0);
          acc = __builtin_amdgcn_mfma_f32_16x16x32_bf16(kl2[ks], qfh[rg][ks], acc, 0, 0, 0);
        }
        const int rbase = q0 + w * 32 + rg * 16;
        float m;
        if (ct * 16 + 15 <= rbase) {
          m = fmaxf(fmaxf(acc[0], acc[1]), fmaxf(acc[2], acc[3]));
        } else {
          m = NEGINF;
#pragma unroll
          for (int j = 0; j < 4; ++j) {
            int tok = ct * 16 + lg * 4 + j;
            if (tok <= rbase + lr) m = fmaxf(m, acc[j]);
          }
        }
        m = fmaxf(m, __shfl_xor(m, 16));
        m = fmaxf(m, __shfl_xor(m, 32));
        if (l < 16) cmaxg[(long)(h * 128 + ct) * 2048 + rbase + l] = m;
      }
    }
  }
#undef STAGE
}

// ======== K2: per-row top-8 selection. ========
__global__ __launch_bounds__(256) void select_kernel(const float* __restrict__ cmaxg,
                                                     u64* __restrict__ selEg,
                                                     u64* __restrict__ selOg,
                                                     float* __restrict__ mxg) {
  __shared__ float Lc[128 * 65];
  const int r0 = (int)blockIdx.x * 64;
  const int h = blockIdx.y;
  const int tid = threadIdx.x;
  const int w = tid >> 6, l = tid & 63;
  const float NEGINF = -__builtin_inff();

  for (int i = tid; i < 128 * 16; i += 256) {
    int ct = i >> 4, rq = (i & 15) * 4;
    float4 v = *(const float4*)&cmaxg[(long)(h * 128 + ct) * 2048 + r0 + rq];
    Lc[ct * 65 + rq]     = v.x;
    Lc[ct * 65 + rq + 1] = v.y;
    Lc[ct * 65 + rq + 2] = v.z;
    Lc[ct * 65 + rq + 3] = v.w;
  }
  __syncthreads();

  const int c0 = 2 * l, c1 = 2 * l + 1;
#pragma unroll 1
  for (int rs = 0; rs < 16; ++rs) {
    const int rloc = w * 16 + rs;
    const int qr = r0 + rloc;
    const int nctr = (qr >> 4) + 1;
    float v0 = (c0 < nctr) ? Lc[c0 * 65 + rloc] : NEGINF;
    float v1 = (c1 < nctr) ? Lc[c1 * 65 + rloc] : NEGINF;
    const float o0 = v0, o1 = v1;
    float T = NEGINF;
    for (int it = 0; it < 8; ++it) {
      float m = fmaxf(v0, v1);
#pragma unroll
      for (int o = 1; o < 64; o <<= 1) m = fmaxf(m, __shfl_xor(m, o));
      u64 bal = __ballot((v0 == m) || (v1 == m));
      int first = __ffsll(bal) - 1;
      if (l == first) { if (v0 == m) v0 = NEGINF; else v1 = NEGINF; }
      T = m;
    }
    bool okc0 = (c0 < nctr) && ((c0 < 8) || (o0 >= T));
    bool okc1 = (c1 < nctr) && ((c1 < 8) || (o1 >= T));
    u64 bE = __ballot(okc0);
    u64 bO = __ballot(okc1);
    bool al0 = (c0 < nctr) && (okc0 || (c0 * 16 + 15 > qr - 128));
    bool al1 = (c1 < nctr) && (okc1 || (c1 * 16 + 15 > qr - 128));
    float mv = fmaxf(al0 ? o0 : NEGINF, al1 ? o1 : NEGINF);
#pragma unroll
    for (int o = 1; o < 64; o <<= 1) mv = fmaxf(mv, __shfl_xor(mv, o));
    if (l == 0) {
      selEg[h * 2048 + qr] = bE;
      selOg[h * 2048 + qr] = bO;
      mxg[h * 2048 + qr] = mv;
    }
  }
}

// ---------------- P LDS swizzled index ----------------
__device__ __forceinline__ int pidx2(int r, int t) {
  return r * 32 + ((((t >> 3) ^ (r & 3)) << 3) | (t & 7));
}

// ======== K3: phase B ========
__global__ __launch_bounds__(256) void attnB(const unsigned short* __restrict__ Qh,
                                             const unsigned short* __restrict__ K2h,
                                             const unsigned short* __restrict__ V2,
                                             const u64* __restrict__ selEg,
                                             const u64* __restrict__ selOg,
                                             const float* __restrict__ mxg,
                                             unsigned short* __restrict__ AO) {
  __shared__ __align__(16) unsigned short Pls[4][512];
  __shared__ int clistS[4][128];

  const int qb = (int)gridDim.x - 1 - (int)blockIdx.x;
  const int kvh = blockIdx.y;
  const int q0 = qb * 16;
  const int nct = qb + 1;
  const int tid = threadIdx.x;
  const int w = tid >> 6, l = tid & 63;
  const int lr = l & 15, lg = l >> 4;
  const int h = kvh * 4 + w;

  bf16x8 qfh[4];
  {
    const unsigned short* qph = Qh + (long)(q0 + lr) * 4096 + h * 128 + lg * 8;
#pragma unroll
    for (int ks = 0; ks < 4; ++ks) qfh[ks] = *(const bf16x8*)(qph + ks * 32);
  }

  u64 myE = selEg[h * 2048 + q0 + lr];
  u64 myO = selOg[h * 2048 + q0 + lr];
  float mymx = mxg[h * 2048 + q0 + lr];

  u64 uE = myE, uO = myO;
#pragma unroll
  for (int o = 1; o < 16; o <<= 1) {
    uE |= __shfl_xor(uE, o);
    uO |= __shfl_xor(uO, o);
  }
  float mxj[4];
  u64 selE[4], selO[4];
#pragma unroll
  for (int j = 0; j < 4; ++j) {
    mxj[j] = __shfl(mymx, lg * 4 + j);
    selE[j] = __shfl(myE, lg * 4 + j);
    selO[j] = __shfl(myO, lg * 4 + j);
  }

  unsigned short* Pw = Pls[w];
  int* cl = clistS[w];

  const int c0 = 2 * l, c1 = 2 * l + 1;
  bool s0ok = (c0 < nct) && (((uE >> l) & 1ull) || (c0 >= qb - 7));
  bool s1ok = (c1 < nct) && (((uO >> l) & 1ull) || (c1 >= qb - 7));
  u64 bA = __ballot(s0ok);
  u64 bB = __ballot(s1ok);
  const int cntA = __popcll(bA);
  const int nsel = cntA + __popcll(bB);
  if (s0ok) cl[__popcll(bA & ((1ull << l) - 1ull))] = c0;
  if (s1ok) cl[cntA + __popcll(bB & ((1ull << l) - 1ull))] = c1;

  const unsigned short* kbh = K2h + (long)kvh * 128 * 2048;

  f32x4 pacc[8] = {};
  float psum[4] = {0.f, 0.f, 0.f, 0.f};
  const int np = (nsel + 1) >> 1;

  bf16x8 kA[4], kB[4];
  {
    const int cA0 = cl[0];
    const int cB0 = (1 < nsel) ? cl[1] : cA0;
    const unsigned short* pA = kbh + (long)cA0 * 2048 + l * 8;
    const unsigned short* pB = kbh + (long)cB0 * 2048 + l * 8;
#pragma unroll
    for (int ks = 0; ks < 4; ++ks) {
      kA[ks] = *(const bf16x8*)(pA + ks * 512);
      kB[ks] = *(const bf16x8*)(pB + ks * 512);
    }
  }

  for (int pi = 0; pi < np; ++pi) {
    const int cA = cl[2 * pi];
    const int iB = 2 * pi + 1;
    const int cB = (iB < nsel) ? cl[iB] : cA;

    const int csel = (lg < 2) ? cA : cB;
    const unsigned short* vp = V2 + (long)(kvh * 128 + csel) * 2048 + ((lg & 1) * 16 + lr) * 8;
    bf16x8 vf[8];
#pragma unroll
    for (int dblk = 0; dblk < 8; ++dblk) vf[dblk] = *(const bf16x8*)(vp + dblk * 256);

    bf16x8 nA[4], nB[4];
    {
      const int pin = (pi + 1 < np) ? pi + 1 : pi;
      const int cA1 = cl[2 * pin];
      const int iB1 = 2 * pin + 1;
      const int cB1 = (iB1 < nsel) ? cl[iB1] : cA1;
      const unsigned short* pA = kbh + (long)cA1 * 2048 + l * 8;
      const unsigned short* pB = kbh + (long)cB1 * 2048 + l * 8;
#pragma unroll
      for (int ks = 0; ks < 4; ++ks) {
        nA[ks] = *(const bf16x8*)(pA + ks * 512);
        nB[ks] = *(const bf16x8*)(pB + ks * 512);
      }
    }

#pragma unroll
    for (int half = 0; half < 2; ++half) {
      const int c = half ? cB : cA;
      const bool vslot = (2 * pi + half) < nsel;
      f32x4 acc = {};
#pragma unroll
      for (int ks = 0; ks < 4; ++ks) {
        bf16x8 kf = half ? kB[ks] : kA[ks];
        acc = __builtin_amdgcn_mfma_f32_16x16x32_bf16(qfh[ks], kf, acc, 0, 0, 0);
      }
#pragma unroll
      for (int j = 0; j < 4; ++j) {
        const int r = lg * 4 + j;
        const int qrr = q0 + r;
        const int tok = c * 16 + lr;
        u64 sm = (c & 1) ? selO[j] : selE[j];
        bool sel = (sm >> (c >> 1)) & 1ull;
        bool al = vslot && (tok <= qrr) && (sel || (tok > qrr - 128));
        float p = al ? __expf(acc[j] - mxj[j]) : 0.f;
        unsigned short pb = f2bf(p);
        psum[j] += bf2f(pb);
        Pw[pidx2(r, half * 16 + lr)] = pb;
      }
    }
    bf16x8 pa = *(const bf16x8*)&Pw[pidx2(lr, lg * 8)];
#pragma unroll
    for (int dblk = 0; dblk < 8; ++dblk)
      pacc[dblk] = __builtin_amdgcn_mfma_f32_16x16x32_bf16(pa, vf[dblk], pacc[dblk], 0, 0, 0);

#pragma unroll
    for (int ks = 0; ks < 4; ++ks) { kA[ks] = nA[ks]; kB[ks] = nB[ks]; }
  }

#pragma unroll
  for (int j = 0; j < 4; ++j) {
    float s = psum[j];
    s += __shfl_xor(s, 1); s += __shfl_xor(s, 2);
    s += __shfl_xor(s, 4); s += __shfl_xor(s, 8);
    const float rd = 1.0f / s;
    const int r = lg * 4 + j;
#pragma unroll
    for (int dblk = 0; dblk < 8; ++dblk)
      AO[(long)(q0 + r) * 4096 + h * 128 + dblk * 16 + lr] = f2bf(pacc[dblk][j] * rd);
  }
}

// ---------------- launch ----------------
extern "C" void kernel_launch(void* const* d_in, const int* in_sizes, int n_in,
                              void* d_out, int out_size, void* d_ws, size_t ws_size,
                              hipStream_t stream) {
  const float* hidden = (const float*)d_in[0];
  const float* wq = (const float*)d_in[1];
  const float* wk = (const float*)d_in[2];
  const float* wv = (const float*)d_in[3];
  const float* wo = (const float*)d_in[4];
  float* out = (float*)d_out;

  unsigned short* hb_hi = (unsigned short*)d_ws;          // [2048][4096]
  unsigned short* hb_lo = hb_hi + (size_t)2048 * 4096;
  unsigned short* wq_hi = hb_lo + (size_t)2048 * 4096;    // [4096][4096]
  unsigned short* wq_lo = wq_hi + (size_t)4096 * 4096;
  unsigned short* wk_hi = wq_lo + (size_t)4096 * 4096;    // [1024][4096]
  unsigned short* wk_lo = wk_hi + (size_t)1024 * 4096;
  unsigned short* wv_b  = wk_lo + (size_t)1024 * 4096;    // [1024][4096]
  unsigned short* wo_b  = wv_b  + (size_t)1024 * 4096;    // [4096][4096]
  unsigned short* Qhi = wo_b + (size_t)4096 * 4096;       // [2048][4096] bf16
  unsigned short* Qlo = Qhi + (size_t)2048 * 4096;
  unsigned short* K2h = Qlo + (size_t)2048 * 4096;        // frag-major
  unsigned short* K2l = K2h + (size_t)2048 * 1024;
  unsigned short* V2  = K2l + (size_t)2048 * 1024;        // frag-major
  unsigned short* AO = hb_hi;         // hidden splits dead after projections
  float* cmaxg = (float*)wq_hi;       // wq splits dead after projections
  u64* selEg = (u64*)wk_hi;           // wk splits dead after projections
  u64* selOg = selEg + 32 * 2048;
  float* mxg = (float*)(selOg + 32 * 2048);
  float* ctab = out;                  // staged in d_out; fully overwritten by o8ph
  float* stab = ctab + 2048 * 64;

  cvt_all<<<49152, 256, 0, stream>>>(hidden, wq, wk, wv, wo,
                                     hb_hi, hb_lo, wq_hi, wq_lo,
                                     wk_hi, wk_lo, wv_b, wo_b);
  rope_table<<<512, 256, 0, stream>>>(ctab, stab);

  qkv_gemm<<<256, 256, 0, stream>>>(hb_hi, hb_lo, wk_hi, wk_lo, wv_b,
                                    ctab, stab, K2h, K2l, V2);
  q8ph<<<256, 512, 0, stream>>>(hb_hi, hb_lo, wq_hi, wq_lo,
                                ctab, stab, Qhi, Qlo);

  cmax_gemm<<<dim3(16, 32), 256, 0, stream>>>(Qhi, Qlo, K2h, K2l, cmaxg);
  select_kernel<<<dim3(32, 32), 256, 0, stream>>>(cmaxg, selEg, selOg, mxg);
  attnB<<<dim3(128, 8), 256, 0, stream>>>(Qhi, K2h, V2, selEg, selOg, mxg, AO);

  o8ph<<<256, 512, 0, stream>>>(AO, wo_b, out);
}

// Round 16
// 672.970 us; speedup vs baseline: 1.0732x; 1.0003x over previous
//
#include <hip/hip_runtime.h>
#include <math.h>

typedef __attribute__((ext_vector_type(4))) float f32x4;
typedef __attribute__((ext_vector_type(8))) __bf16 bf16x8;
typedef __attribute__((ext_vector_type(4))) unsigned short us4;
typedef unsigned long long u64;

__device__ __forceinline__ unsigned short f2bf(float f) {
  unsigned int u = __float_as_uint(f);
  u += 0x7fffu + ((u >> 16) & 1u);            // RNE
  return (unsigned short)(u >> 16);
}
__device__ __forceinline__ float bf2f(unsigned short h) {
  return __uint_as_float(((unsigned int)h) << 16);
}

__device__ __forceinline__ void gload16(const void* g, void* l) {
  __builtin_amdgcn_global_load_lds(
      (__attribute__((address_space(1))) void*)g,
      (__attribute__((address_space(3))) void*)l, 16, 0, 0);
}

// ---------------- K2 fragment-major index: K element (s, kvh, d) ----------------
__device__ __forceinline__ long k2idx(int kvh, int s, int d) {
  int ct = s >> 4;
  int lane = (((d & 31) >> 3) << 4) | (s & 15);
  return ((long)(kvh * 128 + ct) * 4 + (d >> 5)) * 512 + lane * 8 + (d & 7);
}

// ---------------- fused fp32 -> bf16 conversions ----------------
__device__ __forceinline__ void split1(const float* __restrict__ in,
                                       unsigned short* __restrict__ hi,
                                       unsigned short* __restrict__ lo, int i) {
  float4 v = ((const float4*)in)[i];
  us4 h, l;
  float vv[4] = {v.x, v.y, v.z, v.w};
#pragma unroll
  for (int j = 0; j < 4; ++j) {
    unsigned short hh = f2bf(vv[j]);
    h[j] = hh;
    l[j] = f2bf(vv[j] - bf2f(hh));
  }
  ((us4*)hi)[i] = h;
  ((us4*)lo)[i] = l;
}
__device__ __forceinline__ void plain1(const float* __restrict__ in,
                                       unsigned short* __restrict__ out, int i) {
  float4 v = ((const float4*)in)[i];
  us4 o;
  o[0] = f2bf(v.x); o[1] = f2bf(v.y); o[2] = f2bf(v.z); o[3] = f2bf(v.w);
  ((us4*)out)[i] = o;
}

__global__ __launch_bounds__(256) void cvt_all(const float* __restrict__ hidden,
                                               const float* __restrict__ wq,
                                               const float* __restrict__ wk,
                                               const float* __restrict__ wv,
                                               const float* __restrict__ wo,
                                               unsigned short* __restrict__ hb_hi,
                                               unsigned short* __restrict__ hb_lo,
                                               unsigned short* __restrict__ wq_hi,
                                               unsigned short* __restrict__ wq_lo,
                                               unsigned short* __restrict__ wk_hi,
                                               unsigned short* __restrict__ wk_lo,
                                               unsigned short* __restrict__ wv_b,
                                               unsigned short* __restrict__ wo_b) {
  int i = blockIdx.x * 256 + threadIdx.x;
  if (i < 2097152)       split1(hidden, hb_hi, hb_lo, i);
  else if (i < 6291456)  split1(wq, wq_hi, wq_lo, i - 2097152);
  else if (i < 7340032)  split1(wk, wk_hi, wk_lo, i - 6291456);
  else if (i < 8388608)  plain1(wv, wv_b, i - 7340032);
  else if (i < 12582912) plain1(wo, wo_b, i - 8388608);
}

// ---------------- RoPE angle table (staged in d_out; overwritten by final GEMM) ----------------
__global__ __launch_bounds__(256) void rope_table(float* __restrict__ ctab,
                                                  float* __restrict__ stab) {
  int idx = blockIdx.x * 256 + threadIdx.x;   // 2048*64
  if (idx >= 2048 * 64) return;
  int s = idx >> 6, d = idx & 63;
  float inv = powf(10000.0f, -(float)d * (1.0f / 64.0f));
  float ang = (float)s * inv;
  ctab[idx] = cosf(ang);
  stab[idx] = sinf(ang);
}

// ======== Q-proj: 2-coarse-phase counted-vmcnt 3-term GEMM + rope epilogue (round-15) ========
__global__ __launch_bounds__(512, 2) void q8ph(const unsigned short* __restrict__ Ahg,
                                               const unsigned short* __restrict__ Alg,
                                               const unsigned short* __restrict__ wq_hi,
                                               const unsigned short* __restrict__ wq_lo,
                                               const float* __restrict__ ctab,
                                               const float* __restrict__ stab,
                                               unsigned short* __restrict__ Qh,
                                               unsigned short* __restrict__ Ql) {
  __shared__ __align__(16) unsigned short shb[73728];   // 144 KB
  const int bid = blockIdx.x;
  const int tid = threadIdx.x;
  const int w = tid >> 6, l = tid & 63;
  const int lr = l & 15, lg = l >> 4;
  const int wr = w >> 2, wc = w & 3;
  const int nt = 128;

  const int m_idx = (bid & 7) * 2 + ((bid >> 3) & 1);   // A-pair pinned per XCD
  const int n_idx = bid >> 4;
  const long m0 = (long)m_idx * 128;
  const long n0 = (long)n_idx * 256;

  const int arow = tid >> 2;
  const int kg = ((tid & 3) ^ ((tid >> 2) & 3) ^ ((tid >> 4) & 3)) & 3;
  const long aoff  = (m0 + arow) * 4096 + kg * 8;
  const long boff0 = (n0 + arow) * 4096 + kg * 8;
  const long boff1 = (n0 + 128 + arow) * 4096 + kg * 8;
  const int dstw = w * 512;

  const int xk = (lg ^ (lr & 3) ^ ((lr >> 2) & 3)) & 3;

#define QSTG_A(t, bs)                                                         \
  { gload16(Ahg + aoff + (long)(t) * 32, &shb[(bs) * 4096 + dstw]);           \
    gload16(Alg + aoff + (long)(t) * 32, &shb[12288 + (bs) * 4096 + dstw]); }
#define QSTG_BH(t, bs)                                                        \
  { gload16(wq_hi + boff0 + (long)(t) * 32, &shb[24576 + (bs) * 8192 + dstw]);\
    gload16(wq_hi + boff1 + (long)(t) * 32, &shb[24576 + (bs) * 8192 + 4096 + dstw]); }
#define QSTG_BL(t, bs)                                                        \
  { gload16(wq_lo + boff0 + (long)(t) * 32, &shb[49152 + (bs) * 8192 + dstw]);\
    gload16(wq_lo + boff1 + (long)(t) * 32, &shb[49152 + (bs) * 8192 + 4096 + dstw]); }

  f32x4 acc[4][4] = {};

  QSTG_A(0, 0); QSTG_BH(0, 0); QSTG_BL(0, 0);
  QSTG_A(1, 1); QSTG_BH(1, 1); QSTG_BL(1, 1);
  QSTG_A(2, 2); QSTG_BH(2, 2); QSTG_BL(2, 2);
  asm volatile("s_waitcnt vmcnt(12)" ::: "memory");
  __builtin_amdgcn_s_barrier();
  __builtin_amdgcn_sched_barrier(0);

#define PH_ENTER                                         \
  __builtin_amdgcn_sched_barrier(0);                     \
  __builtin_amdgcn_s_barrier();                          \
  asm volatile("s_waitcnt lgkmcnt(0)" ::: "memory");     \
  __builtin_amdgcn_sched_barrier(0);                     \
  __builtin_amdgcn_s_setprio(1);
#define PH_EXIT                                          \
  __builtin_amdgcn_s_setprio(0);                         \
  __builtin_amdgcn_sched_barrier(0);                     \
  __builtin_amdgcn_s_barrier();                          \
  __builtin_amdgcn_sched_barrier(0);
#define QPH_MFMA(p, bh, bl)                                                                    \
  _Pragma("unroll")                                                                            \
  for (int mi = 0; mi < 4; ++mi) {                                                             \
    acc[mi][p] = __builtin_amdgcn_mfma_f32_16x16x32_bf16(afh[mi], bh, acc[mi][p], 0, 0, 0);    \
    acc[mi][p] = __builtin_amdgcn_mfma_f32_16x16x32_bf16(afl[mi], bh, acc[mi][p], 0, 0, 0);    \
    acc[mi][p] = __builtin_amdgcn_mfma_f32_16x16x32_bf16(afh[mi], bl, acc[mi][p], 0, 0, 0);    \
  }
#define QPH_RDB(p, bh, bl)                                                          \
  { int rowb = wc * 64 + (p) * 16 + lr;                                             \
    bh = *(const bf16x8*)&shb[24576 + bs * 8192 + rowb * 32 + xk * 8];              \
    bl = *(const bf16x8*)&shb[49152 + bs * 8192 + rowb * 32 + xk * 8]; }

  for (int t = 0; t < nt; ++t) {
    const int bs = t % 3;
    const int bss = (t + 2) % 3;
    const bool st = (t + 2) < nt;
    bf16x8 afh[4], afl[4], bh0, bl0, bh1, bl1, bh2, bl2, bh3, bl3;
#pragma unroll
    for (int mi = 0; mi < 4; ++mi) {
      int rowa = wr * 64 + mi * 16 + lr;
      afh[mi] = *(const bf16x8*)&shb[bs * 4096 + rowa * 32 + xk * 8];
      afl[mi] = *(const bf16x8*)&shb[12288 + bs * 4096 + rowa * 32 + xk * 8];
    }
    QPH_RDB(0, bh0, bl0);
    QPH_RDB(1, bh1, bl1);
    if (st) { QSTG_A(t + 2, bss); QSTG_BH(t + 2, bss); }
    PH_ENTER;
    QPH_MFMA(0, bh0, bl0);
    QPH_MFMA(1, bh1, bl1);
    PH_EXIT;
    QPH_RDB(2, bh2, bl2);
    QPH_RDB(3, bh3, bl3);
    if (st) QSTG_BL(t + 2, bss);
    if (st) asm volatile("s_waitcnt vmcnt(6)" ::: "memory");
    else    asm volatile("s_waitcnt vmcnt(0)" ::: "memory");
    PH_ENTER;
    QPH_MFMA(2, bh2, bl2);
    QPH_MFMA(3, bh3, bl3);
    PH_EXIT;
  }
#undef QSTG_A
#undef QSTG_BH
#undef QSTG_BL
#undef QPH_MFMA
#undef QPH_RDB

  __syncthreads();
  float* Cls = (float*)shb;                              // 128x256 fp32 = 128 KB
#pragma unroll
  for (int mi = 0; mi < 4; ++mi)
#pragma unroll
    for (int ni = 0; ni < 4; ++ni)
#pragma unroll
      for (int j = 0; j < 4; ++j)
        Cls[(wr * 64 + mi * 16 + lg * 4 + j) * 256 + wc * 64 + ni * 16 + lr] = acc[mi][ni][j];
  __syncthreads();

  const int r0l = tid >> 3;
  const int d0 = (tid & 7) * 8;
#pragma unroll
  for (int h = 0; h < 2; ++h) {
    const int head = n_idx * 2 + h;
#pragma unroll
    for (int k = 0; k < 2; ++k) {
      const int r = r0l + 64 * k;
      const long s = m0 + r;
      float X1[8], X2[8], CC[8], SS[8];
      {
        f32x4 a = *(const f32x4*)&Cls[r * 256 + h * 128 + d0];
        f32x4 b = *(const f32x4*)&Cls[r * 256 + h * 128 + d0 + 4];
        f32x4 c = *(const f32x4*)&Cls[r * 256 + h * 128 + 64 + d0];
        f32x4 d = *(const f32x4*)&Cls[r * 256 + h * 128 + 64 + d0 + 4];
        f32x4 e = *(const f32x4*)&ctab[s * 64 + d0];
        f32x4 f = *(const f32x4*)&ctab[s * 64 + d0 + 4];
        f32x4 g = *(const f32x4*)&stab[s * 64 + d0];
        f32x4 hh = *(const f32x4*)&stab[s * 64 + d0 + 4];
#pragma unroll
        for (int j = 0; j < 4; ++j) {
          X1[j] = a[j]; X1[j + 4] = b[j];
          X2[j] = c[j]; X2[j + 4] = d[j];
          CC[j] = e[j]; CC[j + 4] = f[j];
          SS[j] = g[j]; SS[j + 4] = hh[j];
        }
      }
      us4 H1[2], L1[2], H2[2], L2[2];
#pragma unroll
      for (int j = 0; j < 8; ++j) {
        float y1 = (X1[j] * CC[j] - X2[j] * SS[j]) * 0.08838834764831845f;
        float y2 = (X2[j] * CC[j] + X1[j] * SS[j]) * 0.08838834764831845f;
        unsigned short h1 = f2bf(y1), h2 = f2bf(y2);
        H1[j >> 2][j & 3] = h1; L1[j >> 2][j & 3] = f2bf(y1 - bf2f(h1));
        H2[j >> 2][j & 3] = h2; L2[j >> 2][j & 3] = f2bf(y2 - bf2f(h2));
      }
      long row = s * 4096 + head * 128;
      *(us4*)&Qh[row + d0] = H1[0];      *(us4*)&Qh[row + d0 + 4] = H1[1];
      *(us4*)&Ql[row + d0] = L1[0];      *(us4*)&Ql[row + d0 + 4] = L1[1];
      *(us4*)&Qh[row + 64 + d0] = H2[0]; *(us4*)&Qh[row + 64 + d0 + 4] = H2[1];
      *(us4*)&Ql[row + 64 + d0] = L2[0]; *(us4*)&Ql[row + 64 + d0 + 4] = L2[1];
    }
  }
}

// ======== K/V-proj: 512-thr coarse-phase counted-vmcnt (q8ph skeleton, 96 KB, 2 waves/SIMD) ========
// bid [0,128): K 128x128 3-term + rope epilogue -> K2 frag-major.
// bid [128,256): V 128x128 1-term -> V2 frag-major.
// Per-element accumulation order identical to prior rounds (kt asc; hh,lh,hl).
__global__ __launch_bounds__(512, 2) void kv8ph(const unsigned short* __restrict__ Ahg,
                                                const unsigned short* __restrict__ Alg,
                                                const unsigned short* __restrict__ wk_hi,
                                                const unsigned short* __restrict__ wk_lo,
                                                const unsigned short* __restrict__ wv_b,
                                                const float* __restrict__ ctab,
                                                const float* __restrict__ stab,
                                                unsigned short* __restrict__ K2h,
                                                unsigned short* __restrict__ K2l,
                                                unsigned short* __restrict__ V2) {
  __shared__ __align__(16) unsigned short shb[49152];   // 96 KB
  const int bid = blockIdx.x;
  const int tid = threadIdx.x;
  const int w = tid >> 6, l = tid & 63;
  const int lr = l & 15, lg = l >> 4;
  const int wr = w >> 2, wc = w & 3;
  const int nt = 128;

  const int bb = (bid < 128) ? bid : (bid - 128);
  const int m_idx = (bb & 7) * 2 + ((bb >> 3) & 1);     // A-pair pinned per XCD
  const int n_idx = bb >> 4;                            // 0..7
  const long m0 = (long)m_idx * 128;
  const long n0 = (long)n_idx * 128;

  const int arow = tid >> 2;
  const int kg = ((tid & 3) ^ ((tid >> 2) & 3) ^ ((tid >> 4) & 3)) & 3;
  const long aoff = (m0 + arow) * 4096 + kg * 8;
  const long boff = (n0 + arow) * 4096 + kg * 8;
  const int dstw = w * 512;

  const int xk = (lg ^ (lr & 3) ^ ((lr >> 2) & 3)) & 3;

  if (bid < 128) {
    // ---------------- K-proj: 3-term, 2 coarse phases, vmcnt(4) steady ----------------
    // LDS: Ah@bs*4096, Al@12288+bs*4096, Bh@24576+bs*4096, Bl@36864+bs*4096
#define KSTG_A(t, bs)                                                          \
  { gload16(Ahg + aoff + (long)(t) * 32, &shb[(bs) * 4096 + dstw]);            \
    gload16(Alg + aoff + (long)(t) * 32, &shb[12288 + (bs) * 4096 + dstw]); }
#define KSTG_B(t, bs)                                                          \
  { gload16(wk_hi + boff + (long)(t) * 32, &shb[24576 + (bs) * 4096 + dstw]);  \
    gload16(wk_lo + boff + (long)(t) * 32, &shb[36864 + (bs) * 4096 + dstw]); }
#define KPH_MFMA(p, bh, bl)                                                                    \
  _Pragma("unroll")                                                                            \
  for (int mi = 0; mi < 4; ++mi) {                                                             \
    acc[mi][p] = __builtin_amdgcn_mfma_f32_16x16x32_bf16(afh[mi], bh, acc[mi][p], 0, 0, 0);    \
    acc[mi][p] = __builtin_amdgcn_mfma_f32_16x16x32_bf16(afl[mi], bh, acc[mi][p], 0, 0, 0);    \
    acc[mi][p] = __builtin_amdgcn_mfma_f32_16x16x32_bf16(afh[mi], bl, acc[mi][p], 0, 0, 0);    \
  }

    f32x4 acc[4][2] = {};

    KSTG_A(0, 0); KSTG_B(0, 0);
    KSTG_A(1, 1); KSTG_B(1, 1);
    KSTG_A(2, 2); KSTG_B(2, 2);
    asm volatile("s_waitcnt vmcnt(8)" ::: "memory");     // tile 0 ready
    __builtin_amdgcn_s_barrier();
    __builtin_amdgcn_sched_barrier(0);

    for (int t = 0; t < nt; ++t) {
      const int bs = t % 3;
      const int bss = (t + 2) % 3;
      const bool st = (t + 2) < nt;
      bf16x8 afh[4], afl[4], bh0, bl0, bh1, bl1;
#pragma unroll
      for (int mi = 0; mi < 4; ++mi) {
        int rowa = wr * 64 + mi * 16 + lr;
        afh[mi] = *(const bf16x8*)&shb[bs * 4096 + rowa * 32 + xk * 8];
        afl[mi] = *(const bf16x8*)&shb[12288 + bs * 4096 + rowa * 32 + xk * 8];
      }
      {
        int rowb = wc * 32 + lr;
        bh0 = *(const bf16x8*)&shb[24576 + bs * 4096 + rowb * 32 + xk * 8];
        bl0 = *(const bf16x8*)&shb[36864 + bs * 4096 + rowb * 32 + xk * 8];
      }
      if (st) KSTG_A(t + 2, bss);
      PH_ENTER;
      KPH_MFMA(0, bh0, bl0);
      PH_EXIT;
      {
        int rowb = wc * 32 + 16 + lr;
        bh1 = *(const bf16x8*)&shb[24576 + bs * 4096 + rowb * 32 + xk * 8];
        bl1 = *(const bf16x8*)&shb[36864 + bs * 4096 + rowb * 32 + xk * 8];
      }
      if (st) KSTG_B(t + 2, bss);
      if (st) asm volatile("s_waitcnt vmcnt(4)" ::: "memory");
      else    asm volatile("s_waitcnt vmcnt(0)" ::: "memory");
      PH_ENTER;
      KPH_MFMA(1, bh1, bl1);
      PH_EXIT;
    }
#undef KSTG_A
#undef KSTG_B
#undef KPH_MFMA

    // ---- epilogue: C (128x128 fp32) -> LDS, rope (scale 1) -> K2 frag-major ----
    __syncthreads();
    float* Cls = (float*)shb;                            // 64 KB
#pragma unroll
    for (int mi = 0; mi < 4; ++mi)
#pragma unroll
      for (int ni = 0; ni < 2; ++ni)
#pragma unroll
        for (int j = 0; j < 4; ++j)
          Cls[(wr * 64 + mi * 16 + lg * 4 + j) * 128 + wc * 32 + ni * 16 + lr] = acc[mi][ni][j];
    __syncthreads();

    const int kvh = (int)(n0 >> 7);
    const int r0l = tid >> 3;                            // 0..63
    const int d0 = (tid & 7) * 8;
#pragma unroll
    for (int k = 0; k < 2; ++k) {
      const int r = r0l + 64 * k;
      const long s = m0 + r;
      float X1[8], X2[8], CC[8], SS[8];
      {
        f32x4 a = *(const f32x4*)&Cls[r * 128 + d0];
        f32x4 b = *(const f32x4*)&Cls[r * 128 + d0 + 4];
        f32x4 c = *(const f32x4*)&Cls[r * 128 + 64 + d0];
        f32x4 d = *(const f32x4*)&Cls[r * 128 + 64 + d0 + 4];
        f32x4 e = *(const f32x4*)&ctab[s * 64 + d0];
        f32x4 f = *(const f32x4*)&ctab[s * 64 + d0 + 4];
        f32x4 g = *(const f32x4*)&stab[s * 64 + d0];
        f32x4 h = *(const f32x4*)&stab[s * 64 + d0 + 4];
#pragma unroll
        for (int j = 0; j < 4; ++j) {
          X1[j] = a[j]; X1[j + 4] = b[j];
          X2[j] = c[j]; X2[j + 4] = d[j];
          CC[j] = e[j]; CC[j + 4] = f[j];
          SS[j] = g[j]; SS[j + 4] = h[j];
        }
      }
      us4 H1[2], L1[2], H2[2], L2[2];
#pragma unroll
      for (int j = 0; j < 8; ++j) {
        float y1 = X1[j] * CC[j] - X2[j] * SS[j];
        float y2 = X2[j] * CC[j] + X1[j] * SS[j];
        unsigned short h1 = f2bf(y1), h2 = f2bf(y2);
        H1[j >> 2][j & 3] = h1; L1[j >> 2][j & 3] = f2bf(y1 - bf2f(h1));
        H2[j >> 2][j & 3] = h2; L2[j >> 2][j & 3] = f2bf(y2 - bf2f(h2));
      }
      long i1 = k2idx(kvh, (int)s, d0);
      long i2 = k2idx(kvh, (int)s, d0 + 64);
      *(us4*)&K2h[i1] = H1[0]; *(us4*)&K2h[i1 + 4] = H1[1];
      *(us4*)&K2l[i1] = L1[0]; *(us4*)&K2l[i1 + 4] = L1[1];
      *(us4*)&K2h[i2] = H2[0]; *(us4*)&K2h[i2 + 4] = H2[1];
      *(us4*)&K2l[i2] = L2[0]; *(us4*)&K2l[i2 + 4] = L2[1];
    }
    return;
  }

  // ---------------- V-proj: 1-term, single phase/tile, vmcnt(2) steady ----------------
  // LDS: A@bs*4096, B@12288+bs*4096
  {
#define VSTG(t, bs)                                                            \
  { gload16(Ahg + aoff + (long)(t) * 32, &shb[(bs) * 4096 + dstw]);            \
    gload16(wv_b + boff + (long)(t) * 32, &shb[12288 + (bs) * 4096 + dstw]); }

    f32x4 acc[4][2] = {};

    VSTG(0, 0);
    VSTG(1, 1);
    VSTG(2, 2);
    asm volatile("s_waitcnt vmcnt(4)" ::: "memory");
    __builtin_amdgcn_s_barrier();
    __builtin_amdgcn_sched_barrier(0);

    for (int t = 0; t < nt; ++t) {
      const int bs = t % 3;
      const int bss = (t + 2) % 3;
      const bool st = (t + 2) < nt;
      bf16x8 af[4], bf0, bf1;
#pragma unroll
      for (int mi = 0; mi < 4; ++mi) {
        int rowa = wr * 64 + mi * 16 + lr;
        af[mi] = *(const bf16x8*)&shb[bs * 4096 + rowa * 32 + xk * 8];
      }
      {
        int rb0 = wc * 32 + lr;
        int rb1 = wc * 32 + 16 + lr;
        bf0 = *(const bf16x8*)&shb[12288 + bs * 4096 + rb0 * 32 + xk * 8];
        bf1 = *(const bf16x8*)&shb[12288 + bs * 4096 + rb1 * 32 + xk * 8];
      }
      if (st) VSTG(t + 2, bss);
      if (st) asm volatile("s_waitcnt vmcnt(2)" ::: "memory");
      else    asm volatile("s_waitcnt vmcnt(0)" ::: "memory");
      PH_ENTER;
#pragma unroll
      for (int mi = 0; mi < 4; ++mi) {
        acc[mi][0] = __builtin_amdgcn_mfma_f32_16x16x32_bf16(af[mi], bf0, acc[mi][0], 0, 0, 0);
        acc[mi][1] = __builtin_amdgcn_mfma_f32_16x16x32_bf16(af[mi], bf1, acc[mi][1], 0, 0, 0);
      }
      PH_EXIT;
    }
#undef VSTG

#pragma unroll
    for (int mi = 0; mi < 4; ++mi)
#pragma unroll
      for (int ni = 0; ni < 2; ++ni)
#pragma unroll
        for (int j = 0; j < 4; ++j) {
          long r = m0 + wr * 64 + mi * 16 + lg * 4 + j;
          long cc = n0 + wc * 32 + ni * 16 + lr;
          int kvh = (int)(cc >> 7), d = (int)(cc & 127);
          int c = (int)(r >> 4), t2 = (int)(r & 15);
          long idx = ((long)(kvh * 128 + c) * 8 + (d >> 4)) * 256 + ((t2 >> 3) * 16 + (d & 15)) * 8 + (t2 & 7);
          V2[idx] = f2bf(acc[mi][ni][j]);
        }
  }
}

// ======== O-proj: 8-phase counted-vmcnt 1-term GEMM (round-14, unchanged) ========
__global__ __launch_bounds__(512, 2) void o8ph(const unsigned short* __restrict__ A,
                                               const unsigned short* __restrict__ B,
                                               float* __restrict__ C) {
  __shared__ __align__(16) unsigned short shb[36864];   // 72 KB
  const int bid = blockIdx.x;
  const int tid = threadIdx.x;
  const int w = tid >> 6, l = tid & 63;
  const int lr = l & 15, lg = l >> 4;
  const int wr = w >> 2, wc = w & 3;
  const int nt = 128;

  const int m_idx = (bid & 7) * 2 + ((bid >> 3) & 1);
  const int n_idx = bid >> 4;
  const long m0 = (long)m_idx * 128;
  const long n0 = (long)n_idx * 256;

  const int arow = tid >> 2;
  const int kg = ((tid & 3) ^ ((tid >> 2) & 3) ^ ((tid >> 4) & 3)) & 3;
  const long aoff  = (m0 + arow) * 4096 + kg * 8;
  const long boff0 = (n0 + arow) * 4096 + kg * 8;
  const long boff1 = (n0 + 128 + arow) * 4096 + kg * 8;
  const int dstw = w * 512;

  const int xk = (lg ^ (lr & 3) ^ ((lr >> 2) & 3)) & 3;

#define OSTG_A(t, bs)                                                        \
  gload16(A + aoff + (long)(t) * 32, &shb[(bs) * 4096 + dstw]);
#define OSTG_B0(t, bs)                                                       \
  gload16(B + boff0 + (long)(t) * 32, &shb[12288 + (bs) * 8192 + dstw]);
#define OSTG_B1(t, bs)                                                       \
  gload16(B + boff1 + (long)(t) * 32, &shb[12288 + (bs) * 8192 + 4096 + dstw]);

  f32x4 acc[4][4] = {};

  OSTG_A(0, 0); OSTG_B0(0, 0); OSTG_B1(0, 0);
  OSTG_A(1, 1); OSTG_B0(1, 1); OSTG_B1(1, 1);
  OSTG_A(2, 2); OSTG_B0(2, 2); OSTG_B1(2, 2);
  asm volatile("s_waitcnt vmcnt(6)" ::: "memory");
  __builtin_amdgcn_s_barrier();
  __builtin_amdgcn_sched_barrier(0);

#define OPH_RDB(p, dst)                                                             \
  { int rowb = wc * 64 + (p) * 16 + lr;                                             \
    dst = *(const bf16x8*)&shb[12288 + bs * 8192 + (rowb & 127) * 32 +              \
                               ((rowb >> 7) & 1) * 4096 + xk * 8]; }

  for (int t = 0; t < nt; ++t) {
    const int bs = t % 3;
    const int bss = (t + 2) % 3;
    const bool st = (t + 2) < nt;
    bf16x8 af[4], bf0, bf1, bf2, bf3;
#pragma unroll
    for (int mi = 0; mi < 4; ++mi) {
      int rowa = wr * 64 + mi * 16 + lr;
      af[mi] = *(const bf16x8*)&shb[bs * 4096 + rowa * 32 + xk * 8];
    }
    OPH_RDB(0, bf0);
    OPH_RDB(1, bf1);
    if (st) { OSTG_A(t + 2, bss); OSTG_B0(t + 2, bss); }
    PH_ENTER;
#pragma unroll
    for (int mi = 0; mi < 4; ++mi) {
      acc[mi][0] = __builtin_amdgcn_mfma_f32_16x16x32_bf16(af[mi], bf0, acc[mi][0], 0, 0, 0);
      acc[mi][1] = __builtin_amdgcn_mfma_f32_16x16x32_bf16(af[mi], bf1, acc[mi][1], 0, 0, 0);
    }
    PH_EXIT;
    OPH_RDB(2, bf2);
    OPH_RDB(3, bf3);
    if (st) OSTG_B1(t + 2, bss);
    if (st) asm volatile("s_waitcnt vmcnt(3)" ::: "memory");
    else    asm volatile("s_waitcnt vmcnt(0)" ::: "memory");
    PH_ENTER;
#pragma unroll
    for (int mi = 0; mi < 4; ++mi) {
      acc[mi][2] = __builtin_amdgcn_mfma_f32_16x16x32_bf16(af[mi], bf2, acc[mi][2], 0, 0, 0);
      acc[mi][3] = __builtin_amdgcn_mfma_f32_16x16x32_bf16(af[mi], bf3, acc[mi][3], 0, 0, 0);
    }
    PH_EXIT;
  }
#undef OSTG_A
#undef OSTG_B0
#undef OSTG_B1
#undef OPH_RDB

#pragma unroll
  for (int mi = 0; mi < 4; ++mi)
#pragma unroll
    for (int ni = 0; ni < 4; ++ni)
#pragma unroll
      for (int j = 0; j < 4; ++j) {
        long r = m0 + wr * 64 + mi * 16 + lg * 4 + j;
        long cc = n0 + wc * 64 + ni * 16 + lr;
        C[r * 4096 + cc] = acc[mi][ni][j];
      }
}

// ======== K1: cmax GEMM, 4-deep counted-vmcnt pipeline (unchanged). ========
__global__ __launch_bounds__(256, 2) void cmax_gemm(const unsigned short* __restrict__ Qh,
                                                    const unsigned short* __restrict__ Ql,
                                                    const unsigned short* __restrict__ K2h,
                                                    const unsigned short* __restrict__ K2l,
                                                    float* __restrict__ cmaxg) {
  __shared__ __align__(16) unsigned short Ksh[4][4096];
  __shared__ __align__(16) unsigned short Ksl[4][4096];
  const int qp = 15 - (int)blockIdx.x;
  const int h = blockIdx.y;
  const int kvh = h >> 2;
  const int q0 = qp * 128;
  const int tid = threadIdx.x;
  const int w = tid >> 6, l = tid & 63;
  const int lr = l & 15, lg = l >> 4;
  const int npan = 4 * (qp + 1);
  const float NEGINF = -__builtin_inff();

  bf16x8 qfh[2][4], qfl[2][4];
#pragma unroll
  for (int rg = 0; rg < 2; ++rg) {
    const unsigned short* qph = Qh + (long)(q0 + w * 32 + rg * 16 + lr) * 4096 + h * 128 + lg * 8;
    const unsigned short* qpl = Ql + (long)(q0 + w * 32 + rg * 16 + lr) * 4096 + h * 128 + lg * 8;
#pragma unroll
    for (int ks = 0; ks < 4; ++ks) {
      qfh[rg][ks] = *(const bf16x8*)(qph + ks * 32);
      qfl[rg][ks] = *(const bf16x8*)(qpl + ks * 32);
    }
  }

  const unsigned short* kbh = K2h + (long)kvh * 128 * 2048;
  const unsigned short* kbl = K2l + (long)kvh * 128 * 2048;

#define STAGE(kp, b)                                                       \
  {                                                                        \
    long off = (long)(kp) * 4096;                                          \
    _Pragma("unroll")                                                      \
    for (int i = 0; i < 2; ++i) {                                          \
      int cu = w * 128 + i * 64;                                           \
      gload16(kbh + off + (cu + l) * 8, &Ksh[b][cu * 8]);                  \
      gload16(kbl + off + (cu + l) * 8, &Ksl[b][cu * 8]);                  \
    }                                                                      \
  }

  STAGE(0, 0);
  if (1 < npan) STAGE(1, 1);
  if (2 < npan) STAGE(2, 2);

  for (int kp = 0; kp < npan; ++kp) {
    {
      int ahead = npan - 1 - kp; if (ahead > 2) ahead = 2;
      int st = kp; if (st > 3) st = 3;
      int tgt = 4 * ahead + 4 * st;
      if (tgt >= 20)      asm volatile("s_waitcnt vmcnt(20)" ::: "memory");
      else if (tgt >= 16) asm volatile("s_waitcnt vmcnt(16)" ::: "memory");
      else if (tgt >= 12) asm volatile("s_waitcnt vmcnt(12)" ::: "memory");
      else if (tgt >= 8)  asm volatile("s_waitcnt vmcnt(8)" ::: "memory");
      else                asm volatile("s_waitcnt vmcnt(0)" ::: "memory");
    }
    __builtin_amdgcn_s_barrier();
    __builtin_amdgcn_sched_barrier(0);
    if (kp + 3 < npan) STAGE(kp + 3, (kp + 3) & 3);
    const int b = kp & 3;
#pragma unroll
    for (int c2 = 0; c2 < 2; ++c2) {
      const int ct = kp * 2 + c2;
      bf16x8 kh[4], kl2[4];
#pragma unroll
      for (int ks = 0; ks < 4; ++ks) {
        kh[ks]  = *(const bf16x8*)&Ksh[b][(c2 * 4 + ks) * 512 + l * 8];
        kl2[ks] = *(const bf16x8*)&Ksl[b][(c2 * 4 + ks) * 512 + l * 8];
      }
#pragma unroll
      for (int rg = 0; rg < 2; ++rg) {
        f32x4 acc = {};
#pragma unroll
        for (int ks = 0; ks < 4; ++ks) {
          acc = __builtin_amdgcn_mfma_f32_16x16x32_bf16(kh[ks], qfh[rg][ks], acc, 0, 0, 0);
          acc = __builtin_amdgcn_mfma_f32_16x16x32_bf16(kh[ks], qfl[rg][ks], acc, 0, 0, 0);
          acc = __builtin_amdgcn_mfma_f32_16x16x32_bf16(kl2[ks], qfh[rg][ks], acc, 0, 0, 0);
        }
        const int rbase = q0 + w * 32 + rg * 16;
        float m;
        if (ct * 16 + 15 <= rbase) {
          m = fmaxf(fmaxf(acc[0], acc[1]), fmaxf(acc[2], acc[3]));
        } else {
          m = NEGINF;
#pragma unroll
          for (int j = 0; j < 4; ++j) {
            int tok = ct * 16 + lg * 4 + j;
            if (tok <= rbase + lr) m = fmaxf(m, acc[j]);
          }
        }
        m = fmaxf(m, __shfl_xor(m, 16));
        m = fmaxf(m, __shfl_xor(m, 32));
        if (l < 16) cmaxg[(long)(h * 128 + ct) * 2048 + rbase + l] = m;
      }
    }
  }
#undef STAGE
}

// ======== K2: per-row top-8 selection (unchanged). ========
__global__ __launch_bounds__(256) void select_kernel(const float* __restrict__ cmaxg,
                                                     u64* __restrict__ selEg,
                                                     u64* __restrict__ selOg,
                                                     float* __restrict__ mxg) {
  __shared__ float Lc[128 * 65];
  const int r0 = (int)blockIdx.x * 64;
  const int h = blockIdx.y;
  const int tid = threadIdx.x;
  const int w = tid >> 6, l = tid & 63;
  const float NEGINF = -__builtin_inff();

  for (int i = tid; i < 128 * 16; i += 256) {
    int ct = i >> 4, rq = (i & 15) * 4;
    float4 v = *(const float4*)&cmaxg[(long)(h * 128 + ct) * 2048 + r0 + rq];
    Lc[ct * 65 + rq]     = v.x;
    Lc[ct * 65 + rq + 1] = v.y;
    Lc[ct * 65 + rq + 2] = v.z;
    Lc[ct * 65 + rq + 3] = v.w;
  }
  __syncthreads();

  const int c0 = 2 * l, c1 = 2 * l + 1;
#pragma unroll 1
  for (int rs = 0; rs < 16; ++rs) {
    const int rloc = w * 16 + rs;
    const int qr = r0 + rloc;
    const int nctr = (qr >> 4) + 1;
    float v0 = (c0 < nctr) ? Lc[c0 * 65 + rloc] : NEGINF;
    float v1 = (c1 < nctr) ? Lc[c1 * 65 + rloc] : NEGINF;
    const float o0 = v0, o1 = v1;
    float T = NEGINF;
    for (int it = 0; it < 8; ++it) {
      float m = fmaxf(v0, v1);
#pragma unroll
      for (int o = 1; o < 64; o <<= 1) m = fmaxf(m, __shfl_xor(m, o));
      u64 bal = __ballot((v0 == m) || (v1 == m));
      int first = __ffsll(bal) - 1;
      if (l == first) { if (v0 == m) v0 = NEGINF; else v1 = NEGINF; }
      T = m;
    }
    bool okc0 = (c0 < nctr) && ((c0 < 8) || (o0 >= T));
    bool okc1 = (c1 < nctr) && ((c1 < 8) || (o1 >= T));
    u64 bE = __ballot(okc0);
    u64 bO = __ballot(okc1);
    bool al0 = (c0 < nctr) && (okc0 || (c0 * 16 + 15 > qr - 128));
    bool al1 = (c1 < nctr) && (okc1 || (c1 * 16 + 15 > qr - 128));
    float mv = fmaxf(al0 ? o0 : NEGINF, al1 ? o1 : NEGINF);
#pragma unroll
    for (int o = 1; o < 64; o <<= 1) mv = fmaxf(mv, __shfl_xor(mv, o));
    if (l == 0) {
      selEg[h * 2048 + qr] = bE;
      selOg[h * 2048 + qr] = bO;
      mxg[h * 2048 + qr] = mv;
    }
  }
}

// ---------------- P LDS swizzled index ----------------
__device__ __forceinline__ int pidx2(int r, int t) {
  return r * 32 + ((((t >> 3) ^ (r & 3)) << 3) | (t & 7));
}

// ======== K3: phase B (unchanged) ========
__global__ __launch_bounds__(256) void attnB(const unsigned short* __restrict__ Qh,
                                             const unsigned short* __restrict__ K2h,
                                             const unsigned short* __restrict__ V2,
                                             const u64* __restrict__ selEg,
                                             const u64* __restrict__ selOg,
                                             const float* __restrict__ mxg,
                                             unsigned short* __restrict__ AO) {
  __shared__ __align__(16) unsigned short Pls[4][512];
  __shared__ int clistS[4][128];

  const int qb = (int)gridDim.x - 1 - (int)blockIdx.x;
  const int kvh = blockIdx.y;
  const int q0 = qb * 16;
  const int nct = qb + 1;
  const int tid = threadIdx.x;
  const int w = tid >> 6, l = tid & 63;
  const int lr = l & 15, lg = l >> 4;
  const int h = kvh * 4 + w;

  bf16x8 qfh[4];
  {
    const unsigned short* qph = Qh + (long)(q0 + lr) * 4096 + h * 128 + lg * 8;
#pragma unroll
    for (int ks = 0; ks < 4; ++ks) qfh[ks] = *(const bf16x8*)(qph + ks * 32);
  }

  u64 myE = selEg[h * 2048 + q0 + lr];
  u64 myO = selOg[h * 2048 + q0 + lr];
  float mymx = mxg[h * 2048 + q0 + lr];

  u64 uE = myE, uO = myO;
#pragma unroll
  for (int o = 1; o < 16; o <<= 1) {
    uE |= __shfl_xor(uE, o);
    uO |= __shfl_xor(uO, o);
  }
  float mxj[4];
  u64 selE[4], selO[4];
#pragma unroll
  for (int j = 0; j < 4; ++j) {
    mxj[j] = __shfl(mymx, lg * 4 + j);
    selE[j] = __shfl(myE, lg * 4 + j);
    selO[j] = __shfl(myO, lg * 4 + j);
  }

  unsigned short* Pw = Pls[w];
  int* cl = clistS[w];

  const int c0 = 2 * l, c1 = 2 * l + 1;
  bool s0ok = (c0 < nct) && (((uE >> l) & 1ull) || (c0 >= qb - 7));
  bool s1ok = (c1 < nct) && (((uO >> l) & 1ull) || (c1 >= qb - 7));
  u64 bA = __ballot(s0ok);
  u64 bB = __ballot(s1ok);
  const int cntA = __popcll(bA);
  const int nsel = cntA + __popcll(bB);
  if (s0ok) cl[__popcll(bA & ((1ull << l) - 1ull))] = c0;
  if (s1ok) cl[cntA + __popcll(bB & ((1ull << l) - 1ull))] = c1;

  const unsigned short* kbh = K2h + (long)kvh * 128 * 2048;

  f32x4 pacc[8] = {};
  float psum[4] = {0.f, 0.f, 0.f, 0.f};
  const int np = (nsel + 1) >> 1;

  bf16x8 kA[4], kB[4];
  {
    const int cA0 = cl[0];
    const int cB0 = (1 < nsel) ? cl[1] : cA0;
    const unsigned short* pA = kbh + (long)cA0 * 2048 + l * 8;
    const unsigned short* pB = kbh + (long)cB0 * 2048 + l * 8;
#pragma unroll
    for (int ks = 0; ks < 4; ++ks) {
      kA[ks] = *(const bf16x8*)(pA + ks * 512);
      kB[ks] = *(const bf16x8*)(pB + ks * 512);
    }
  }

  for (int pi = 0; pi < np; ++pi) {
    const int cA = cl[2 * pi];
    const int iB = 2 * pi + 1;
    const int cB = (iB < nsel) ? cl[iB] : cA;

    const int csel = (lg < 2) ? cA : cB;
    const unsigned short* vp = V2 + (long)(kvh * 128 + csel) * 2048 + ((lg & 1) * 16 + lr) * 8;
    bf16x8 vf[8];
#pragma unroll
    for (int dblk = 0; dblk < 8; ++dblk) vf[dblk] = *(const bf16x8*)(vp + dblk * 256);

    bf16x8 nA[4], nB[4];
    {
      const int pin = (pi + 1 < np) ? pi + 1 : pi;
      const int cA1 = cl[2 * pin];
      const int iB1 = 2 * pin + 1;
      const int cB1 = (iB1 < nsel) ? cl[iB1] : cA1;
      const unsigned short* pA = kbh + (long)cA1 * 2048 + l * 8;
      const unsigned short* pB = kbh + (long)cB1 * 2048 + l * 8;
#pragma unroll
      for (int ks = 0; ks < 4; ++ks) {
        nA[ks] = *(const bf16x8*)(pA + ks * 512);
        nB[ks] = *(const bf16x8*)(pB + ks * 512);
      }
    }

#pragma unroll
    for (int half = 0; half < 2; ++half) {
      const int c = half ? cB : cA;
      const bool vslot = (2 * pi + half) < nsel;
      f32x4 acc = {};
#pragma unroll
      for (int ks = 0; ks < 4; ++ks) {
        bf16x8 kf = half ? kB[ks] : kA[ks];
        acc = __builtin_amdgcn_mfma_f32_16x16x32_bf16(qfh[ks], kf, acc, 0, 0, 0);
      }
#pragma unroll
      for (int j = 0; j < 4; ++j) {
        const int r = lg * 4 + j;
        const int qrr = q0 + r;
        const int tok = c * 16 + lr;
        u64 sm = (c & 1) ? selO[j] : selE[j];
        bool sel = (sm >> (c >> 1)) & 1ull;
        bool al = vslot && (tok <= qrr) && (sel || (tok > qrr - 128));
        float p = al ? __expf(acc[j] - mxj[j]) : 0.f;
        unsigned short pb = f2bf(p);
        psum[j] += bf2f(pb);
        Pw[pidx2(r, half * 16 + lr)] = pb;
      }
    }
    bf16x8 pa = *(const bf16x8*)&Pw[pidx2(lr, lg * 8)];
#pragma unroll
    for (int dblk = 0; dblk < 8; ++dblk)
      pacc[dblk] = __builtin_amdgcn_mfma_f32_16x16x32_bf16(pa, vf[dblk], pacc[dblk], 0, 0, 0);

#pragma unroll
    for (int ks = 0; ks < 4; ++ks) { kA[ks] = nA[ks]; kB[ks] = nB[ks]; }
  }

#pragma unroll
  for (int j = 0; j < 4; ++j) {
    float s = psum[j];
    s += __shfl_xor(s, 1); s += __shfl_xor(s, 2);
    s += __shfl_xor(s, 4); s += __shfl_xor(s, 8);
    const float rd = 1.0f / s;
    const int r = lg * 4 + j;
#pragma unroll
    for (int dblk = 0; dblk < 8; ++dblk)
      AO[(long)(q0 + r) * 4096 + h * 128 + dblk * 16 + lr] = f2bf(pacc[dblk][j] * rd);
  }
}

// ---------------- launch ----------------
extern "C" void kernel_launch(void* const* d_in, const int* in_sizes, int n_in,
                              void* d_out, int out_size, void* d_ws, size_t ws_size,
                              hipStream_t stream) {
  const float* hidden = (const float*)d_in[0];
  const float* wq = (const float*)d_in[1];
  const float* wk = (const float*)d_in[2];
  const float* wv = (const float*)d_in[3];
  const float* wo = (const float*)d_in[4];
  float* out = (float*)d_out;

  unsigned short* hb_hi = (unsigned short*)d_ws;          // [2048][4096]
  unsigned short* hb_lo = hb_hi + (size_t)2048 * 4096;
  unsigned short* wq_hi = hb_lo + (size_t)2048 * 4096;    // [4096][4096]
  unsigned short* wq_lo = wq_hi + (size_t)4096 * 4096;
  unsigned short* wk_hi = wq_lo + (size_t)4096 * 4096;    // [1024][4096]
  unsigned short* wk_lo = wk_hi + (size_t)1024 * 4096;
  unsigned short* wv_b  = wk_lo + (size_t)1024 * 4096;    // [1024][4096]
  unsigned short* wo_b  = wv_b  + (size_t)1024 * 4096;    // [4096][4096]
  unsigned short* Qhi = wo_b + (size_t)4096 * 4096;       // [2048][4096] bf16
  unsigned short* Qlo = Qhi + (size_t)2048 * 4096;
  unsigned short* K2h = Qlo + (size_t)2048 * 4096;        // frag-major
  unsigned short* K2l = K2h + (size_t)2048 * 1024;
  unsigned short* V2  = K2l + (size_t)2048 * 1024;        // frag-major
  unsigned short* AO = hb_hi;         // hidden splits dead after projections
  float* cmaxg = (float*)wq_hi;       // wq splits dead after projections
  u64* selEg = (u64*)wk_hi;           // wk splits dead after projections
  u64* selOg = selEg + 32 * 2048;
  float* mxg = (float*)(selOg + 32 * 2048);
  float* ctab = out;                  // staged in d_out; fully overwritten by o8ph
  float* stab = ctab + 2048 * 64;

  cvt_all<<<49152, 256, 0, stream>>>(hidden, wq, wk, wv, wo,
                                     hb_hi, hb_lo, wq_hi, wq_lo,
                                     wk_hi, wk_lo, wv_b, wo_b);
  rope_table<<<512, 256, 0, stream>>>(ctab, stab);

  kv8ph<<<256, 512, 0, stream>>>(hb_hi, hb_lo, wk_hi, wk_lo, wv_b,
                                 ctab, stab, K2h, K2l, V2);
  q8ph<<<256, 512, 0, stream>>>(hb_hi, hb_lo, wq_hi, wq_lo,
                                ctab, stab, Qhi, Qlo);

  cmax_gemm<<<dim3(16, 32), 256, 0, stream>>>(Qhi, Qlo, K2h, K2l, cmaxg);
  select_kernel<<<dim3(32, 32), 256, 0, stream>>>(cmaxg, selEg, selOg, mxg);
  attnB<<<dim3(128, 8), 256, 0, stream>>>(Qhi, K2h, V2, selEg, selOg, mxg, AO);

  o8ph<<<256, 512, 0, stream>>>(AO, wo_b, out);
}

// Round 17
// 666.627 us; speedup vs baseline: 1.0834x; 1.0095x over previous
//
#include <hip/hip_runtime.h>
#include <math.h>

typedef __attribute__((ext_vector_type(4))) float f32x4;
typedef __attribute__((ext_vector_type(8))) __bf16 bf16x8;
typedef __attribute__((ext_vector_type(4))) unsigned short us4;
typedef unsigned long long u64;

__device__ __forceinline__ unsigned short f2bf(float f) {
  unsigned int u = __float_as_uint(f);
  u += 0x7fffu + ((u >> 16) & 1u);            // RNE
  return (unsigned short)(u >> 16);
}
__device__ __forceinline__ float bf2f(unsigned short h) {
  return __uint_as_float(((unsigned int)h) << 16);
}

__device__ __forceinline__ void gload16(const void* g, void* l) {
  __builtin_amdgcn_global_load_lds(
      (__attribute__((address_space(1))) void*)g,
      (__attribute__((address_space(3))) void*)l, 16, 0, 0);
}

// ---------------- K2 fragment-major index: K element (s, kvh, d) ----------------
__device__ __forceinline__ long k2idx(int kvh, int s, int d) {
  int ct = s >> 4;
  int lane = (((d & 31) >> 3) << 4) | (s & 15);
  return ((long)(kvh * 128 + ct) * 4 + (d >> 5)) * 512 + lane * 8 + (d & 7);
}

// ---------------- fused fp32 -> bf16 conversions ----------------
__device__ __forceinline__ void split1(const float* __restrict__ in,
                                       unsigned short* __restrict__ hi,
                                       unsigned short* __restrict__ lo, int i) {
  float4 v = ((const float4*)in)[i];
  us4 h, l;
  float vv[4] = {v.x, v.y, v.z, v.w};
#pragma unroll
  for (int j = 0; j < 4; ++j) {
    unsigned short hh = f2bf(vv[j]);
    h[j] = hh;
    l[j] = f2bf(vv[j] - bf2f(hh));
  }
  ((us4*)hi)[i] = h;
  ((us4*)lo)[i] = l;
}
__device__ __forceinline__ void plain1(const float* __restrict__ in,
                                       unsigned short* __restrict__ out, int i) {
  float4 v = ((const float4*)in)[i];
  us4 o;
  o[0] = f2bf(v.x); o[1] = f2bf(v.y); o[2] = f2bf(v.z); o[3] = f2bf(v.w);
  ((us4*)out)[i] = o;
}

__global__ __launch_bounds__(256) void cvt_all(const float* __restrict__ hidden,
                                               const float* __restrict__ wq,
                                               const float* __restrict__ wk,
                                               const float* __restrict__ wv,
                                               const float* __restrict__ wo,
                                               unsigned short* __restrict__ hb_hi,
                                               unsigned short* __restrict__ hb_lo,
                                               unsigned short* __restrict__ wq_hi,
                                               unsigned short* __restrict__ wq_lo,
                                               unsigned short* __restrict__ wk_hi,
                                               unsigned short* __restrict__ wk_lo,
                                               unsigned short* __restrict__ wv_b,
                                               unsigned short* __restrict__ wo_b) {
  int i = blockIdx.x * 256 + threadIdx.x;
  if (i < 2097152)       split1(hidden, hb_hi, hb_lo, i);
  else if (i < 6291456)  split1(wq, wq_hi, wq_lo, i - 2097152);
  else if (i < 7340032)  split1(wk, wk_hi, wk_lo, i - 6291456);
  else if (i < 8388608)  plain1(wv, wv_b, i - 7340032);
  else if (i < 12582912) plain1(wo, wo_b, i - 8388608);
}

// ---------------- RoPE angle table (staged in d_out; overwritten by final GEMM) ----------------
__global__ __launch_bounds__(256) void rope_table(float* __restrict__ ctab,
                                                  float* __restrict__ stab) {
  int idx = blockIdx.x * 256 + threadIdx.x;   // 2048*64
  if (idx >= 2048 * 64) return;
  int s = idx >> 6, d = idx & 63;
  float inv = powf(10000.0f, -(float)d * (1.0f / 64.0f));
  float ang = (float)s * inv;
  ctab[idx] = cosf(ang);
  stab[idx] = sinf(ang);
}

// shared phase macros
#define PH_SYNC                                          \
  __builtin_amdgcn_sched_barrier(0);                     \
  __builtin_amdgcn_s_barrier();                          \
  asm volatile("s_waitcnt lgkmcnt(0)" ::: "memory");     \
  __builtin_amdgcn_sched_barrier(0);                     \
  __builtin_amdgcn_s_setprio(1);
#define PH_DONE                                          \
  __builtin_amdgcn_s_setprio(0);                         \
  __builtin_amdgcn_sched_barrier(0);
#define PH_ENTER                                         \
  __builtin_amdgcn_sched_barrier(0);                     \
  __builtin_amdgcn_s_barrier();                          \
  asm volatile("s_waitcnt lgkmcnt(0)" ::: "memory");     \
  __builtin_amdgcn_sched_barrier(0);                     \
  __builtin_amdgcn_s_setprio(1);
#define PH_EXIT                                          \
  __builtin_amdgcn_s_setprio(0);                         \
  __builtin_amdgcn_sched_barrier(0);                     \
  __builtin_amdgcn_s_barrier();                          \
  __builtin_amdgcn_sched_barrier(0);

// ======== Q-proj: single-barrier-phase counted-vmcnt 3-term GEMM + rope epilogue ========
// Triple-buffered (distance-2 staging => WAR-free with one barrier/phase). vmcnt(4) steady.
__global__ __launch_bounds__(512, 2) void q8ph(const unsigned short* __restrict__ Ahg,
                                               const unsigned short* __restrict__ Alg,
                                               const unsigned short* __restrict__ wq_hi,
                                               const unsigned short* __restrict__ wq_lo,
                                               const float* __restrict__ ctab,
                                               const float* __restrict__ stab,
                                               unsigned short* __restrict__ Qh,
                                               unsigned short* __restrict__ Ql) {
  __shared__ __align__(16) unsigned short shb[73728];   // 144 KB
  const int bid = blockIdx.x;
  const int tid = threadIdx.x;
  const int w = tid >> 6, l = tid & 63;
  const int lr = l & 15, lg = l >> 4;
  const int wr = w >> 2, wc = w & 3;
  const int nt = 128;

  const int m_idx = (bid & 7) * 2 + ((bid >> 3) & 1);   // A-pair pinned per XCD
  const int n_idx = bid >> 4;
  const long m0 = (long)m_idx * 128;
  const long n0 = (long)n_idx * 256;

  const int arow = tid >> 2;
  const int kg = ((tid & 3) ^ ((tid >> 2) & 3) ^ ((tid >> 4) & 3)) & 3;
  const long aoff  = (m0 + arow) * 4096 + kg * 8;
  const long boff0 = (n0 + arow) * 4096 + kg * 8;
  const long boff1 = (n0 + 128 + arow) * 4096 + kg * 8;
  const int dstw = w * 512;

  const int xk = (lg ^ (lr & 3) ^ ((lr >> 2) & 3)) & 3;

#define QSTG_A(t, bs)                                                         \
  { gload16(Ahg + aoff + (long)(t) * 32, &shb[(bs) * 4096 + dstw]);           \
    gload16(Alg + aoff + (long)(t) * 32, &shb[12288 + (bs) * 4096 + dstw]); }
#define QSTG_BH(t, bs)                                                        \
  { gload16(wq_hi + boff0 + (long)(t) * 32, &shb[24576 + (bs) * 8192 + dstw]);\
    gload16(wq_hi + boff1 + (long)(t) * 32, &shb[24576 + (bs) * 8192 + 4096 + dstw]); }
#define QSTG_BL(t, bs)                                                        \
  { gload16(wq_lo + boff0 + (long)(t) * 32, &shb[49152 + (bs) * 8192 + dstw]);\
    gload16(wq_lo + boff1 + (long)(t) * 32, &shb[49152 + (bs) * 8192 + 4096 + dstw]); }

  f32x4 acc[4][4] = {};

  QSTG_A(0, 0); QSTG_BH(0, 0); QSTG_BL(0, 0);
  QSTG_A(1, 1); QSTG_BH(1, 1); QSTG_BL(1, 1);
  QSTG_A(2, 2); QSTG_BH(2, 2); QSTG_BL(2, 2);
  asm volatile("s_waitcnt vmcnt(12)" ::: "memory");
  __builtin_amdgcn_s_barrier();
  __builtin_amdgcn_sched_barrier(0);

#define QPH_MFMA(p, bh, bl)                                                                    \
  _Pragma("unroll")                                                                            \
  for (int mi = 0; mi < 4; ++mi) {                                                             \
    acc[mi][p] = __builtin_amdgcn_mfma_f32_16x16x32_bf16(afh[mi], bh, acc[mi][p], 0, 0, 0);    \
    acc[mi][p] = __builtin_amdgcn_mfma_f32_16x16x32_bf16(afl[mi], bh, acc[mi][p], 0, 0, 0);    \
    acc[mi][p] = __builtin_amdgcn_mfma_f32_16x16x32_bf16(afh[mi], bl, acc[mi][p], 0, 0, 0);    \
  }
#define QPH_RDB(p, bh, bl)                                                          \
  { int rowb = wc * 64 + (p) * 16 + lr;                                             \
    bh = *(const bf16x8*)&shb[24576 + bs * 8192 + rowb * 32 + xk * 8];              \
    bl = *(const bf16x8*)&shb[49152 + bs * 8192 + rowb * 32 + xk * 8]; }

  for (int t = 0; t < nt; ++t) {
    const int bs = t % 3;
    const int bss = (t + 2) % 3;
    const bool st = (t + 2) < nt;
    bf16x8 afh[4], afl[4], bh0, bl0, bh1, bl1, bh2, bl2, bh3, bl3;
    // ---- phase A: ds_read A frags + B(0,1); barrier; stage A+BH(t+2); 24 MFMA ----
#pragma unroll
    for (int mi = 0; mi < 4; ++mi) {
      int rowa = wr * 64 + mi * 16 + lr;
      afh[mi] = *(const bf16x8*)&shb[bs * 4096 + rowa * 32 + xk * 8];
      afl[mi] = *(const bf16x8*)&shb[12288 + bs * 4096 + rowa * 32 + xk * 8];
    }
    QPH_RDB(0, bh0, bl0);
    QPH_RDB(1, bh1, bl1);
    PH_SYNC;
    if (st) { QSTG_A(t + 2, bss); QSTG_BH(t + 2, bss); }
    __builtin_amdgcn_sched_barrier(0);
    QPH_MFMA(0, bh0, bl0);
    QPH_MFMA(1, bh1, bl1);
    PH_DONE;
    // ---- phase B: ds_read B(2,3); counted vmcnt; barrier; stage BL(t+2); 24 MFMA ----
    QPH_RDB(2, bh2, bl2);
    QPH_RDB(3, bh3, bl3);
    if (st) asm volatile("s_waitcnt vmcnt(4)" ::: "memory");
    else    asm volatile("s_waitcnt vmcnt(0)" ::: "memory");
    PH_SYNC;
    if (st) QSTG_BL(t + 2, bss);
    __builtin_amdgcn_sched_barrier(0);
    QPH_MFMA(2, bh2, bl2);
    QPH_MFMA(3, bh3, bl3);
    PH_DONE;
  }
#undef QSTG_A
#undef QSTG_BH
#undef QSTG_BL
#undef QPH_MFMA
#undef QPH_RDB

  __syncthreads();
  float* Cls = (float*)shb;                              // 128 x 260-stride fp32 (padded, 133 KB)
#pragma unroll
  for (int mi = 0; mi < 4; ++mi)
#pragma unroll
    for (int ni = 0; ni < 4; ++ni)
#pragma unroll
      for (int j = 0; j < 4; ++j)
        Cls[(wr * 64 + mi * 16 + lg * 4 + j) * 260 + wc * 64 + ni * 16 + lr] = acc[mi][ni][j];
  __syncthreads();

  const int r0l = tid >> 3;
  const int d0 = (tid & 7) * 8;
#pragma unroll
  for (int h = 0; h < 2; ++h) {
    const int head = n_idx * 2 + h;
#pragma unroll
    for (int k = 0; k < 2; ++k) {
      const int r = r0l + 64 * k;
      const long s = m0 + r;
      float X1[8], X2[8], CC[8], SS[8];
      {
        f32x4 a = *(const f32x4*)&Cls[r * 260 + h * 128 + d0];
        f32x4 b = *(const f32x4*)&Cls[r * 260 + h * 128 + d0 + 4];
        f32x4 c = *(const f32x4*)&Cls[r * 260 + h * 128 + 64 + d0];
        f32x4 d = *(const f32x4*)&Cls[r * 260 + h * 128 + 64 + d0 + 4];
        f32x4 e = *(const f32x4*)&ctab[s * 64 + d0];
        f32x4 f = *(const f32x4*)&ctab[s * 64 + d0 + 4];
        f32x4 g = *(const f32x4*)&stab[s * 64 + d0];
        f32x4 hh = *(const f32x4*)&stab[s * 64 + d0 + 4];
#pragma unroll
        for (int j = 0; j < 4; ++j) {
          X1[j] = a[j]; X1[j + 4] = b[j];
          X2[j] = c[j]; X2[j + 4] = d[j];
          CC[j] = e[j]; CC[j + 4] = f[j];
          SS[j] = g[j]; SS[j + 4] = hh[j];
        }
      }
      us4 H1[2], L1[2], H2[2], L2[2];
#pragma unroll
      for (int j = 0; j < 8; ++j) {
        float y1 = (X1[j] * CC[j] - X2[j] * SS[j]) * 0.08838834764831845f;
        float y2 = (X2[j] * CC[j] + X1[j] * SS[j]) * 0.08838834764831845f;
        unsigned short h1 = f2bf(y1), h2 = f2bf(y2);
        H1[j >> 2][j & 3] = h1; L1[j >> 2][j & 3] = f2bf(y1 - bf2f(h1));
        H2[j >> 2][j & 3] = h2; L2[j >> 2][j & 3] = f2bf(y2 - bf2f(h2));
      }
      long row = s * 4096 + head * 128;
      *(us4*)&Qh[row + d0] = H1[0];      *(us4*)&Qh[row + d0 + 4] = H1[1];
      *(us4*)&Ql[row + d0] = L1[0];      *(us4*)&Ql[row + d0 + 4] = L1[1];
      *(us4*)&Qh[row + 64 + d0] = H2[0]; *(us4*)&Qh[row + 64 + d0 + 4] = H2[1];
      *(us4*)&Ql[row + 64 + d0] = L2[0]; *(us4*)&Ql[row + 64 + d0 + 4] = L2[1];
    }
  }
}

// ======== K/V-proj: K-branch single-barrier phases (vmcnt 2); V-branch unchanged ========
__global__ __launch_bounds__(512, 2) void kv8ph(const unsigned short* __restrict__ Ahg,
                                                const unsigned short* __restrict__ Alg,
                                                const unsigned short* __restrict__ wk_hi,
                                                const unsigned short* __restrict__ wk_lo,
                                                const unsigned short* __restrict__ wv_b,
                                                const float* __restrict__ ctab,
                                                const float* __restrict__ stab,
                                                unsigned short* __restrict__ K2h,
                                                unsigned short* __restrict__ K2l,
                                                unsigned short* __restrict__ V2) {
  __shared__ __align__(16) unsigned short shb[49152];   // 96 KB
  const int bid = blockIdx.x;
  const int tid = threadIdx.x;
  const int w = tid >> 6, l = tid & 63;
  const int lr = l & 15, lg = l >> 4;
  const int wr = w >> 2, wc = w & 3;
  const int nt = 128;

  const int bb = (bid < 128) ? bid : (bid - 128);
  const int m_idx = (bb & 7) * 2 + ((bb >> 3) & 1);
  const int n_idx = bb >> 4;
  const long m0 = (long)m_idx * 128;
  const long n0 = (long)n_idx * 128;

  const int arow = tid >> 2;
  const int kg = ((tid & 3) ^ ((tid >> 2) & 3) ^ ((tid >> 4) & 3)) & 3;
  const long aoff = (m0 + arow) * 4096 + kg * 8;
  const long boff = (n0 + arow) * 4096 + kg * 8;
  const int dstw = w * 512;

  const int xk = (lg ^ (lr & 3) ^ ((lr >> 2) & 3)) & 3;

  if (bid < 128) {
#define KSTG_A(t, bs)                                                          \
  { gload16(Ahg + aoff + (long)(t) * 32, &shb[(bs) * 4096 + dstw]);            \
    gload16(Alg + aoff + (long)(t) * 32, &shb[12288 + (bs) * 4096 + dstw]); }
#define KSTG_B(t, bs)                                                          \
  { gload16(wk_hi + boff + (long)(t) * 32, &shb[24576 + (bs) * 4096 + dstw]);  \
    gload16(wk_lo + boff + (long)(t) * 32, &shb[36864 + (bs) * 4096 + dstw]); }
#define KPH_MFMA(p, bh, bl)                                                                    \
  _Pragma("unroll")                                                                            \
  for (int mi = 0; mi < 4; ++mi) {                                                             \
    acc[mi][p] = __builtin_amdgcn_mfma_f32_16x16x32_bf16(afh[mi], bh, acc[mi][p], 0, 0, 0);    \
    acc[mi][p] = __builtin_amdgcn_mfma_f32_16x16x32_bf16(afl[mi], bh, acc[mi][p], 0, 0, 0);    \
    acc[mi][p] = __builtin_amdgcn_mfma_f32_16x16x32_bf16(afh[mi], bl, acc[mi][p], 0, 0, 0);    \
  }

    f32x4 acc[4][2] = {};

    KSTG_A(0, 0); KSTG_B(0, 0);
    KSTG_A(1, 1); KSTG_B(1, 1);
    KSTG_A(2, 2); KSTG_B(2, 2);
    asm volatile("s_waitcnt vmcnt(8)" ::: "memory");
    __builtin_amdgcn_s_barrier();
    __builtin_amdgcn_sched_barrier(0);

    for (int t = 0; t < nt; ++t) {
      const int bs = t % 3;
      const int bss = (t + 2) % 3;
      const bool st = (t + 2) < nt;
      bf16x8 afh[4], afl[4], bh0, bl0, bh1, bl1;
#pragma unroll
      for (int mi = 0; mi < 4; ++mi) {
        int rowa = wr * 64 + mi * 16 + lr;
        afh[mi] = *(const bf16x8*)&shb[bs * 4096 + rowa * 32 + xk * 8];
        afl[mi] = *(const bf16x8*)&shb[12288 + bs * 4096 + rowa * 32 + xk * 8];
      }
      {
        int rowb = wc * 32 + lr;
        bh0 = *(const bf16x8*)&shb[24576 + bs * 4096 + rowb * 32 + xk * 8];
        bl0 = *(const bf16x8*)&shb[36864 + bs * 4096 + rowb * 32 + xk * 8];
      }
      PH_SYNC;
      if (st) KSTG_A(t + 2, bss);
      __builtin_amdgcn_sched_barrier(0);
      KPH_MFMA(0, bh0, bl0);
      PH_DONE;
      {
        int rowb = wc * 32 + 16 + lr;
        bh1 = *(const bf16x8*)&shb[24576 + bs * 4096 + rowb * 32 + xk * 8];
        bl1 = *(const bf16x8*)&shb[36864 + bs * 4096 + rowb * 32 + xk * 8];
      }
      if (st) asm volatile("s_waitcnt vmcnt(2)" ::: "memory");
      else    asm volatile("s_waitcnt vmcnt(0)" ::: "memory");
      PH_SYNC;
      if (st) KSTG_B(t + 2, bss);
      __builtin_amdgcn_sched_barrier(0);
      KPH_MFMA(1, bh1, bl1);
      PH_DONE;
    }
#undef KSTG_A
#undef KSTG_B
#undef KPH_MFMA

    __syncthreads();
    float* Cls = (float*)shb;                            // 128 x 132-stride fp32 (padded)
#pragma unroll
    for (int mi = 0; mi < 4; ++mi)
#pragma unroll
      for (int ni = 0; ni < 2; ++ni)
#pragma unroll
        for (int j = 0; j < 4; ++j)
          Cls[(wr * 64 + mi * 16 + lg * 4 + j) * 132 + wc * 32 + ni * 16 + lr] = acc[mi][ni][j];
    __syncthreads();

    const int kvh = (int)(n0 >> 7);
    const int r0l = tid >> 3;
    const int d0 = (tid & 7) * 8;
#pragma unroll
    for (int k = 0; k < 2; ++k) {
      const int r = r0l + 64 * k;
      const long s = m0 + r;
      float X1[8], X2[8], CC[8], SS[8];
      {
        f32x4 a = *(const f32x4*)&Cls[r * 132 + d0];
        f32x4 b = *(const f32x4*)&Cls[r * 132 + d0 + 4];
        f32x4 c = *(const f32x4*)&Cls[r * 132 + 64 + d0];
        f32x4 d = *(const f32x4*)&Cls[r * 132 + 64 + d0 + 4];
        f32x4 e = *(const f32x4*)&ctab[s * 64 + d0];
        f32x4 f = *(const f32x4*)&ctab[s * 64 + d0 + 4];
        f32x4 g = *(const f32x4*)&stab[s * 64 + d0];
        f32x4 h = *(const f32x4*)&stab[s * 64 + d0 + 4];
#pragma unroll
        for (int j = 0; j < 4; ++j) {
          X1[j] = a[j]; X1[j + 4] = b[j];
          X2[j] = c[j]; X2[j + 4] = d[j];
          CC[j] = e[j]; CC[j + 4] = f[j];
          SS[j] = g[j]; SS[j + 4] = h[j];
        }
      }
      us4 H1[2], L1[2], H2[2], L2[2];
#pragma unroll
      for (int j = 0; j < 8; ++j) {
        float y1 = X1[j] * CC[j] - X2[j] * SS[j];
        float y2 = X2[j] * CC[j] + X1[j] * SS[j];
        unsigned short h1 = f2bf(y1), h2 = f2bf(y2);
        H1[j >> 2][j & 3] = h1; L1[j >> 2][j & 3] = f2bf(y1 - bf2f(h1));
        H2[j >> 2][j & 3] = h2; L2[j >> 2][j & 3] = f2bf(y2 - bf2f(h2));
      }
      long i1 = k2idx(kvh, (int)s, d0);
      long i2 = k2idx(kvh, (int)s, d0 + 64);
      *(us4*)&K2h[i1] = H1[0]; *(us4*)&K2h[i1 + 4] = H1[1];
      *(us4*)&K2l[i1] = L1[0]; *(us4*)&K2l[i1 + 4] = L1[1];
      *(us4*)&K2h[i2] = H2[0]; *(us4*)&K2h[i2 + 4] = H2[1];
      *(us4*)&K2l[i2] = L2[0]; *(us4*)&K2l[i2 + 4] = L2[1];
    }
    return;
  }

  // ---------------- V-proj: unchanged (2-barrier single phase, vmcnt(2)) ----------------
  {
#define VSTG(t, bs)                                                            \
  { gload16(Ahg + aoff + (long)(t) * 32, &shb[(bs) * 4096 + dstw]);            \
    gload16(wv_b + boff + (long)(t) * 32, &shb[12288 + (bs) * 4096 + dstw]); }

    f32x4 acc[4][2] = {};

    VSTG(0, 0);
    VSTG(1, 1);
    VSTG(2, 2);
    asm volatile("s_waitcnt vmcnt(4)" ::: "memory");
    __builtin_amdgcn_s_barrier();
    __builtin_amdgcn_sched_barrier(0);

    for (int t = 0; t < nt; ++t) {
      const int bs = t % 3;
      const int bss = (t + 2) % 3;
      const bool st = (t + 2) < nt;
      bf16x8 af[4], bf0, bf1;
#pragma unroll
      for (int mi = 0; mi < 4; ++mi) {
        int rowa = wr * 64 + mi * 16 + lr;
        af[mi] = *(const bf16x8*)&shb[bs * 4096 + rowa * 32 + xk * 8];
      }
      {
        int rb0 = wc * 32 + lr;
        int rb1 = wc * 32 + 16 + lr;
        bf0 = *(const bf16x8*)&shb[12288 + bs * 4096 + rb0 * 32 + xk * 8];
        bf1 = *(const bf16x8*)&shb[12288 + bs * 4096 + rb1 * 32 + xk * 8];
      }
      if (st) VSTG(t + 2, bss);
      if (st) asm volatile("s_waitcnt vmcnt(2)" ::: "memory");
      else    asm volatile("s_waitcnt vmcnt(0)" ::: "memory");
      PH_ENTER;
#pragma unroll
      for (int mi = 0; mi < 4; ++mi) {
        acc[mi][0] = __builtin_amdgcn_mfma_f32_16x16x32_bf16(af[mi], bf0, acc[mi][0], 0, 0, 0);
        acc[mi][1] = __builtin_amdgcn_mfma_f32_16x16x32_bf16(af[mi], bf1, acc[mi][1], 0, 0, 0);
      }
      PH_EXIT;
    }
#undef VSTG

#pragma unroll
    for (int mi = 0; mi < 4; ++mi)
#pragma unroll
      for (int ni = 0; ni < 2; ++ni)
#pragma unroll
        for (int j = 0; j < 4; ++j) {
          long r = m0 + wr * 64 + mi * 16 + lg * 4 + j;
          long cc = n0 + wc * 32 + ni * 16 + lr;
          int kvh = (int)(cc >> 7), d = (int)(cc & 127);
          int c = (int)(r >> 4), t2 = (int)(r & 15);
          long idx = ((long)(kvh * 128 + c) * 8 + (d >> 4)) * 256 + ((t2 >> 3) * 16 + (d & 15)) * 8 + (t2 & 7);
          V2[idx] = f2bf(acc[mi][ni][j]);
        }
  }
}

// ======== O-proj: single-barrier phases (vmcnt 2) ========
__global__ __launch_bounds__(512, 2) void o8ph(const unsigned short* __restrict__ A,
                                               const unsigned short* __restrict__ B,
                                               float* __restrict__ C) {
  __shared__ __align__(16) unsigned short shb[36864];   // 72 KB
  const int bid = blockIdx.x;
  const int tid = threadIdx.x;
  const int w = tid >> 6, l = tid & 63;
  const int lr = l & 15, lg = l >> 4;
  const int wr = w >> 2, wc = w & 3;
  const int nt = 128;

  const int m_idx = (bid & 7) * 2 + ((bid >> 3) & 1);
  const int n_idx = bid >> 4;
  const long m0 = (long)m_idx * 128;
  const long n0 = (long)n_idx * 256;

  const int arow = tid >> 2;
  const int kg = ((tid & 3) ^ ((tid >> 2) & 3) ^ ((tid >> 4) & 3)) & 3;
  const long aoff  = (m0 + arow) * 4096 + kg * 8;
  const long boff0 = (n0 + arow) * 4096 + kg * 8;
  const long boff1 = (n0 + 128 + arow) * 4096 + kg * 8;
  const int dstw = w * 512;

  const int xk = (lg ^ (lr & 3) ^ ((lr >> 2) & 3)) & 3;

#define OSTG_A(t, bs)                                                        \
  gload16(A + aoff + (long)(t) * 32, &shb[(bs) * 4096 + dstw]);
#define OSTG_B0(t, bs)                                                       \
  gload16(B + boff0 + (long)(t) * 32, &shb[12288 + (bs) * 8192 + dstw]);
#define OSTG_B1(t, bs)                                                       \
  gload16(B + boff1 + (long)(t) * 32, &shb[12288 + (bs) * 8192 + 4096 + dstw]);

  f32x4 acc[4][4] = {};

  OSTG_A(0, 0); OSTG_B0(0, 0); OSTG_B1(0, 0);
  OSTG_A(1, 1); OSTG_B0(1, 1); OSTG_B1(1, 1);
  OSTG_A(2, 2); OSTG_B0(2, 2); OSTG_B1(2, 2);
  asm volatile("s_waitcnt vmcnt(6)" ::: "memory");
  __builtin_amdgcn_s_barrier();
  __builtin_amdgcn_sched_barrier(0);

#define OPH_RDB(p, dst)                                                             \
  { int rowb = wc * 64 + (p) * 16 + lr;                                             \
    dst = *(const bf16x8*)&shb[12288 + bs * 8192 + (rowb & 127) * 32 +              \
                               ((rowb >> 7) & 1) * 4096 + xk * 8]; }

  for (int t = 0; t < nt; ++t) {
    const int bs = t % 3;
    const int bss = (t + 2) % 3;
    const bool st = (t + 2) < nt;
    bf16x8 af[4], bf0, bf1, bf2, bf3;
#pragma unroll
    for (int mi = 0; mi < 4; ++mi) {
      int rowa = wr * 64 + mi * 16 + lr;
      af[mi] = *(const bf16x8*)&shb[bs * 4096 + rowa * 32 + xk * 8];
    }
    OPH_RDB(0, bf0);
    OPH_RDB(1, bf1);
    PH_SYNC;
    if (st) { OSTG_A(t + 2, bss); OSTG_B0(t + 2, bss); }
    __builtin_amdgcn_sched_barrier(0);
#pragma unroll
    for (int mi = 0; mi < 4; ++mi) {
      acc[mi][0] = __builtin_amdgcn_mfma_f32_16x16x32_bf16(af[mi], bf0, acc[mi][0], 0, 0, 0);
      acc[mi][1] = __builtin_amdgcn_mfma_f32_16x16x32_bf16(af[mi], bf1, acc[mi][1], 0, 0, 0);
    }
    PH_DONE;
    OPH_RDB(2, bf2);
    OPH_RDB(3, bf3);
    if (st) asm volatile("s_waitcnt vmcnt(2)" ::: "memory");
    else    asm volatile("s_waitcnt vmcnt(0)" ::: "memory");
    PH_SYNC;
    if (st) OSTG_B1(t + 2, bss);
    __builtin_amdgcn_sched_barrier(0);
#pragma unroll
    for (int mi = 0; mi < 4; ++mi) {
      acc[mi][2] = __builtin_amdgcn_mfma_f32_16x16x32_bf16(af[mi], bf2, acc[mi][2], 0, 0, 0);
      acc[mi][3] = __builtin_amdgcn_mfma_f32_16x16x32_bf16(af[mi], bf3, acc[mi][3], 0, 0, 0);
    }
    PH_DONE;
  }
#undef OSTG_A
#undef OSTG_B0
#undef OSTG_B1
#undef OPH_RDB

#pragma unroll
  for (int mi = 0; mi < 4; ++mi)
#pragma unroll
    for (int ni = 0; ni < 4; ++ni)
#pragma unroll
      for (int j = 0; j < 4; ++j) {
        long r = m0 + wr * 64 + mi * 16 + lg * 4 + j;
        long cc = n0 + wc * 64 + ni * 16 + lr;
        C[r * 4096 + cc] = acc[mi][ni][j];
      }
}

// ======== K1: cmax GEMM, 4-deep counted-vmcnt pipeline (unchanged). ========
__global__ __launch_bounds__(256, 2) void cmax_gemm(const unsigned short* __restrict__ Qh,
                                                    const unsigned short* __restrict__ Ql,
                                                    const unsigned short* __restrict__ K2h,
                                                    const unsigned short* __restrict__ K2l,
                                                    float* __restrict__ cmaxg) {
  __shared__ __align__(16) unsigned short Ksh[4][4096];
  __shared__ __align__(16) unsigned short Ksl[4][4096];
  const int qp = 15 - (int)blockIdx.x;
  const int h = blockIdx.y;
  const int kvh = h >> 2;
  const int q0 = qp * 128;
  const int tid = threadIdx.x;
  const int w = tid >> 6, l = tid & 63;
  const int lr = l & 15, lg = l >> 4;
  const int npan = 4 * (qp + 1);
  const float NEGINF = -__builtin_inff();

  bf16x8 qfh[2][4], qfl[2][4];
#pragma unroll
  for (int rg = 0; rg < 2; ++rg) {
    const unsigned short* qph = Qh + (long)(q0 + w * 32 + rg * 16 + lr) * 4096 + h * 128 + lg * 8;
    const unsigned short* qpl = Ql + (long)(q0 + w * 32 + rg * 16 + lr) * 4096 + h * 128 + lg * 8;
#pragma unroll
    for (int ks = 0; ks < 4; ++ks) {
      qfh[rg][ks] = *(const bf16x8*)(qph + ks * 32);
      qfl[rg][ks] = *(const bf16x8*)(qpl + ks * 32);
    }
  }

  const unsigned short* kbh = K2h + (long)kvh * 128 * 2048;
  const unsigned short* kbl = K2l + (long)kvh * 128 * 2048;

#define STAGE(kp, b)                                                       \
  {                                                                        \
    long off = (long)(kp) * 4096;                                          \
    _Pragma("unroll")                                                      \
    for (int i = 0; i < 2; ++i) {                                          \
      int cu = w * 128 + i * 64;                                           \
      gload16(kbh + off + (cu + l) * 8, &Ksh[b][cu * 8]);                  \
      gload16(kbl + off + (cu + l) * 8, &Ksl[b][cu * 8]);                  \
    }                                                                      \
  }

  STAGE(0, 0);
  if (1 < npan) STAGE(1, 1);
  if (2 < npan) STAGE(2, 2);

  for (int kp = 0; kp < npan; ++kp) {
    {
      int ahead = npan - 1 - kp; if (ahead > 2) ahead = 2;
      int st = kp; if (st > 3) st = 3;
      int tgt = 4 * ahead + 4 * st;
      if (tgt >= 20)      asm volatile("s_waitcnt vmcnt(20)" ::: "memory");
      else if (tgt >= 16) asm volatile("s_waitcnt vmcnt(16)" ::: "memory");
      else if (tgt >= 12) asm volatile("s_waitcnt vmcnt(12)" ::: "memory");
      else if (tgt >= 8)  asm volatile("s_waitcnt vmcnt(8)" ::: "memory");
      else                asm volatile("s_waitcnt vmcnt(0)" ::: "memory");
    }
    __builtin_amdgcn_s_barrier();
    __builtin_amdgcn_sched_barrier(0);
    if (kp + 3 < npan) STAGE(kp + 3, (kp + 3) & 3);
    const int b = kp & 3;
#pragma unroll
    for (int c2 = 0; c2 < 2; ++c2) {
      const int ct = kp * 2 + c2;
      bf16x8 kh[4], kl2[4];
#pragma unroll
      for (int ks = 0; ks < 4; ++ks) {
        kh[ks]  = *(const bf16x8*)&Ksh[b][(c2 * 4 + ks) * 512 + l * 8];
        kl2[ks] = *(const bf16x8*)&Ksl[b][(c2 * 4 + ks) * 512 + l * 8];
      }
#pragma unroll
      for (int rg = 0; rg < 2; ++rg) {
        f32x4 acc = {};
#pragma unroll
        for (int ks = 0; ks < 4; ++ks) {
          acc = __builtin_amdgcn_mfma_f32_16x16x32_bf16(kh[ks], qfh[rg][ks], acc, 0, 0, 0);
          acc = __builtin_amdgcn_mfma_f32_16x16x32_bf16(kh[ks], qfl[rg][ks], acc, 0, 0, 0);
          acc = __builtin_amdgcn_mfma_f32_16x16x32_bf16(kl2[ks], qfh[rg][ks], acc, 0, 0, 0);
        }
        const int rbase = q0 + w * 32 + rg * 16;
        float m;
        if (ct * 16 + 15 <= rbase) {
          m = fmaxf(fmaxf(acc[0], acc[1]), fmaxf(acc[2], acc[3]));
        } else {
          m = NEGINF;
#pragma unroll
          for (int j = 0; j < 4; ++j) {
            int tok = ct * 16 + lg * 4 + j;
            if (tok <= rbase + lr) m = fmaxf(m, acc[j]);
          }
        }
        m = fmaxf(m, __shfl_xor(m, 16));
        m = fmaxf(m, __shfl_xor(m, 32));
        if (l < 16) cmaxg[(long)(h * 128 + ct) * 2048 + rbase + l] = m;
      }
    }
  }
#undef STAGE
}

// ======== K2: per-row top-8 selection (unchanged). ========
__global__ __launch_bounds__(256) void select_kernel(const float* __restrict__ cmaxg,
                                                     u64* __restrict__ selEg,
                                                     u64* __restrict__ selOg,
                                                     float* __restrict__ mxg) {
  __shared__ float Lc[128 * 65];
  const int r0 = (int)blockIdx.x * 64;
  const int h = blockIdx.y;
  const int tid = threadIdx.x;
  const int w = tid >> 6, l = tid & 63;
  const float NEGINF = -__builtin_inff();

  for (int i = tid; i < 128 * 16; i += 256) {
    int ct = i >> 4, rq = (i & 15) * 4;
    float4 v = *(const float4*)&cmaxg[(long)(h * 128 + ct) * 2048 + r0 + rq];
    Lc[ct * 65 + rq]     = v.x;
    Lc[ct * 65 + rq + 1] = v.y;
    Lc[ct * 65 + rq + 2] = v.z;
    Lc[ct * 65 + rq + 3] = v.w;
  }
  __syncthreads();

  const int c0 = 2 * l, c1 = 2 * l + 1;
#pragma unroll 1
  for (int rs = 0; rs < 16; ++rs) {
    const int rloc = w * 16 + rs;
    const int qr = r0 + rloc;
    const int nctr = (qr >> 4) + 1;
    float v0 = (c0 < nctr) ? Lc[c0 * 65 + rloc] : NEGINF;
    float v1 = (c1 < nctr) ? Lc[c1 * 65 + rloc] : NEGINF;
    const float o0 = v0, o1 = v1;
    float T = NEGINF;
    for (int it = 0; it < 8; ++it) {
      float m = fmaxf(v0, v1);
#pragma unroll
      for (int o = 1; o < 64; o <<= 1) m = fmaxf(m, __shfl_xor(m, o));
      u64 bal = __ballot((v0 == m) || (v1 == m));
      int first = __ffsll(bal) - 1;
      if (l == first) { if (v0 == m) v0 = NEGINF; else v1 = NEGINF; }
      T = m;
    }
    bool okc0 = (c0 < nctr) && ((c0 < 8) || (o0 >= T));
    bool okc1 = (c1 < nctr) && ((c1 < 8) || (o1 >= T));
    u64 bE = __ballot(okc0);
    u64 bO = __ballot(okc1);
    bool al0 = (c0 < nctr) && (okc0 || (c0 * 16 + 15 > qr - 128));
    bool al1 = (c1 < nctr) && (okc1 || (c1 * 16 + 15 > qr - 128));
    float mv = fmaxf(al0 ? o0 : NEGINF, al1 ? o1 : NEGINF);
#pragma unroll
    for (int o = 1; o < 64; o <<= 1) mv = fmaxf(mv, __shfl_xor(mv, o));
    if (l == 0) {
      selEg[h * 2048 + qr] = bE;
      selOg[h * 2048 + qr] = bO;
      mxg[h * 2048 + qr] = mv;
    }
  }
}

// ---------------- P LDS swizzled index ----------------
__device__ __forceinline__ int pidx2(int r, int t) {
  return r * 32 + ((((t >> 3) ^ (r & 3)) << 3) | (t & 7));
}

// ======== K3: phase B (unchanged) ========
__global__ __launch_bounds__(256) void attnB(const unsigned short* __restrict__ Qh,
                                             const unsigned short* __restrict__ K2h,
                                             const unsigned short* __restrict__ V2,
                                             const u64* __restrict__ selEg,
                                             const u64* __restrict__ selOg,
                                             const float* __restrict__ mxg,
                                             unsigned short* __restrict__ AO) {
  __shared__ __align__(16) unsigned short Pls[4][512];
  __shared__ int clistS[4][128];

  const int qb = (int)gridDim.x - 1 - (int)blockIdx.x;
  const int kvh = blockIdx.y;
  const int q0 = qb * 16;
  const int nct = qb + 1;
  const int tid = threadIdx.x;
  const int w = tid >> 6, l = tid & 63;
  const int lr = l & 15, lg = l >> 4;
  const int h = kvh * 4 + w;

  bf16x8 qfh[4];
  {
    const unsigned short* qph = Qh + (long)(q0 + lr) * 4096 + h * 128 + lg * 8;
#pragma unroll
    for (int ks = 0; ks < 4; ++ks) qfh[ks] = *(const bf16x8*)(qph + ks * 32);
  }

  u64 myE = selEg[h * 2048 + q0 + lr];
  u64 myO = selOg[h * 2048 + q0 + lr];
  float mymx = mxg[h * 2048 + q0 + lr];

  u64 uE = myE, uO = myO;
#pragma unroll
  for (int o = 1; o < 16; o <<= 1) {
    uE |= __shfl_xor(uE, o);
    uO |= __shfl_xor(uO, o);
  }
  float mxj[4];
  u64 selE[4], selO[4];
#pragma unroll
  for (int j = 0; j < 4; ++j) {
    mxj[j] = __shfl(mymx, lg * 4 + j);
    selE[j] = __shfl(myE, lg * 4 + j);
    selO[j] = __shfl(myO, lg * 4 + j);
  }

  unsigned short* Pw = Pls[w];
  int* cl = clistS[w];

  const int c0 = 2 * l, c1 = 2 * l + 1;
  bool s0ok = (c0 < nct) && (((uE >> l) & 1ull) || (c0 >= qb - 7));
  bool s1ok = (c1 < nct) && (((uO >> l) & 1ull) || (c1 >= qb - 7));
  u64 bA = __ballot(s0ok);
  u64 bB = __ballot(s1ok);
  const int cntA = __popcll(bA);
  const int nsel = cntA + __popcll(bB);
  if (s0ok) cl[__popcll(bA & ((1ull << l) - 1ull))] = c0;
  if (s1ok) cl[cntA + __popcll(bB & ((1ull << l) - 1ull))] = c1;

  const unsigned short* kbh = K2h + (long)kvh * 128 * 2048;

  f32x4 pacc[8] = {};
  float psum[4] = {0.f, 0.f, 0.f, 0.f};
  const int np = (nsel + 1) >> 1;

  bf16x8 kA[4], kB[4];
  {
    const int cA0 = cl[0];
    const int cB0 = (1 < nsel) ? cl[1] : cA0;
    const unsigned short* pA = kbh + (long)cA0 * 2048 + l * 8;
    const unsigned short* pB = kbh + (long)cB0 * 2048 + l * 8;
#pragma unroll
    for (int ks = 0; ks < 4; ++ks) {
      kA[ks] = *(const bf16x8*)(pA + ks * 512);
      kB[ks] = *(const bf16x8*)(pB + ks * 512);
    }
  }

  for (int pi = 0; pi < np; ++pi) {
    const int cA = cl[2 * pi];
    const int iB = 2 * pi + 1;
    const int cB = (iB < nsel) ? cl[iB] : cA;

    const int csel = (lg < 2) ? cA : cB;
    const unsigned short* vp = V2 + (long)(kvh * 128 + csel) * 2048 + ((lg & 1) * 16 + lr) * 8;
    bf16x8 vf[8];
#pragma unroll
    for (int dblk = 0; dblk < 8; ++dblk) vf[dblk] = *(const bf16x8*)(vp + dblk * 256);

    bf16x8 nA[4], nB[4];
    {
      const int pin = (pi + 1 < np) ? pi + 1 : pi;
      const int cA1 = cl[2 * pin];
      const int iB1 = 2 * pin + 1;
      const int cB1 = (iB1 < nsel) ? cl[iB1] : cA1;
      const unsigned short* pA = kbh + (long)cA1 * 2048 + l * 8;
      const unsigned short* pB = kbh + (long)cB1 * 2048 + l * 8;
#pragma unroll
      for (int ks = 0; ks < 4; ++ks) {
        nA[ks] = *(const bf16x8*)(pA + ks * 512);
        nB[ks] = *(const bf16x8*)(pB + ks * 512);
      }
    }

#pragma unroll
    for (int half = 0; half < 2; ++half) {
      const int c = half ? cB : cA;
      const bool vslot = (2 * pi + half) < nsel;
      f32x4 acc = {};
#pragma unroll
      for (int ks = 0; ks < 4; ++ks) {
        bf16x8 kf = half ? kB[ks] : kA[ks];
        acc = __builtin_amdgcn_mfma_f32_16x16x32_bf16(qfh[ks], kf, acc, 0, 0, 0);
      }
#pragma unroll
      for (int j = 0; j < 4; ++j) {
        const int r = lg * 4 + j;
        const int qrr = q0 + r;
        const int tok = c * 16 + lr;
        u64 sm = (c & 1) ? selO[j] : selE[j];
        bool sel = (sm >> (c >> 1)) & 1ull;
        bool al = vslot && (tok <= qrr) && (sel || (tok > qrr - 128));
        float p = al ? __expf(acc[j] - mxj[j]) : 0.f;
        unsigned short pb = f2bf(p);
        psum[j] += bf2f(pb);
        Pw[pidx2(r, half * 16 + lr)] = pb;
      }
    }
    bf16x8 pa = *(const bf16x8*)&Pw[pidx2(lr, lg * 8)];
#pragma unroll
    for (int dblk = 0; dblk < 8; ++dblk)
      pacc[dblk] = __builtin_amdgcn_mfma_f32_16x16x32_bf16(pa, vf[dblk], pacc[dblk], 0, 0, 0);

#pragma unroll
    for (int ks = 0; ks < 4; ++ks) { kA[ks] = nA[ks]; kB[ks] = nB[ks]; }
  }

#pragma unroll
  for (int j = 0; j < 4; ++j) {
    float s = psum[j];
    s += __shfl_xor(s, 1); s += __shfl_xor(s, 2);
    s += __shfl_xor(s, 4); s += __shfl_xor(s, 8);
    const float rd = 1.0f / s;
    const int r = lg * 4 + j;
#pragma unroll
    for (int dblk = 0; dblk < 8; ++dblk)
      AO[(long)(q0 + r) * 4096 + h * 128 + dblk * 16 + lr] = f2bf(pacc[dblk][j] * rd);
  }
}

// ---------------- launch ----------------
extern "C" void kernel_launch(void* const* d_in, const int* in_sizes, int n_in,
                              void* d_out, int out_size, void* d_ws, size_t ws_size,
                              hipStream_t stream) {
  const float* hidden = (const float*)d_in[0];
  const float* wq = (const float*)d_in[1];
  const float* wk = (const float*)d_in[2];
  const float* wv = (const float*)d_in[3];
  const float* wo = (const float*)d_in[4];
  float* out = (float*)d_out;

  unsigned short* hb_hi = (unsigned short*)d_ws;          // [2048][4096]
  unsigned short* hb_lo = hb_hi + (size_t)2048 * 4096;
  unsigned short* wq_hi = hb_lo + (size_t)2048 * 4096;    // [4096][4096]
  unsigned short* wq_lo = wq_hi + (size_t)4096 * 4096;
  unsigned short* wk_hi = wq_lo + (size_t)4096 * 4096;    // [1024][4096]
  unsigned short* wk_lo = wk_hi + (size_t)1024 * 4096;
  unsigned short* wv_b  = wk_lo + (size_t)1024 * 4096;    // [1024][4096]
  unsigned short* wo_b  = wv_b  + (size_t)1024 * 4096;    // [4096][4096]
  unsigned short* Qhi = wo_b + (size_t)4096 * 4096;       // [2048][4096] bf16
  unsigned short* Qlo = Qhi + (size_t)2048 * 4096;
  unsigned short* K2h = Qlo + (size_t)2048 * 4096;        // frag-major
  unsigned short* K2l = K2h + (size_t)2048 * 1024;
  unsigned short* V2  = K2l + (size_t)2048 * 1024;        // frag-major
  unsigned short* AO = hb_hi;         // hidden splits dead after projections
  float* cmaxg = (float*)wq_hi;       // wq splits dead after projections
  u64* selEg = (u64*)wk_hi;           // wk splits dead after projections
  u64* selOg = selEg + 32 * 2048;
  float* mxg = (float*)(selOg + 32 * 2048);
  float* ctab = out;                  // staged in d_out; fully overwritten by o8ph
  float* stab = ctab + 2048 * 64;

  cvt_all<<<49152, 256, 0, stream>>>(hidden, wq, wk, wv, wo,
                                     hb_hi, hb_lo, wq_hi, wq_lo,
                                     wk_hi, wk_lo, wv_b, wo_b);
  rope_table<<<512, 256, 0, stream>>>(ctab, stab);

  kv8ph<<<256, 512, 0, stream>>>(hb_hi, hb_lo, wk_hi, wk_lo, wv_b,
                                 ctab, stab, K2h, K2l, V2);
  q8ph<<<256, 512, 0, stream>>>(hb_hi, hb_lo, wq_hi, wq_lo,
                                ctab, stab, Qhi, Qlo);

  cmax_gemm<<<dim3(16, 32), 256, 0, stream>>>(Qhi, Qlo, K2h, K2l, cmaxg);
  select_kernel<<<dim3(32, 32), 256, 0, stream>>>(cmaxg, selEg, selOg, mxg);
  attnB<<<dim3(128, 8), 256, 0, stream>>>(Qhi, K2h, V2, selEg, selOg, mxg, AO);

  o8ph<<<256, 512, 0, stream>>>(AO, wo_b, out);
}